// Round 2
// baseline (29980.035 us; speedup 1.0000x reference)
//
#include <hip/hip_runtime.h>
#include <hip/hip_bf16.h>

// Problem constants
#define N_ROWS   16384      // 8*2048
#define EMB_DIM  64
#define NUM_EMB  8192
#define TOP_K    10
#define PERP_W   0.01

// Pass-1 chunking: 16 code-chunks of 512; per-chunk top-12 per row.
// Union of per-chunk top-12 provably contains the global top-10.
#define CHUNKS        16
#define CHUNK_CODES   512
#define TILE_CODES    16
#define TILES_PER_CH  (CHUNK_CODES / TILE_CODES)   // 32
#define M_CHUNK       12
#define CANDS         (CHUNKS * M_CHUNK)           // 192

// Output layout (all float32, concatenated in return order)
#define QST_OFF   0
#define LOSS_OFF  (N_ROWS * EMB_DIM)                 // 1048576
#define IDX_OFF   (LOSS_OFF + 1)                     // 1048577
#define MIND_OFF  (IDX_OFF + N_ROWS)                 // 1064961
#define PERP_OFF  (MIND_OFF + N_ROWS)                // 1081345

// ws layout (bytes)
#define WS_E2F    0                                  // 8192 floats  (32 KB)
#define WS_COUNTS 32768                              // 8192 ints    (32 KB)
#define WS_LOSS   65536                              // 1 double
#define WS_NVALID 65544                              // 1 int
#define WS_CAND   65600                              // 16384*192 ushort (6.3 MB)

// ---------------------------------------------------------------------------
// Kernel 0: precompute ||e_k||^2 (fp32, pass-1 ranking only) and zero atomics.
// ---------------------------------------------------------------------------
__global__ __launch_bounds__(256) void vq_init(const float* __restrict__ cb,
                                               float* __restrict__ e2f,
                                               int* __restrict__ counts,
                                               int* __restrict__ nvalid,
                                               double* __restrict__ lossacc) {
    int k = blockIdx.x * 256 + threadIdx.x;   // 0..8191
    counts[k] = 0;
    const float* row = cb + k * EMB_DIM;
    float s = 0.0f;
#pragma unroll 8
    for (int d = 0; d < EMB_DIM; ++d) s += row[d] * row[d];
    e2f[k] = s;
    if (k == 0) { *nvalid = 0; *lossacc = 0.0; }
}

// ---------------------------------------------------------------------------
// Kernel 1: distance GEMM + per-(row,chunk) top-12, thread-per-row.
// Block: 256 threads = 256 rows; blockIdx.y = code chunk (512 codes).
// Codebook tile (16 codes x 64 dims) double-buffered in LDS; all lanes read
// the same LDS address (broadcast, conflict-free). Per-thread top list lives
// in an LDS column [k][tid] (lane-stride-1, conflict-free, no barriers).
// Ranking score s = dot - (x2+e2)/2 = -d/2  (maximize s == minimize d).
// ---------------------------------------------------------------------------
__global__ __launch_bounds__(256, 4) void vq_gemm_topk(
        const float* __restrict__ inp, const float* __restrict__ cb,
        const float* __restrict__ e2f, unsigned short* __restrict__ cand) {
    __shared__ __align__(16) float bt[2][EMB_DIM][20];   // [buf][d][code], pad 20 keeps 16B align
    __shared__ __align__(16) float e2s[2][TILE_CODES];
    __shared__ float          lvs[M_CHUNK][256];
    __shared__ unsigned short lis[M_CHUNK][256];

    const int tid   = threadIdx.x;
    const int row   = blockIdx.x * 256 + tid;
    const int code0 = blockIdx.y * CHUNK_CODES;

    float* lv = &lvs[0][0];
    unsigned short* li = &lis[0][0];

    // load x row into registers (64 floats)
    float4 xv[16];
    const float4* xp = (const float4*)(inp + (size_t)row * EMB_DIM);
#pragma unroll
    for (int i = 0; i < 16; ++i) xv[i] = xp[i];
    float x2 = 0.0f;
#pragma unroll
    for (int i = 0; i < 16; ++i)
        x2 += xv[i].x * xv[i].x + xv[i].y * xv[i].y + xv[i].z * xv[i].z + xv[i].w * xv[i].w;

    // init per-thread list (ascending by s; [0] = threshold)
#pragma unroll
    for (int k = 0; k < M_CHUNK; ++k) { lv[k * 256 + tid] = -3.0e38f; li[k * 256 + tid] = 0; }
    float thr = -3.0e38f;

    // stage tile 0 into buffer 0
    {
        const int c = tid >> 4, dq = (tid & 15) << 2;
        float4 v = *(const float4*)(cb + (size_t)(code0 + c) * EMB_DIM + dq);
        bt[0][dq + 0][c] = v.x; bt[0][dq + 1][c] = v.y;
        bt[0][dq + 2][c] = v.z; bt[0][dq + 3][c] = v.w;
        if (tid < TILE_CODES) e2s[0][tid] = e2f[code0 + tid];
    }

    for (int t = 0; t < TILES_PER_CH; ++t) {
        const int p = t & 1;
        __syncthreads();
        // prefetch tile t+1 into the other buffer
        if (t + 1 < TILES_PER_CH) {
            const int q = p ^ 1;
            const int c = tid >> 4, dq = (tid & 15) << 2;
            float4 v = *(const float4*)(cb + (size_t)(code0 + (t + 1) * TILE_CODES + c) * EMB_DIM + dq);
            bt[q][dq + 0][c] = v.x; bt[q][dq + 1][c] = v.y;
            bt[q][dq + 2][c] = v.z; bt[q][dq + 3][c] = v.w;
            if (tid < TILE_CODES) e2s[q][tid] = e2f[code0 + (t + 1) * TILE_CODES + tid];
        }

        // accumulators initialized to -(x2+e2)/2
        float4 a0, a1, a2, a3;
        {
            const float4 e0 = *(const float4*)&e2s[p][0];
            const float4 e1 = *(const float4*)&e2s[p][4];
            const float4 e2v = *(const float4*)&e2s[p][8];
            const float4 e3 = *(const float4*)&e2s[p][12];
            a0.x = -0.5f * (x2 + e0.x);  a0.y = -0.5f * (x2 + e0.y);
            a0.z = -0.5f * (x2 + e0.z);  a0.w = -0.5f * (x2 + e0.w);
            a1.x = -0.5f * (x2 + e1.x);  a1.y = -0.5f * (x2 + e1.y);
            a1.z = -0.5f * (x2 + e1.z);  a1.w = -0.5f * (x2 + e1.w);
            a2.x = -0.5f * (x2 + e2v.x); a2.y = -0.5f * (x2 + e2v.y);
            a2.z = -0.5f * (x2 + e2v.z); a2.w = -0.5f * (x2 + e2v.w);
            a3.x = -0.5f * (x2 + e3.x);  a3.y = -0.5f * (x2 + e3.y);
            a3.z = -0.5f * (x2 + e3.z);  a3.w = -0.5f * (x2 + e3.w);
        }

#define DSTEP(XD, DD) { \
        const float4 b0 = *(const float4*)&bt[p][DD][0];  \
        const float4 b1 = *(const float4*)&bt[p][DD][4];  \
        const float4 b2 = *(const float4*)&bt[p][DD][8];  \
        const float4 b3 = *(const float4*)&bt[p][DD][12]; \
        a0.x = fmaf(XD, b0.x, a0.x); a0.y = fmaf(XD, b0.y, a0.y); \
        a0.z = fmaf(XD, b0.z, a0.z); a0.w = fmaf(XD, b0.w, a0.w); \
        a1.x = fmaf(XD, b1.x, a1.x); a1.y = fmaf(XD, b1.y, a1.y); \
        a1.z = fmaf(XD, b1.z, a1.z); a1.w = fmaf(XD, b1.w, a1.w); \
        a2.x = fmaf(XD, b2.x, a2.x); a2.y = fmaf(XD, b2.y, a2.y); \
        a2.z = fmaf(XD, b2.z, a2.z); a2.w = fmaf(XD, b2.w, a2.w); \
        a3.x = fmaf(XD, b3.x, a3.x); a3.y = fmaf(XD, b3.y, a3.y); \
        a3.z = fmaf(XD, b3.z, a3.z); a3.w = fmaf(XD, b3.w, a3.w); }

#pragma unroll
        for (int dq = 0; dq < 16; ++dq) {
            const float4 xq = xv[dq];
            DSTEP(xq.x, (4 * dq + 0));
            DSTEP(xq.y, (4 * dq + 1));
            DSTEP(xq.z, (4 * dq + 2));
            DSTEP(xq.w, (4 * dq + 3));
        }
#undef DSTEP

        // selection: keep 12 largest s per thread (rare inserts)
        const int cbase = code0 + t * TILE_CODES;
#define CHECK(SV, II) \
        if ((SV) > thr) { \
            float s_ = (SV); int k_ = 0; \
            while (k_ + 1 < M_CHUNK && s_ > lv[(k_ + 1) * 256 + tid]) { \
                lv[k_ * 256 + tid] = lv[(k_ + 1) * 256 + tid]; \
                li[k_ * 256 + tid] = li[(k_ + 1) * 256 + tid]; \
                ++k_; \
            } \
            lv[k_ * 256 + tid] = s_; \
            li[k_ * 256 + tid] = (unsigned short)(II); \
            thr = lv[tid]; \
        }
        CHECK(a0.x, cbase + 0)  CHECK(a0.y, cbase + 1)
        CHECK(a0.z, cbase + 2)  CHECK(a0.w, cbase + 3)
        CHECK(a1.x, cbase + 4)  CHECK(a1.y, cbase + 5)
        CHECK(a1.z, cbase + 6)  CHECK(a1.w, cbase + 7)
        CHECK(a2.x, cbase + 8)  CHECK(a2.y, cbase + 9)
        CHECK(a2.z, cbase + 10) CHECK(a2.w, cbase + 11)
        CHECK(a3.x, cbase + 12) CHECK(a3.y, cbase + 13)
        CHECK(a3.z, cbase + 14) CHECK(a3.w, cbase + 15)
#undef CHECK
    }

    // dump candidate indices (global code ids, 13-bit, as ushort)
    unsigned short* cr = cand + (size_t)row * CANDS + blockIdx.y * M_CHUNK;
#pragma unroll
    for (int k = 0; k < M_CHUNK; ++k) cr[k] = li[k * 256 + tid];
}

// ---------------------------------------------------------------------------
// Kernel 2: fp64 re-rank of 192 candidates, stable (d,idx) top-10, Gumbel-max
// sample, outputs + atomics. One wave per row; 4 rows per 256-thread block.
// ---------------------------------------------------------------------------
__global__ __launch_bounds__(256) void vq_finalize(const float* __restrict__ inp,
                                                   const float* __restrict__ cb,
                                                   const float* __restrict__ gumbel,
                                                   const unsigned short* __restrict__ cand,
                                                   float* __restrict__ out,
                                                   int* __restrict__ counts,
                                                   int* __restrict__ nvalid,
                                                   double* __restrict__ lossacc) {
    __shared__ double xs[4][EMB_DIM];
    __shared__ double dvs[4][CANDS];
    __shared__ int    dis[4][CANDS];

    const int tid  = threadIdx.x;
    const int w    = tid >> 6;
    const int lane = tid & 63;
    const int row  = blockIdx.x * 4 + w;

    const float xf = inp[(size_t)row * EMB_DIM + lane];
    const double xd = (double)xf;
    xs[w][lane] = xd;

    // wave-wide ||x||^2 in fp64
    double x2 = xd * xd;
#pragma unroll
    for (int off = 32; off >= 1; off >>= 1) x2 += __shfl_xor(x2, off);
    const bool valid = sqrt(x2) > 1e-6;

    __syncthreads();  // publish xs

    // 3 candidates per lane: exact fp64 distances
#pragma unroll
    for (int m = 0; m < 3; ++m) {
        const int j  = lane + 64 * m;
        const int ci = (int)cand[(size_t)row * CANDS + j];
        const float* e = cb + (size_t)ci * EMB_DIM;
        double dot = 0.0, ee = 0.0;
#pragma unroll
        for (int dq = 0; dq < 16; ++dq) {
            const float4 ev = *(const float4*)(e + 4 * dq);
            const double e0 = (double)ev.x, e1 = (double)ev.y;
            const double e2d = (double)ev.z, e3 = (double)ev.w;
            dot = fma(xs[w][4 * dq + 0], e0, dot);
            dot = fma(xs[w][4 * dq + 1], e1, dot);
            dot = fma(xs[w][4 * dq + 2], e2d, dot);
            dot = fma(xs[w][4 * dq + 3], e3, dot);
            ee  = fma(e0, e0, ee); ee = fma(e1, e1, ee);
            ee  = fma(e2d, e2d, ee); ee = fma(e3, e3, ee);
        }
        dvs[w][j] = x2 + ee - 2.0 * dot;
        dis[w][j] = ci;
    }
    __syncthreads();

    int   cidx = 0;
    float mind = 0.0f;
    if (lane == 0) {
        // running top-10 by (distance, index) — JAX top_k tie-break
        double sv[TOP_K]; int si[TOP_K]; int cnt = 0;
        for (int j = 0; j < CANDS; ++j) {
            const double v = dvs[w][j];
            const int   ii = dis[w][j];
            if (cnt == TOP_K) {
                if (!(v < sv[TOP_K - 1] ||
                      (v == sv[TOP_K - 1] && ii < si[TOP_K - 1]))) continue;
                --cnt;
            }
            int p = cnt;
            while (p > 0 && (sv[p - 1] > v || (sv[p - 1] == v && si[p - 1] > ii))) {
                sv[p] = sv[p - 1]; si[p] = si[p - 1]; --p;
            }
            sv[p] = v; si[p] = ii; ++cnt;
        }
        // Gumbel-max over top-10 (argmax keeps first max, like jnp.argmax)
        const float* g = gumbel + (size_t)row * TOP_K;
        float best = -3.0e38f; int bj = 0;
        for (int k = 0; k < TOP_K; ++k) {
            const float sc = (float)(-sv[k]) + g[k];
            if (sc > best) { best = sc; bj = k; }
        }
        cidx = si[bj];
        mind = (float)sv[bj];
    }
    cidx = __shfl(cidx, 0);
    mind = __shfl(mind, 0);

    const float vm = valid ? 1.0f : 0.0f;
    const float q  = cb[(size_t)cidx * EMB_DIM + lane];
    const float qv = q * vm;
    out[QST_OFF + (size_t)row * EMB_DIM + lane] = xf + (qv - xf);

    // loss term uses UNMASKED q_valid, masked by vm
    double dq = (double)q - xd;
    double l  = dq * dq * (double)vm;
#pragma unroll
    for (int off = 32; off >= 1; off >>= 1) l += __shfl_xor(l, off);

    if (lane == 0) {
        atomicAdd(lossacc, l);
        if (valid) {
            atomicAdd(&counts[cidx], 1);
            atomicAdd(nvalid, 1);
        }
        out[IDX_OFF + row]  = valid ? (float)cidx : 0.0f;
        out[MIND_OFF + row] = valid ? mind : 0.0f;
    }
}

// ---------------------------------------------------------------------------
// Kernel 3: perplexity + total loss scalars.
// ---------------------------------------------------------------------------
__global__ __launch_bounds__(256) void vq_scalars(const int* __restrict__ counts,
                                                  const int* __restrict__ nvalid,
                                                  const double* __restrict__ lossacc,
                                                  float* __restrict__ out) {
    __shared__ double red[256];
    const int tid = threadIdx.x;
    int nv_i = *nvalid;
    double nv = (double)(nv_i > 0 ? nv_i : 1);

    double h = 0.0;
    for (int k = tid; k < NUM_EMB; k += 256) {
        double p = (double)counts[k] / nv;
        h += p * log(p + 1e-10);
    }
    red[tid] = h;
    __syncthreads();
    for (int s = 128; s >= 1; s >>= 1) {
        if (tid < s) red[tid] += red[tid + s];
        __syncthreads();
    }
    if (tid == 0) {
        double H = red[0];                       // sum p*log(p+1e-10)
        double perp = exp(-H);
        double ploss = -log(perp + 1e-10);
        double lvq = (*lossacc) / (nv * (double)EMB_DIM);
        out[LOSS_OFF] = (float)(lvq + PERP_W * ploss);
        out[PERP_OFF] = (float)perp;
    }
}

// ---------------------------------------------------------------------------
extern "C" void kernel_launch(void* const* d_in, const int* in_sizes, int n_in,
                              void* d_out, int out_size, void* d_ws, size_t ws_size,
                              hipStream_t stream) {
    const float* inp    = (const float*)d_in[0];  // [16384, 64]
    const float* cb     = (const float*)d_in[1];  // [8192, 64]
    const float* gumbel = (const float*)d_in[2];  // [16384, 10]
    float* out = (float*)d_out;

    char* ws = (char*)d_ws;
    float*          e2f     = (float*)(ws + WS_E2F);
    int*            counts  = (int*)(ws + WS_COUNTS);
    double*         lossacc = (double*)(ws + WS_LOSS);
    int*            nvalid  = (int*)(ws + WS_NVALID);
    unsigned short* candw   = (unsigned short*)(ws + WS_CAND);

    vq_init<<<NUM_EMB / 256, 256, 0, stream>>>(cb, e2f, counts, nvalid, lossacc);
    vq_gemm_topk<<<dim3(N_ROWS / 256, CHUNKS), 256, 0, stream>>>(inp, cb, e2f, candw);
    vq_finalize<<<N_ROWS / 4, 256, 0, stream>>>(inp, cb, gumbel, candw, out,
                                                counts, nvalid, lossacc);
    vq_scalars<<<1, 256, 0, stream>>>(counts, nvalid, lossacc, out);
}

// Round 3
// 2240.005 us; speedup vs baseline: 13.3839x; 13.3839x over previous
//
#include <hip/hip_runtime.h>
#include <hip/hip_bf16.h>

// Problem constants
#define N_ROWS   16384      // 8*2048
#define EMB_DIM  64
#define NUM_EMB  8192
#define TOP_K    10
#define PERP_W   0.01

// Pass-1 chunking: 16 code-chunks of 512; per-chunk top-12 per row.
// Union of per-chunk top-12 provably contains the global top-10.
#define CHUNKS        16
#define CHUNK_CODES   512
#define M_CHUNK       12
#define CANDS         (CHUNKS * M_CHUNK)           // 192

// Output layout (all float32, concatenated in return order)
#define QST_OFF   0
#define LOSS_OFF  (N_ROWS * EMB_DIM)                 // 1048576
#define IDX_OFF   (LOSS_OFF + 1)                     // 1048577
#define MIND_OFF  (IDX_OFF + N_ROWS)                 // 1064961
#define PERP_OFF  (MIND_OFF + N_ROWS)                // 1081345

// ws layout (bytes)
#define WS_E2F    0                                  // 8192 floats  (32 KB)
#define WS_COUNTS 32768                              // 8192 ints    (32 KB)
#define WS_LOSS   65536                              // 1 double
#define WS_NVALID 65544                              // 1 int
#define WS_CAND   65600                              // 16384*192 ushort (6.3 MB)

// ---------------------------------------------------------------------------
// Kernel 0: precompute ||e_k||^2 (fp32, pass-1 ranking only) and zero atomics.
// ---------------------------------------------------------------------------
__global__ __launch_bounds__(256) void vq_init(const float* __restrict__ cb,
                                               float* __restrict__ e2f,
                                               int* __restrict__ counts,
                                               int* __restrict__ nvalid,
                                               double* __restrict__ lossacc) {
    int k = blockIdx.x * 256 + threadIdx.x;   // 0..8191
    counts[k] = 0;
    const float* row = cb + k * EMB_DIM;
    float s = 0.0f;
#pragma unroll 8
    for (int d = 0; d < EMB_DIM; ++d) s += row[d] * row[d];
    e2f[k] = s;
    if (k == 0) { *nvalid = 0; *lossacc = 0.0; }
}

// ---------------------------------------------------------------------------
// Kernel 1: distance GEMM + per-(row,chunk) top-12, thread-per-row.
// Block: 256 threads = 256 rows; blockIdx.y = code chunk (512 codes).
// Codebook values are block-uniform -> read straight from global with
// uniform indices (const __restrict__), which the compiler scalarizes to
// s_load + v_fma with SGPR operand. No LDS staging, no barriers.
// x row (64 floats) lives in VGPRs (NO launch-bounds clamp -> no spill).
// Per-thread top list in LDS columns [k][tid] (lane-stride-1, conflict-free).
// Ranking score s = dot - (x2+e2)/2 = -d/2  (maximize s == minimize d).
// ---------------------------------------------------------------------------
__global__ __launch_bounds__(256) void vq_gemm_topk(
        const float* __restrict__ inp, const float* __restrict__ cb,
        const float* __restrict__ e2f, unsigned short* __restrict__ cand) {
    __shared__ float          lvs[M_CHUNK][256];
    __shared__ unsigned short lis[M_CHUNK][256];

    const int tid   = threadIdx.x;
    const int row   = blockIdx.x * 256 + tid;
    const int code0 = blockIdx.y * CHUNK_CODES;

    float* lv = &lvs[0][0];
    unsigned short* li = &lis[0][0];

    // load x row into registers (64 floats)
    float xr[EMB_DIM];
    {
        const float4* xp = (const float4*)(inp + (size_t)row * EMB_DIM);
#pragma unroll
        for (int i = 0; i < 16; ++i) {
            float4 v = xp[i];
            xr[4 * i + 0] = v.x; xr[4 * i + 1] = v.y;
            xr[4 * i + 2] = v.z; xr[4 * i + 3] = v.w;
        }
    }
    float x2 = 0.0f;
#pragma unroll
    for (int i = 0; i < EMB_DIM; ++i) x2 += xr[i] * xr[i];

    // init per-thread list (ascending by score; [0] = threshold slot)
#pragma unroll
    for (int k = 0; k < M_CHUNK; ++k) { lv[k * 256 + tid] = -3.0e38f; li[k * 256 + tid] = 0; }
    float thr = -3.0e38f;

    for (int cg = 0; cg < CHUNK_CODES; cg += 8) {
        const float* cbr = cb + (size_t)(code0 + cg) * EMB_DIM;   // uniform base

        float a0 = -0.5f * (x2 + e2f[code0 + cg + 0]);
        float a1 = -0.5f * (x2 + e2f[code0 + cg + 1]);
        float a2 = -0.5f * (x2 + e2f[code0 + cg + 2]);
        float a3 = -0.5f * (x2 + e2f[code0 + cg + 3]);
        float a4 = -0.5f * (x2 + e2f[code0 + cg + 4]);
        float a5 = -0.5f * (x2 + e2f[code0 + cg + 5]);
        float a6 = -0.5f * (x2 + e2f[code0 + cg + 6]);
        float a7 = -0.5f * (x2 + e2f[code0 + cg + 7]);

#pragma unroll
        for (int d = 0; d < EMB_DIM; ++d) {
            const float xd = xr[d];
            a0 = fmaf(xd, cbr[0 * EMB_DIM + d], a0);
            a1 = fmaf(xd, cbr[1 * EMB_DIM + d], a1);
            a2 = fmaf(xd, cbr[2 * EMB_DIM + d], a2);
            a3 = fmaf(xd, cbr[3 * EMB_DIM + d], a3);
            a4 = fmaf(xd, cbr[4 * EMB_DIM + d], a4);
            a5 = fmaf(xd, cbr[5 * EMB_DIM + d], a5);
            a6 = fmaf(xd, cbr[6 * EMB_DIM + d], a6);
            a7 = fmaf(xd, cbr[7 * EMB_DIM + d], a7);
        }

        // selection: keep 12 largest scores per thread (rare inserts).
        // Codes visited in ascending index order; strict-> insert keeps the
        // earliest index on ties (JAX top_k tie-break preserved downstream).
        const int cbase = code0 + cg;
#define CHECK(SV, II) \
        if ((SV) > thr) { \
            float s_ = (SV); int k_ = 0; \
            while (k_ + 1 < M_CHUNK && s_ > lv[(k_ + 1) * 256 + tid]) { \
                lv[k_ * 256 + tid] = lv[(k_ + 1) * 256 + tid]; \
                li[k_ * 256 + tid] = li[(k_ + 1) * 256 + tid]; \
                ++k_; \
            } \
            lv[k_ * 256 + tid] = s_; \
            li[k_ * 256 + tid] = (unsigned short)(II); \
            thr = lv[tid]; \
        }
        CHECK(a0, cbase + 0)  CHECK(a1, cbase + 1)
        CHECK(a2, cbase + 2)  CHECK(a3, cbase + 3)
        CHECK(a4, cbase + 4)  CHECK(a5, cbase + 5)
        CHECK(a6, cbase + 6)  CHECK(a7, cbase + 7)
#undef CHECK
    }

    // dump candidate indices (global code ids, 13-bit, as ushort)
    unsigned short* cr = cand + (size_t)row * CANDS + blockIdx.y * M_CHUNK;
#pragma unroll
    for (int k = 0; k < M_CHUNK; ++k) cr[k] = li[k * 256 + tid];
}

// ---------------------------------------------------------------------------
// Kernel 2: fp64 re-rank of 192 candidates, stable (d,idx) top-10, Gumbel-max
// sample, outputs + atomics. One wave per row; 4 rows per 256-thread block.
// ---------------------------------------------------------------------------
__global__ __launch_bounds__(256) void vq_finalize(const float* __restrict__ inp,
                                                   const float* __restrict__ cb,
                                                   const float* __restrict__ gumbel,
                                                   const unsigned short* __restrict__ cand,
                                                   float* __restrict__ out,
                                                   int* __restrict__ counts,
                                                   int* __restrict__ nvalid,
                                                   double* __restrict__ lossacc) {
    __shared__ double xs[4][EMB_DIM];
    __shared__ double dvs[4][CANDS];
    __shared__ int    dis[4][CANDS];

    const int tid  = threadIdx.x;
    const int w    = tid >> 6;
    const int lane = tid & 63;
    const int row  = blockIdx.x * 4 + w;

    const float xf = inp[(size_t)row * EMB_DIM + lane];
    const double xd = (double)xf;
    xs[w][lane] = xd;

    // wave-wide ||x||^2 in fp64
    double x2 = xd * xd;
#pragma unroll
    for (int off = 32; off >= 1; off >>= 1) x2 += __shfl_xor(x2, off);
    const bool valid = sqrt(x2) > 1e-6;

    __syncthreads();  // publish xs

    // 3 candidates per lane: exact fp64 distances
#pragma unroll
    for (int m = 0; m < 3; ++m) {
        const int j  = lane + 64 * m;
        const int ci = (int)cand[(size_t)row * CANDS + j];
        const float* e = cb + (size_t)ci * EMB_DIM;
        double dot = 0.0, ee = 0.0;
#pragma unroll
        for (int dq = 0; dq < 16; ++dq) {
            const float4 ev = *(const float4*)(e + 4 * dq);
            const double e0 = (double)ev.x, e1 = (double)ev.y;
            const double e2d = (double)ev.z, e3 = (double)ev.w;
            dot = fma(xs[w][4 * dq + 0], e0, dot);
            dot = fma(xs[w][4 * dq + 1], e1, dot);
            dot = fma(xs[w][4 * dq + 2], e2d, dot);
            dot = fma(xs[w][4 * dq + 3], e3, dot);
            ee  = fma(e0, e0, ee); ee = fma(e1, e1, ee);
            ee  = fma(e2d, e2d, ee); ee = fma(e3, e3, ee);
        }
        dvs[w][j] = x2 + ee - 2.0 * dot;
        dis[w][j] = ci;
    }
    __syncthreads();

    int   cidx = 0;
    float mind = 0.0f;
    if (lane == 0) {
        // running top-10 by (distance, index) — JAX top_k tie-break
        double sv[TOP_K]; int si[TOP_K]; int cnt = 0;
        for (int j = 0; j < CANDS; ++j) {
            const double v = dvs[w][j];
            const int   ii = dis[w][j];
            if (cnt == TOP_K) {
                if (!(v < sv[TOP_K - 1] ||
                      (v == sv[TOP_K - 1] && ii < si[TOP_K - 1]))) continue;
                --cnt;
            }
            int p = cnt;
            while (p > 0 && (sv[p - 1] > v || (sv[p - 1] == v && si[p - 1] > ii))) {
                sv[p] = sv[p - 1]; si[p] = si[p - 1]; --p;
            }
            sv[p] = v; si[p] = ii; ++cnt;
        }
        // Gumbel-max over top-10 (argmax keeps first max, like jnp.argmax)
        const float* g = gumbel + (size_t)row * TOP_K;
        float best = -3.0e38f; int bj = 0;
        for (int k = 0; k < TOP_K; ++k) {
            const float sc = (float)(-sv[k]) + g[k];
            if (sc > best) { best = sc; bj = k; }
        }
        cidx = si[bj];
        mind = (float)sv[bj];
    }
    cidx = __shfl(cidx, 0);
    mind = __shfl(mind, 0);

    const float vm = valid ? 1.0f : 0.0f;
    const float q  = cb[(size_t)cidx * EMB_DIM + lane];
    const float qv = q * vm;
    out[QST_OFF + (size_t)row * EMB_DIM + lane] = xf + (qv - xf);

    // loss term uses UNMASKED q_valid, masked by vm
    double dq = (double)q - xd;
    double l  = dq * dq * (double)vm;
#pragma unroll
    for (int off = 32; off >= 1; off >>= 1) l += __shfl_xor(l, off);

    if (lane == 0) {
        atomicAdd(lossacc, l);
        if (valid) {
            atomicAdd(&counts[cidx], 1);
            atomicAdd(nvalid, 1);
        }
        out[IDX_OFF + row]  = valid ? (float)cidx : 0.0f;
        out[MIND_OFF + row] = valid ? mind : 0.0f;
    }
}

// ---------------------------------------------------------------------------
// Kernel 3: perplexity + total loss scalars.
// ---------------------------------------------------------------------------
__global__ __launch_bounds__(256) void vq_scalars(const int* __restrict__ counts,
                                                  const int* __restrict__ nvalid,
                                                  const double* __restrict__ lossacc,
                                                  float* __restrict__ out) {
    __shared__ double red[256];
    const int tid = threadIdx.x;
    int nv_i = *nvalid;
    double nv = (double)(nv_i > 0 ? nv_i : 1);

    double h = 0.0;
    for (int k = tid; k < NUM_EMB; k += 256) {
        double p = (double)counts[k] / nv;
        h += p * log(p + 1e-10);
    }
    red[tid] = h;
    __syncthreads();
    for (int s = 128; s >= 1; s >>= 1) {
        if (tid < s) red[tid] += red[tid + s];
        __syncthreads();
    }
    if (tid == 0) {
        double H = red[0];                       // sum p*log(p+1e-10)
        double perp = exp(-H);
        double ploss = -log(perp + 1e-10);
        double lvq = (*lossacc) / (nv * (double)EMB_DIM);
        out[LOSS_OFF] = (float)(lvq + PERP_W * ploss);
        out[PERP_OFF] = (float)perp;
    }
}

// ---------------------------------------------------------------------------
extern "C" void kernel_launch(void* const* d_in, const int* in_sizes, int n_in,
                              void* d_out, int out_size, void* d_ws, size_t ws_size,
                              hipStream_t stream) {
    const float* inp    = (const float*)d_in[0];  // [16384, 64]
    const float* cb     = (const float*)d_in[1];  // [8192, 64]
    const float* gumbel = (const float*)d_in[2];  // [16384, 10]
    float* out = (float*)d_out;

    char* ws = (char*)d_ws;
    float*          e2f     = (float*)(ws + WS_E2F);
    int*            counts  = (int*)(ws + WS_COUNTS);
    double*         lossacc = (double*)(ws + WS_LOSS);
    int*            nvalid  = (int*)(ws + WS_NVALID);
    unsigned short* candw   = (unsigned short*)(ws + WS_CAND);

    vq_init<<<NUM_EMB / 256, 256, 0, stream>>>(cb, e2f, counts, nvalid, lossacc);
    vq_gemm_topk<<<dim3(N_ROWS / 256, CHUNKS), 256, 0, stream>>>(inp, cb, e2f, candw);
    vq_finalize<<<N_ROWS / 4, 256, 0, stream>>>(inp, cb, gumbel, candw, out,
                                                counts, nvalid, lossacc);
    vq_scalars<<<1, 256, 0, stream>>>(counts, nvalid, lossacc, out);
}

// Round 4
// 946.499 us; speedup vs baseline: 31.6747x; 2.3666x over previous
//
#include <hip/hip_runtime.h>
#include <hip/hip_bf16.h>

// Problem constants
#define N_ROWS   16384      // 8*2048
#define EMB_DIM  64
#define NUM_EMB  8192
#define TOP_K    10
#define PERP_W   0.01

// Pass-1: 4 chunks of 2048 codes (one per wave); within a chunk each lane-quad
// sees a disjoint quarter of every 16-code tile (512 codes); per-(lane,chunk)
// top-12 list. Union over 4 quads x 4 chunks = 192 candidates/row, provably
// containing the true top-10 (any top-10 item has <=9 better codes globally,
// so it is <=rank-10 within its lane subset; bf16 error << order-stat spacing).
#define M_CHUNK   12
#define CANDS     192

// Output layout (all float32, concatenated in return order)
#define QST_OFF   0
#define LOSS_OFF  (N_ROWS * EMB_DIM)                 // 1048576
#define IDX_OFF   (LOSS_OFF + 1)                     // 1048577
#define MIND_OFF  (IDX_OFF + N_ROWS)                 // 1064961
#define PERP_OFF  (MIND_OFF + N_ROWS)                // 1081345

// ws layout (bytes)
#define WS_E2F    0                                  // 8192 f32   (32 KB)
#define WS_E2D    32768                              // 8192 f64   (64 KB)
#define WS_COUNTS 98304                              // 8192 i32   (32 KB)
#define WS_LOSS   131072                             // 1 double
#define WS_NVALID 131080                             // 1 int
#define WS_CB16   131136                             // 8192*64 bf16 (1 MB)
#define WS_CAND   1179712                            // 16384*192 u16 (6 MB)

typedef short bf16x8 __attribute__((ext_vector_type(8)));
typedef float f32x4  __attribute__((ext_vector_type(4)));

__device__ __forceinline__ unsigned short f2bf(float f) {
    // round-to-nearest-even fp32 -> bf16 (inputs are finite gaussians)
    unsigned int u = __float_as_uint(f);
    unsigned int r = u + 0x7fffu + ((u >> 16) & 1u);
    return (unsigned short)(r >> 16);
}

// ---------------------------------------------------------------------------
// Kernel 0: prep — zero atomics, ||e||^2 in fp32 (pass-1) and fp64 (pass-2),
// codebook -> bf16. One thread per code row.
// ---------------------------------------------------------------------------
__global__ __launch_bounds__(256) void vq_prep(const float* __restrict__ cb,
                                               float* __restrict__ e2f,
                                               double* __restrict__ e2d,
                                               unsigned short* __restrict__ cb16,
                                               int* __restrict__ counts,
                                               int* __restrict__ nvalid,
                                               double* __restrict__ lossacc) {
    const int k = blockIdx.x * 256 + threadIdx.x;   // 0..8191
    counts[k] = 0;
    const float4* rp = (const float4*)(cb + (size_t)k * EMB_DIM);
    float  s  = 0.0f;
    double sd = 0.0;
#pragma unroll
    for (int i = 0; i < 16; ++i) {
        const float4 v = rp[i];
        s += v.x * v.x + v.y * v.y + v.z * v.z + v.w * v.w;
        sd += (double)v.x * (double)v.x + (double)v.y * (double)v.y
            + (double)v.z * (double)v.z + (double)v.w * (double)v.w;
        unsigned long long p =
              (unsigned long long)f2bf(v.x)
            | ((unsigned long long)f2bf(v.y) << 16)
            | ((unsigned long long)f2bf(v.z) << 32)
            | ((unsigned long long)f2bf(v.w) << 48);
        *(unsigned long long*)(cb16 + (size_t)k * EMB_DIM + 4 * i) = p;
    }
    e2f[k] = s;
    e2d[k] = sd;
    if (k == 0) { *nvalid = 0; *lossacc = 0.0; }
}

// ---------------------------------------------------------------------------
// Kernel 1: MFMA distance GEMM + per-(lane,chunk) top-12.
// Block = 256 threads = 4 waves; block owns 16 rows; wave w owns code chunk
// [w*2048, (w+1)*2048). Per 16-code tile: 2x mfma_f32_16x16x32_bf16 (K=64).
// A operand = codes (m = lane&15), B operand = rows (n = lane&15), so each
// lane's D regs are 4 codes (m = quad*4+reg) of its own row (n = lane&15).
// Score s = dot - e2/2 (x2 is row-uniform -> irrelevant for ranking).
// Per-thread top list in LDS columns [k][tid]: lane-stride-1, conflict-free,
// no barriers anywhere.
// ---------------------------------------------------------------------------
__global__ __launch_bounds__(256) void vq_gemm_topk(
        const float* __restrict__ inp, const unsigned short* __restrict__ cb16,
        const float* __restrict__ e2f, unsigned short* __restrict__ cand) {
    __shared__ float          lvs[M_CHUNK][256];
    __shared__ unsigned short lis[M_CHUNK][256];

    const int tid   = threadIdx.x;
    const int w     = tid >> 6;        // chunk
    const int lane  = tid & 63;
    const int q     = lane >> 4;       // quad: k-slice for A/B, code group for D
    const int rsub  = lane & 15;
    const int row   = blockIdx.x * 16 + rsub;
    const int cbase = w * 2048;

    float* lv = &lvs[0][0];
    unsigned short* li = &lis[0][0];

    // B fragments (this lane's row, k = q*8+j and +32), fp32 -> bf16 on the fly
    bf16x8 b0, b1;
    {
        const float* xp = inp + (size_t)row * EMB_DIM + q * 8;
#pragma unroll
        for (int j = 0; j < 8; ++j) b0[j] = (short)f2bf(xp[j]);
#pragma unroll
        for (int j = 0; j < 8; ++j) b1[j] = (short)f2bf(xp[32 + j]);
    }

    // init per-thread list (ascending by score; [0] = threshold slot)
#pragma unroll
    for (int k = 0; k < M_CHUNK; ++k) { lv[k * 256 + tid] = -3.0e38f; li[k * 256 + tid] = 0; }
    float thr = -3.0e38f;

    // prefetch tile 0 A-fragments
    bf16x8 a0, a1;
    {
        const bf16x8* ap = (const bf16x8*)(cb16 + ((size_t)(cbase + rsub) << 6) + (q << 3));
        a0 = ap[0]; a1 = ap[4];   // k 0..31 and 32..63
    }

    for (int t = 0; t < 128; ++t) {
        const int c0 = cbase + t * 16;
        const bf16x8 ca0 = a0, ca1 = a1;
        // prefetch next tile (wrap on last iter -> valid addr, result unused)
        {
            const int tn = (t + 1) & 127;
            const bf16x8* ap = (const bf16x8*)(cb16 + ((size_t)(cbase + tn * 16 + rsub) << 6) + (q << 3));
            a0 = ap[0]; a1 = ap[4];
        }

        f32x4 acc = {0.0f, 0.0f, 0.0f, 0.0f};
        acc = __builtin_amdgcn_mfma_f32_16x16x32_bf16(ca0, b0, acc, 0, 0, 0);
        acc = __builtin_amdgcn_mfma_f32_16x16x32_bf16(ca1, b1, acc, 0, 0, 0);

        const float4 e2v = *(const float4*)(e2f + c0 + (q << 2));
        const float s0 = acc[0] - 0.5f * e2v.x;
        const float s1 = acc[1] - 0.5f * e2v.y;
        const float s2 = acc[2] - 0.5f * e2v.z;
        const float s3 = acc[3] - 0.5f * e2v.w;
        const int cb0 = c0 + (q << 2);

#define CHECK(SV, II) \
        if ((SV) > thr) { \
            float s_ = (SV); int k_ = 0; \
            while (k_ + 1 < M_CHUNK && s_ > lv[(k_ + 1) * 256 + tid]) { \
                lv[k_ * 256 + tid] = lv[(k_ + 1) * 256 + tid]; \
                li[k_ * 256 + tid] = li[(k_ + 1) * 256 + tid]; \
                ++k_; \
            } \
            lv[k_ * 256 + tid] = s_; \
            li[k_ * 256 + tid] = (unsigned short)(II); \
            thr = lv[tid]; \
        }
        CHECK(s0, cb0 + 0) CHECK(s1, cb0 + 1) CHECK(s2, cb0 + 2) CHECK(s3, cb0 + 3)
#undef CHECK
    }

    // dump candidates: row-major [row][chunk][quad][k]
    unsigned short* cr = cand + (size_t)row * CANDS + w * 48 + q * 12;
#pragma unroll
    for (int k = 0; k < M_CHUNK; ++k) cr[k] = li[k * 256 + tid];
}

// ---------------------------------------------------------------------------
// Kernel 2: fp64 re-rank of 192 candidates, parallel wave-wide top-10 by
// (d, idx) via shuffle butterflies (all registers, fully unrolled), Gumbel-max
// sample, outputs + atomics. One wave per row; 4 rows per block.
// ---------------------------------------------------------------------------
__global__ __launch_bounds__(256) void vq_finalize(const float* __restrict__ inp,
                                                   const float* __restrict__ cb,
                                                   const double* __restrict__ e2d,
                                                   const float* __restrict__ gumbel,
                                                   const unsigned short* __restrict__ cand,
                                                   float* __restrict__ out,
                                                   int* __restrict__ counts,
                                                   int* __restrict__ nvalid,
                                                   double* __restrict__ lossacc) {
    __shared__ double xs[4][EMB_DIM];

    const int tid  = threadIdx.x;
    const int w    = tid >> 6;
    const int lane = tid & 63;
    const int row  = blockIdx.x * 4 + w;

    const float xf = inp[(size_t)row * EMB_DIM + lane];
    const double xd = (double)xf;
    xs[w][lane] = xd;

    // wave-wide ||x||^2 in fp64
    double x2 = xd * xd;
#pragma unroll
    for (int off = 32; off >= 1; off >>= 1) x2 += __shfl_xor(x2, off);
    const bool valid = sqrt(x2) > 1e-6;

    __syncthreads();  // publish xs

    // 3 candidates per lane: exact fp64 distances (e2 precomputed in fp64)
    double cd[3]; int ci[3];
#pragma unroll
    for (int m = 0; m < 3; ++m) {
        const int c = (int)cand[(size_t)row * CANDS + lane + 64 * m];
        const float* e = cb + (size_t)c * EMB_DIM;
        double dot = 0.0;
#pragma unroll
        for (int dq = 0; dq < 16; ++dq) {
            const float4 ev = *(const float4*)(e + 4 * dq);
            dot = fma(xs[w][4 * dq + 0], (double)ev.x, dot);
            dot = fma(xs[w][4 * dq + 1], (double)ev.y, dot);
            dot = fma(xs[w][4 * dq + 2], (double)ev.z, dot);
            dot = fma(xs[w][4 * dq + 3], (double)ev.w, dot);
        }
        cd[m] = x2 + e2d[c] - 2.0 * dot;
        ci[m] = c;
    }

    // 10 wave-wide min-extractions by (d, idx) — JAX top_k order + tie-break.
    // Candidate indices are unique (disjoint code subsets), so idx equality
    // identifies the extracted element exactly.
    double seld[TOP_K]; int seli[TOP_K];
#pragma unroll
    for (int k = 0; k < TOP_K; ++k) {
        double bd = cd[0]; int bi = ci[0];
        if (cd[1] < bd || (cd[1] == bd && ci[1] < bi)) { bd = cd[1]; bi = ci[1]; }
        if (cd[2] < bd || (cd[2] == bd && ci[2] < bi)) { bd = cd[2]; bi = ci[2]; }
#pragma unroll
        for (int off = 1; off < 64; off <<= 1) {
            const double od = __shfl_xor(bd, off);
            const int    oi = __shfl_xor(bi, off);
            if (od < bd || (od == bd && oi < bi)) { bd = od; bi = oi; }
        }
        seld[k] = bd; seli[k] = bi;   // uniform across wave
        if (ci[0] == bi) cd[0] = 1.0e300;
        if (ci[1] == bi) cd[1] = 1.0e300;
        if (ci[2] == bi) cd[2] = 1.0e300;
    }

    // Gumbel-max over top-10 (argmax keeps first max, like jnp.argmax)
    float gv = 0.0f;
    if (lane < TOP_K) gv = gumbel[(size_t)row * TOP_K + lane];
    float bestsc = -3.0e38f; double bestd = 0.0; int besti = 0;
#pragma unroll
    for (int k = 0; k < TOP_K; ++k) {
        const float gk = __shfl(gv, k);
        const float sc = (float)(-seld[k]) + gk;
        if (sc > bestsc) { bestsc = sc; bestd = seld[k]; besti = seli[k]; }
    }
    const int   cidx = besti;           // uniform
    const float mind = (float)bestd;

    const float vm = valid ? 1.0f : 0.0f;
    const float qv = cb[(size_t)cidx * EMB_DIM + lane];
    out[QST_OFF + (size_t)row * EMB_DIM + lane] = xf + (qv * vm - xf);

    // loss term uses UNMASKED q_valid, masked by vm
    const double dq = (double)qv - xd;
    double l = dq * dq * (double)vm;
#pragma unroll
    for (int off = 32; off >= 1; off >>= 1) l += __shfl_xor(l, off);

    if (lane == 0) {
        atomicAdd(lossacc, l);
        if (valid) {
            atomicAdd(&counts[cidx], 1);
            atomicAdd(nvalid, 1);
        }
        out[IDX_OFF + row]  = valid ? (float)cidx : 0.0f;
        out[MIND_OFF + row] = valid ? mind : 0.0f;
    }
}

// ---------------------------------------------------------------------------
// Kernel 3: perplexity + total loss scalars.
// ---------------------------------------------------------------------------
__global__ __launch_bounds__(256) void vq_scalars(const int* __restrict__ counts,
                                                  const int* __restrict__ nvalid,
                                                  const double* __restrict__ lossacc,
                                                  float* __restrict__ out) {
    __shared__ double red[256];
    const int tid = threadIdx.x;
    const int nv_i = *nvalid;
    const double nv = (double)(nv_i > 0 ? nv_i : 1);

    double h = 0.0;
    for (int k = tid; k < NUM_EMB; k += 256) {
        const double p = (double)counts[k] / nv;
        h += p * log(p + 1e-10);
    }
    red[tid] = h;
    __syncthreads();
    for (int s = 128; s >= 1; s >>= 1) {
        if (tid < s) red[tid] += red[tid + s];
        __syncthreads();
    }
    if (tid == 0) {
        const double H = red[0];                 // sum p*log(p+1e-10)
        const double perp = exp(-H);
        const double ploss = -log(perp + 1e-10);
        const double lvq = (*lossacc) / (nv * (double)EMB_DIM);
        out[LOSS_OFF] = (float)(lvq + PERP_W * ploss);
        out[PERP_OFF] = (float)perp;
    }
}

// ---------------------------------------------------------------------------
extern "C" void kernel_launch(void* const* d_in, const int* in_sizes, int n_in,
                              void* d_out, int out_size, void* d_ws, size_t ws_size,
                              hipStream_t stream) {
    const float* inp    = (const float*)d_in[0];  // [16384, 64]
    const float* cb     = (const float*)d_in[1];  // [8192, 64]
    const float* gumbel = (const float*)d_in[2];  // [16384, 10]
    float* out = (float*)d_out;

    char* ws = (char*)d_ws;
    float*          e2f     = (float*)(ws + WS_E2F);
    double*         e2d     = (double*)(ws + WS_E2D);
    int*            counts  = (int*)(ws + WS_COUNTS);
    double*         lossacc = (double*)(ws + WS_LOSS);
    int*            nvalid  = (int*)(ws + WS_NVALID);
    unsigned short* cb16    = (unsigned short*)(ws + WS_CB16);
    unsigned short* candw   = (unsigned short*)(ws + WS_CAND);

    vq_prep<<<NUM_EMB / 256, 256, 0, stream>>>(cb, e2f, e2d, cb16, counts, nvalid, lossacc);
    vq_gemm_topk<<<N_ROWS / 16, 256, 0, stream>>>(inp, cb16, e2f, candw);
    vq_finalize<<<N_ROWS / 4, 256, 0, stream>>>(inp, cb, e2d, gumbel, candw, out,
                                                counts, nvalid, lossacc);
    vq_scalars<<<1, 256, 0, stream>>>(counts, nvalid, lossacc, out);
}

// Round 5
// 650.800 us; speedup vs baseline: 46.0665x; 1.4544x over previous
//
#include <hip/hip_runtime.h>
#include <hip/hip_bf16.h>

// Problem constants
#define N_ROWS   16384      // 8*2048
#define EMB_DIM  64
#define NUM_EMB  8192
#define TOP_K    10
#define PERP_W   0.01

// Pass-1: 4 chunks of 2048 codes (one per wave); within a chunk each lane-quad
// owns a disjoint quarter of every 16-code tile (512 codes/lane); per-lane
// top-12 kept in REGISTERS as packed u32 = (23-bit monotone score | 9-bit
// subset-local idx). Union over 16 subsets x 12 = 192 candidates/row provably
// contains the true top-10 (<=9 global betters -> subset rank <=10; bf16 +
// 2^-14 quantization noise << order-stat spacing, margin ~10 ranks).
#define M_CHUNK   12
#define CANDS     192

// Output layout (all float32, concatenated in return order)
#define QST_OFF   0
#define LOSS_OFF  (N_ROWS * EMB_DIM)                 // 1048576
#define IDX_OFF   (LOSS_OFF + 1)                     // 1048577
#define MIND_OFF  (IDX_OFF + N_ROWS)                 // 1064961
#define PERP_OFF  (MIND_OFF + N_ROWS)                // 1081345

// ws layout (bytes)
#define WS_E2H    0                                  // 8192 f32 = -0.5*||e||^2 (32 KB)
#define WS_E2D    32768                              // 8192 f64   (64 KB)
#define WS_COUNTS 98304                              // 8192 i32   (32 KB)
#define WS_LOSS   131072                             // 1 double
#define WS_NVALID 131080                             // 1 int
#define WS_CB16   131136                             // 8192*64 bf16 (1 MB)
#define WS_CAND   1179712                            // 16384*192 u16 (6 MB)

typedef short bf16x8 __attribute__((ext_vector_type(8)));
typedef float f32x4  __attribute__((ext_vector_type(4)));

__device__ __forceinline__ unsigned short f2bf(float f) {
    // round-to-nearest-even fp32 -> bf16 (inputs are finite gaussians)
    unsigned int u = __float_as_uint(f);
    unsigned int r = u + 0x7fffu + ((u >> 16) & 1u);
    return (unsigned short)(r >> 16);
}

// ---------------------------------------------------------------------------
// Kernel 0: prep — zero atomics, -||e||^2/2 (fp32, MFMA C-init) and ||e||^2
// (fp64, pass-2), codebook -> bf16. One thread per code row.
// ---------------------------------------------------------------------------
__global__ __launch_bounds__(256) void vq_prep(const float* __restrict__ cb,
                                               float* __restrict__ e2h,
                                               double* __restrict__ e2d,
                                               unsigned short* __restrict__ cb16,
                                               int* __restrict__ counts,
                                               int* __restrict__ nvalid,
                                               double* __restrict__ lossacc) {
    const int k = blockIdx.x * 256 + threadIdx.x;   // 0..8191
    counts[k] = 0;
    const float4* rp = (const float4*)(cb + (size_t)k * EMB_DIM);
    float  s  = 0.0f;
    double sd = 0.0;
#pragma unroll
    for (int i = 0; i < 16; ++i) {
        const float4 v = rp[i];
        s += v.x * v.x + v.y * v.y + v.z * v.z + v.w * v.w;
        sd += (double)v.x * (double)v.x + (double)v.y * (double)v.y
            + (double)v.z * (double)v.z + (double)v.w * (double)v.w;
        unsigned long long p =
              (unsigned long long)f2bf(v.x)
            | ((unsigned long long)f2bf(v.y) << 16)
            | ((unsigned long long)f2bf(v.z) << 32)
            | ((unsigned long long)f2bf(v.w) << 48);
        *(unsigned long long*)(cb16 + (size_t)k * EMB_DIM + 4 * i) = p;
    }
    e2h[k] = -0.5f * s;
    e2d[k] = sd;
    if (k == 0) { *nvalid = 0; *lossacc = 0.0; }
}

// ---------------------------------------------------------------------------
// Kernel 1: MFMA distance GEMM + per-lane register top-12.
// Block = 256 = 4 waves = 16 rows; wave w owns code chunk [w*2048,(w+1)*2048).
// 32 codes (2 MFMA tiles) per iteration, 64 iterations. Accumulators are
// C-initialized with -e2/2 so score s = dot - e2/2 falls out of the MFMA.
// Selection: packed u32 (score-hi23 | idx9), sorted 12-reg list, branch-gated
// unrolled min/max bubble. Zero LDS, zero barriers.
// ---------------------------------------------------------------------------
__global__ __launch_bounds__(256) void vq_gemm_topk(
        const float* __restrict__ inp, const unsigned short* __restrict__ cb16,
        const float* __restrict__ e2h, unsigned short* __restrict__ cand) {
    const int tid   = threadIdx.x;
    const int w     = tid >> 6;        // chunk
    const int lane  = tid & 63;
    const int q     = lane >> 4;       // quad: k-slice for A/B, code subgroup for D
    const int rsub  = lane & 15;
    const int row   = blockIdx.x * 16 + rsub;
    const int cbase = w * 2048;

    // B fragments (this lane's row, k = q*8+j and +32), fp32 -> bf16
    bf16x8 b0, b1;
    {
        const float* xp = inp + (size_t)row * EMB_DIM + q * 8;
#pragma unroll
        for (int j = 0; j < 8; ++j) b0[j] = (short)f2bf(xp[j]);
#pragma unroll
        for (int j = 0; j < 8; ++j) b1[j] = (short)f2bf(xp[32 + j]);
    }

    // sorted-desc register list of packed (score|idx); l0 best, l11 worst
    unsigned l0=0,l1=0,l2=0,l3=0,l4=0,l5=0,l6=0,l7=0,l8=0,l9=0,l10=0,l11=0;

    // A / e2 base pointers (per-lane)
    const unsigned short* abase = cb16 + ((size_t)(cbase + rsub) << 6) + (q << 3);
    const float*          ebase = e2h + cbase + (q << 2);

    // prefetch iteration 0
    bf16x8 a00 = *(const bf16x8*)(abase);               // tile h=0, k 0..31 slice
    bf16x8 a01 = *(const bf16x8*)(abase + 32);          // tile h=0, k 32..63 slice
    bf16x8 a10 = *(const bf16x8*)(abase + 1024);        // tile h=1 (+16 codes)
    bf16x8 a11 = *(const bf16x8*)(abase + 1024 + 32);
    f32x4  e0  = *(const f32x4*)(ebase);
    f32x4  e1  = *(const f32x4*)(ebase + 16);

#define BUB(LK) { unsigned mx_ = (v_ > LK) ? v_ : LK; \
                  v_ = (v_ > LK) ? LK : v_; LK = mx_; }
#define PINS(SV, HR) { \
        unsigned u_ = __float_as_uint(SV); \
        unsigned key_ = (u_ & 0x80000000u) ? ~u_ : (u_ | 0x80000000u); \
        unsigned p_ = (key_ & 0xFFFFFE00u) | (tb + (HR)); \
        if (p_ > l11) { unsigned v_ = p_; \
            BUB(l0) BUB(l1) BUB(l2) BUB(l3) BUB(l4)  BUB(l5) \
            BUB(l6) BUB(l7) BUB(l8) BUB(l9) BUB(l10) BUB(l11) } }

    for (int t = 0; t < 64; ++t) {
        const bf16x8 ca00 = a00, ca01 = a01, ca10 = a10, ca11 = a11;
        const f32x4  ce0 = e0, ce1 = e1;
        // prefetch next iteration (wrap on last -> valid addr, unused)
        {
            const int tn = (t + 1) & 63;
            const unsigned short* ab = abase + (size_t)tn * 2048;
            a00 = *(const bf16x8*)(ab);
            a01 = *(const bf16x8*)(ab + 32);
            a10 = *(const bf16x8*)(ab + 1024);
            a11 = *(const bf16x8*)(ab + 1024 + 32);
            const float* eb = ebase + tn * 32;
            e0 = *(const f32x4*)(eb);
            e1 = *(const f32x4*)(eb + 16);
        }

        f32x4 acc0 = __builtin_amdgcn_mfma_f32_16x16x32_bf16(ca00, b0, ce0, 0, 0, 0);
        acc0       = __builtin_amdgcn_mfma_f32_16x16x32_bf16(ca01, b1, acc0, 0, 0, 0);
        f32x4 acc1 = __builtin_amdgcn_mfma_f32_16x16x32_bf16(ca10, b0, ce1, 0, 0, 0);
        acc1       = __builtin_amdgcn_mfma_f32_16x16x32_bf16(ca11, b1, acc1, 0, 0, 0);

        const unsigned tb = (unsigned)(t << 3);
        PINS(acc0[0], 0) PINS(acc0[1], 1) PINS(acc0[2], 2) PINS(acc0[3], 3)
        PINS(acc1[0], 4) PINS(acc1[1], 5) PINS(acc1[2], 6) PINS(acc1[3], 7)
    }
#undef PINS
#undef BUB

    // dump: decode packed -> global code id
    // code = cbase + t*32 + h*16 + q*4 + reg, tidx = (t<<3)|(h<<2)|reg
    unsigned short* cr = cand + (size_t)row * CANDS + w * 48 + q * 12;
#define DUMP(K, LK) { const unsigned t9 = (LK) & 0x1FFu; \
        cr[K] = (unsigned short)(cbase + ((t9 >> 3) << 5) + (((t9 >> 2) & 1u) << 4) \
                                 + (q << 2) + (t9 & 3u)); }
    DUMP(0, l0)  DUMP(1, l1)  DUMP(2, l2)  DUMP(3, l3)
    DUMP(4, l4)  DUMP(5, l5)  DUMP(6, l6)  DUMP(7, l7)
    DUMP(8, l8)  DUMP(9, l9)  DUMP(10, l10) DUMP(11, l11)
#undef DUMP
}

// ---------------------------------------------------------------------------
// Kernel 2: fp64 re-rank of 192 candidates (one lane-QUAD per candidate ->
// coalesced codebook reads), wave-wide top-10 by (d, idx) via shuffle
// butterflies, Gumbel-max sample, outputs + atomics. One wave per row.
// ---------------------------------------------------------------------------
__global__ __launch_bounds__(256) void vq_finalize(const float* __restrict__ inp,
                                                   const float* __restrict__ cb,
                                                   const double* __restrict__ e2d,
                                                   const float* __restrict__ gumbel,
                                                   const unsigned short* __restrict__ cand,
                                                   float* __restrict__ out,
                                                   int* __restrict__ counts,
                                                   int* __restrict__ nvalid,
                                                   double* __restrict__ lossacc) {
    __shared__ double xs[4][EMB_DIM];
    __shared__ double dvs[4][CANDS];
    __shared__ int    dis[4][CANDS];

    const int tid  = threadIdx.x;
    const int w    = tid >> 6;
    const int lane = tid & 63;
    const int row  = blockIdx.x * 4 + w;

    const float xf = inp[(size_t)row * EMB_DIM + lane];
    const double xd = (double)xf;
    xs[w][lane] = xd;

    // wave-wide ||x||^2 in fp64
    double x2 = xd * xd;
#pragma unroll
    for (int off = 32; off >= 1; off >>= 1) x2 += __shfl_xor(x2, off);
    const bool valid = sqrt(x2) > 1e-6;

    __syncthreads();  // publish xs

    // 12 rounds x 16 quads: quad g handles candidate j = r*16+g; lane-quarter
    // lq covers 16 contiguous dims (coalesced 64B per quad).
    const int g  = lane >> 2;
    const int lq = lane & 3;
    const double* xq = &xs[w][lq << 4];
#pragma unroll
    for (int r = 0; r < 12; ++r) {
        const int j = r * 16 + g;
        const int c = (int)cand[(size_t)row * CANDS + j];
        const float4* ep = (const float4*)(cb + ((size_t)c << 6) + (lq << 4));
        double dot = 0.0;
#pragma unroll
        for (int i = 0; i < 4; ++i) {
            const float4 ev = ep[i];
            dot = fma(xq[4 * i + 0], (double)ev.x, dot);
            dot = fma(xq[4 * i + 1], (double)ev.y, dot);
            dot = fma(xq[4 * i + 2], (double)ev.z, dot);
            dot = fma(xq[4 * i + 3], (double)ev.w, dot);
        }
        dot += __shfl_xor(dot, 1);
        dot += __shfl_xor(dot, 2);
        if (lq == 0) { dvs[w][j] = x2 + e2d[c] - 2.0 * dot; dis[w][j] = c; }
    }
    __syncthreads();

    // 3 candidates per lane; 10 wave-wide min-extractions by (d, idx).
    double cd[3]; int ci[3];
#pragma unroll
    for (int m = 0; m < 3; ++m) { cd[m] = dvs[w][lane + 64 * m]; ci[m] = dis[w][lane + 64 * m]; }

    double seld[TOP_K]; int seli[TOP_K];
#pragma unroll
    for (int k = 0; k < TOP_K; ++k) {
        double bd = cd[0]; int bi = ci[0];
        if (cd[1] < bd || (cd[1] == bd && ci[1] < bi)) { bd = cd[1]; bi = ci[1]; }
        if (cd[2] < bd || (cd[2] == bd && ci[2] < bi)) { bd = cd[2]; bi = ci[2]; }
#pragma unroll
        for (int off = 1; off < 64; off <<= 1) {
            const double od = __shfl_xor(bd, off);
            const int    oi = __shfl_xor(bi, off);
            if (od < bd || (od == bd && oi < bi)) { bd = od; bi = oi; }
        }
        seld[k] = bd; seli[k] = bi;   // uniform across wave
        if (ci[0] == bi) cd[0] = 1.0e300;
        if (ci[1] == bi) cd[1] = 1.0e300;
        if (ci[2] == bi) cd[2] = 1.0e300;
    }

    // Gumbel-max over top-10 (argmax keeps first max, like jnp.argmax)
    float gv = 0.0f;
    if (lane < TOP_K) gv = gumbel[(size_t)row * TOP_K + lane];
    float bestsc = -3.0e38f; double bestd = 0.0; int besti = 0;
#pragma unroll
    for (int k = 0; k < TOP_K; ++k) {
        const float gk = __shfl(gv, k);
        const float sc = (float)(-seld[k]) + gk;
        if (sc > bestsc) { bestsc = sc; bestd = seld[k]; besti = seli[k]; }
    }
    const int   cidx = besti;           // uniform
    const float mind = (float)bestd;

    const float vm = valid ? 1.0f : 0.0f;
    const float qv = cb[(size_t)cidx * EMB_DIM + lane];
    out[QST_OFF + (size_t)row * EMB_DIM + lane] = xf + (qv * vm - xf);

    // loss term uses UNMASKED q_valid, masked by vm
    const double dq = (double)qv - xd;
    double l = dq * dq * (double)vm;
#pragma unroll
    for (int off = 32; off >= 1; off >>= 1) l += __shfl_xor(l, off);

    if (lane == 0) {
        atomicAdd(lossacc, l);
        if (valid) {
            atomicAdd(&counts[cidx], 1);
            atomicAdd(nvalid, 1);
        }
        out[IDX_OFF + row]  = valid ? (float)cidx : 0.0f;
        out[MIND_OFF + row] = valid ? mind : 0.0f;
    }
}

// ---------------------------------------------------------------------------
// Kernel 3: perplexity + total loss scalars.
// ---------------------------------------------------------------------------
__global__ __launch_bounds__(256) void vq_scalars(const int* __restrict__ counts,
                                                  const int* __restrict__ nvalid,
                                                  const double* __restrict__ lossacc,
                                                  float* __restrict__ out) {
    __shared__ double red[256];
    const int tid = threadIdx.x;
    const int nv_i = *nvalid;
    const double nv = (double)(nv_i > 0 ? nv_i : 1);

    double h = 0.0;
    for (int k = tid; k < NUM_EMB; k += 256) {
        const double p = (double)counts[k] / nv;
        h += p * log(p + 1e-10);
    }
    red[tid] = h;
    __syncthreads();
    for (int s = 128; s >= 1; s >>= 1) {
        if (tid < s) red[tid] += red[tid + s];
        __syncthreads();
    }
    if (tid == 0) {
        const double H = red[0];                 // sum p*log(p+1e-10)
        const double perp = exp(-H);
        const double ploss = -log(perp + 1e-10);
        const double lvq = (*lossacc) / (nv * (double)EMB_DIM);
        out[LOSS_OFF] = (float)(lvq + PERP_W * ploss);
        out[PERP_OFF] = (float)perp;
    }
}

// ---------------------------------------------------------------------------
extern "C" void kernel_launch(void* const* d_in, const int* in_sizes, int n_in,
                              void* d_out, int out_size, void* d_ws, size_t ws_size,
                              hipStream_t stream) {
    const float* inp    = (const float*)d_in[0];  // [16384, 64]
    const float* cb     = (const float*)d_in[1];  // [8192, 64]
    const float* gumbel = (const float*)d_in[2];  // [16384, 10]
    float* out = (float*)d_out;

    char* ws = (char*)d_ws;
    float*          e2h     = (float*)(ws + WS_E2H);
    double*         e2d     = (double*)(ws + WS_E2D);
    int*            counts  = (int*)(ws + WS_COUNTS);
    double*         lossacc = (double*)(ws + WS_LOSS);
    int*            nvalid  = (int*)(ws + WS_NVALID);
    unsigned short* cb16    = (unsigned short*)(ws + WS_CB16);
    unsigned short* candw   = (unsigned short*)(ws + WS_CAND);

    vq_prep<<<NUM_EMB / 256, 256, 0, stream>>>(cb, e2h, e2d, cb16, counts, nvalid, lossacc);
    vq_gemm_topk<<<N_ROWS / 16, 256, 0, stream>>>(inp, cb16, e2h, candw);
    vq_finalize<<<N_ROWS / 4, 256, 0, stream>>>(inp, cb, e2d, gumbel, candw, out,
                                                counts, nvalid, lossacc);
    vq_scalars<<<1, 256, 0, stream>>>(counts, nvalid, lossacc, out);
}

// Round 6
// 635.137 us; speedup vs baseline: 47.2024x; 1.0247x over previous
//
#include <hip/hip_runtime.h>
#include <hip/hip_bf16.h>

// Problem constants
#define N_ROWS   16384      // 8*2048
#define EMB_DIM  64
#define NUM_EMB  8192
#define TOP_K    10
#define PERP_W   0.01

// Pass-1: 4 chunks of 2048 codes (one per wave); within a chunk each lane-quad
// owns a disjoint quarter of every 16-code tile (512 codes/lane); per-lane
// top-12 kept in REGISTERS as packed u32 = (23-bit monotone score | 9-bit
// subset-local idx). Union over 16 subsets x 12 = 192 candidates/row provably
// contains the true top-10 (<=9 global betters -> subset rank <=10; bf16 +
// 2^-14 quantization noise << order-stat spacing, margin ~2 ranks).
#define M_CHUNK   12
#define CANDS     192

// Output layout (all float32, concatenated in return order)
#define QST_OFF   0
#define LOSS_OFF  (N_ROWS * EMB_DIM)                 // 1048576
#define IDX_OFF   (LOSS_OFF + 1)                     // 1048577
#define MIND_OFF  (IDX_OFF + N_ROWS)                 // 1064961
#define PERP_OFF  (MIND_OFF + N_ROWS)                // 1081345

// ws layout (bytes)
#define WS_E2H    0                                  // 8192 f32 = -0.5*||e||^2 (32 KB)
#define WS_E2D    32768                              // 8192 f64   (64 KB)
#define WS_COUNTS 98304                              // 8192 i32   (32 KB)
#define WS_LOSS   131072                             // 1 double
#define WS_NVALID 131080                             // 1 int
#define WS_CB16   131136                             // 8192*64 bf16 (1 MB)
#define WS_CAND   1179712                            // 16384*192 u16 (6 MB)

typedef short bf16x8 __attribute__((ext_vector_type(8)));
typedef float f32x4  __attribute__((ext_vector_type(4)));

__device__ __forceinline__ unsigned short f2bf(float f) {
    // round-to-nearest-even fp32 -> bf16 (inputs are finite gaussians)
    unsigned int u = __float_as_uint(f);
    unsigned int r = u + 0x7fffu + ((u >> 16) & 1u);
    return (unsigned short)(r >> 16);
}

// ---------------------------------------------------------------------------
// Kernel 0: prep — zero atomics, -||e||^2/2 (fp32, MFMA C-init) and ||e||^2
// (fp64, pass-2), codebook -> bf16. One thread per code row.
// ---------------------------------------------------------------------------
__global__ __launch_bounds__(256) void vq_prep(const float* __restrict__ cb,
                                               float* __restrict__ e2h,
                                               double* __restrict__ e2d,
                                               unsigned short* __restrict__ cb16,
                                               int* __restrict__ counts,
                                               int* __restrict__ nvalid,
                                               double* __restrict__ lossacc) {
    const int k = blockIdx.x * 256 + threadIdx.x;   // 0..8191
    counts[k] = 0;
    const float4* rp = (const float4*)(cb + (size_t)k * EMB_DIM);
    float  s  = 0.0f;
    double sd = 0.0;
#pragma unroll
    for (int i = 0; i < 16; ++i) {
        const float4 v = rp[i];
        s += v.x * v.x + v.y * v.y + v.z * v.z + v.w * v.w;
        sd += (double)v.x * (double)v.x + (double)v.y * (double)v.y
            + (double)v.z * (double)v.z + (double)v.w * (double)v.w;
        unsigned long long p =
              (unsigned long long)f2bf(v.x)
            | ((unsigned long long)f2bf(v.y) << 16)
            | ((unsigned long long)f2bf(v.z) << 32)
            | ((unsigned long long)f2bf(v.w) << 48);
        *(unsigned long long*)(cb16 + (size_t)k * EMB_DIM + 4 * i) = p;
    }
    e2h[k] = -0.5f * s;
    e2d[k] = sd;
    if (k == 0) { *nvalid = 0; *lossacc = 0.0; }
}

// ---------------------------------------------------------------------------
// Kernel 1: MFMA distance GEMM + per-lane register top-12.
// Block = 256 = 4 waves = 16 rows; wave w owns code chunk [w*2048,(w+1)*2048).
// 32 codes (2 MFMA tiles) per sub-iter; unrolled by 2 with prefetch distance
// 2 (two register buffer sets) so loads are issued ~400+ cycles before use.
// Accumulators C-initialized with -e2/2 so score s = dot - e2/2 is free.
// Selection: packed u32 (score-hi23 | idx9), sorted 12-reg list, branch-gated
// unrolled min/max bubble. Zero LDS, zero barriers.
// ---------------------------------------------------------------------------
__global__ __launch_bounds__(256) void vq_gemm_topk(
        const float* __restrict__ inp, const unsigned short* __restrict__ cb16,
        const float* __restrict__ e2h, unsigned short* __restrict__ cand) {
    const int tid   = threadIdx.x;
    const int w     = tid >> 6;        // chunk
    const int lane  = tid & 63;
    const int q     = lane >> 4;       // quad: k-slice for A/B, code subgroup for D
    const int rsub  = lane & 15;
    const int row   = blockIdx.x * 16 + rsub;
    const int cbase = w * 2048;

    // B fragments (this lane's row, k = q*8+j and +32), fp32 -> bf16
    bf16x8 b0, b1;
    {
        const float* xp = inp + (size_t)row * EMB_DIM + q * 8;
#pragma unroll
        for (int j = 0; j < 8; ++j) b0[j] = (short)f2bf(xp[j]);
#pragma unroll
        for (int j = 0; j < 8; ++j) b1[j] = (short)f2bf(xp[32 + j]);
    }

    // sorted-desc register list of packed (score|idx); l0 best, l11 worst
    unsigned l0=0,l1=0,l2=0,l3=0,l4=0,l5=0,l6=0,l7=0,l8=0,l9=0,l10=0,l11=0;

    // A / e2 base pointers (per-lane)
    const unsigned short* abase = cb16 + ((size_t)(cbase + rsub) << 6) + (q << 3);
    const float*          ebase = e2h + cbase + (q << 2);

#define LOADP(P0,P1,P2,P3,E0,E1,TT) { \
        const unsigned short* ab_ = abase + (size_t)(TT) * 2048; \
        P0 = *(const bf16x8*)(ab_); \
        P1 = *(const bf16x8*)(ab_ + 32); \
        P2 = *(const bf16x8*)(ab_ + 1024); \
        P3 = *(const bf16x8*)(ab_ + 1024 + 32); \
        const float* eb_ = ebase + (TT) * 32; \
        E0 = *(const f32x4*)(eb_); \
        E1 = *(const f32x4*)(eb_ + 16); }

    bf16x8 A00, A01, A10, A11, B00, B01, B10, B11;
    f32x4  Ae0, Ae1, Be0, Be1;
    LOADP(A00, A01, A10, A11, Ae0, Ae1, 0)
    LOADP(B00, B01, B10, B11, Be0, Be1, 1)

#define BUB(LK) { unsigned mx_ = (v_ > LK) ? v_ : LK; \
                  v_ = (v_ > LK) ? LK : v_; LK = mx_; }
#define PINS(SV, HR, TB) { \
        unsigned u_ = __float_as_uint(SV); \
        unsigned key_ = (u_ & 0x80000000u) ? ~u_ : (u_ | 0x80000000u); \
        unsigned p_ = (key_ & 0xFFFFFE00u) | ((TB) + (HR)); \
        if (p_ > l11) { unsigned v_ = p_; \
            BUB(l0) BUB(l1) BUB(l2) BUB(l3) BUB(l4)  BUB(l5) \
            BUB(l6) BUB(l7) BUB(l8) BUB(l9) BUB(l10) BUB(l11) } }

#define SUBITER(P0,P1,P2,P3,E0,E1,TT,TP) { \
        const bf16x8 c00_ = P0, c01_ = P1, c10_ = P2, c11_ = P3; \
        const f32x4  ce0_ = E0, ce1_ = E1; \
        LOADP(P0, P1, P2, P3, E0, E1, (TP) & 63) \
        f32x4 acc0_ = __builtin_amdgcn_mfma_f32_16x16x32_bf16(c00_, b0, ce0_, 0, 0, 0); \
        acc0_       = __builtin_amdgcn_mfma_f32_16x16x32_bf16(c01_, b1, acc0_, 0, 0, 0); \
        f32x4 acc1_ = __builtin_amdgcn_mfma_f32_16x16x32_bf16(c10_, b0, ce1_, 0, 0, 0); \
        acc1_       = __builtin_amdgcn_mfma_f32_16x16x32_bf16(c11_, b1, acc1_, 0, 0, 0); \
        const unsigned tb_ = (unsigned)((TT) << 3); \
        PINS(acc0_[0], 0, tb_) PINS(acc0_[1], 1, tb_) \
        PINS(acc0_[2], 2, tb_) PINS(acc0_[3], 3, tb_) \
        PINS(acc1_[0], 4, tb_) PINS(acc1_[1], 5, tb_) \
        PINS(acc1_[2], 6, tb_) PINS(acc1_[3], 7, tb_) }

    for (int t = 0; t < 64; t += 2) {
        SUBITER(A00, A01, A10, A11, Ae0, Ae1, t,     t + 2)
        SUBITER(B00, B01, B10, B11, Be0, Be1, t + 1, t + 3)
    }
#undef SUBITER
#undef PINS
#undef BUB
#undef LOADP

    // dump: decode packed -> global code id
    // code = cbase + t*32 + h*16 + q*4 + reg, tidx = (t<<3)|(h<<2)|reg
    unsigned short* cr = cand + (size_t)row * CANDS + w * 48 + q * 12;
#define DUMP(K, LK) { const unsigned t9 = (LK) & 0x1FFu; \
        cr[K] = (unsigned short)(cbase + ((t9 >> 3) << 5) + (((t9 >> 2) & 1u) << 4) \
                                 + (q << 2) + (t9 & 3u)); }
    DUMP(0, l0)  DUMP(1, l1)  DUMP(2, l2)  DUMP(3, l3)
    DUMP(4, l4)  DUMP(5, l5)  DUMP(6, l6)  DUMP(7, l7)
    DUMP(8, l8)  DUMP(9, l9)  DUMP(10, l10) DUMP(11, l11)
#undef DUMP
}

// ---------------------------------------------------------------------------
// Kernel 2: fp64 re-rank of 192 candidates. One lane-QUAD per candidate
// (coalesced 64B codebook reads); candidate ids hoisted (12 independent
// loads); gathers software-pipelined 3 deep; lane's 16-dim fp64 x-slice in
// registers (no LDS in the dot). Then wave-wide top-10 by (d, idx) via
// shuffle butterflies, Gumbel-max sample, outputs + atomics. 1 wave per row.
// ---------------------------------------------------------------------------
__global__ __launch_bounds__(256) void vq_finalize(const float* __restrict__ inp,
                                                   const float* __restrict__ cb,
                                                   const double* __restrict__ e2d,
                                                   const float* __restrict__ gumbel,
                                                   const unsigned short* __restrict__ cand,
                                                   float* __restrict__ out,
                                                   int* __restrict__ counts,
                                                   int* __restrict__ nvalid,
                                                   double* __restrict__ lossacc) {
    __shared__ double dvs[4][CANDS];
    __shared__ int    dis[4][CANDS];

    const int tid  = threadIdx.x;
    const int w    = tid >> 6;
    const int lane = tid & 63;
    const int row  = blockIdx.x * 4 + w;
    const int g    = lane >> 2;   // quad id 0..15
    const int lq   = lane & 3;    // quarter within quad

    const float xf = inp[(size_t)row * EMB_DIM + lane];
    const double xd = (double)xf;

    // wave-wide ||x||^2 in fp64
    double x2 = xd * xd;
#pragma unroll
    for (int off = 32; off >= 1; off >>= 1) x2 += __shfl_xor(x2, off);
    const bool valid = sqrt(x2) > 1e-6;

    // lane's fp64 x-slice: dims [lq*16, lq*16+16) in registers
    double xq[16];
    {
        const float4* xp = (const float4*)(inp + (size_t)row * EMB_DIM + (lq << 4));
#pragma unroll
        for (int i = 0; i < 4; ++i) {
            const float4 v = xp[i];
            xq[4 * i + 0] = (double)v.x; xq[4 * i + 1] = (double)v.y;
            xq[4 * i + 2] = (double)v.z; xq[4 * i + 3] = (double)v.w;
        }
    }

    // hoisted candidate ids for this lane's quad (12 independent loads)
    int cid[12];
    {
        const unsigned short* crow = cand + (size_t)row * CANDS;
#pragma unroll
        for (int r = 0; r < 12; ++r) cid[r] = (int)crow[16 * r + g];
    }

    // software-pipelined gathers, depth 3 (buffers A,B,C rotate)
    float4 gA0, gA1, gA2, gA3, gB0, gB1, gB2, gB3, gC0, gC1, gC2, gC3;
#define GLOAD(S0,S1,S2,S3, R) { \
        const float4* ep_ = (const float4*)(cb + ((size_t)cid[R] << 6) + (lq << 4)); \
        S0 = ep_[0]; S1 = ep_[1]; S2 = ep_[2]; S3 = ep_[3]; }
    GLOAD(gA0,gA1,gA2,gA3, 0)
    GLOAD(gB0,gB1,gB2,gB3, 1)
    GLOAD(gC0,gC1,gC2,gC3, 2)

#define ROUND(R, S0,S1,S2,S3, PR) { \
        const float4 v0_ = S0, v1_ = S1, v2_ = S2, v3_ = S3; \
        if ((PR) < 12) { GLOAD(S0,S1,S2,S3, PR) } \
        double d0_ = 0.0, d1_ = 0.0; \
        d0_ = fma(xq[0],  (double)v0_.x, d0_); d0_ = fma(xq[1],  (double)v0_.y, d0_); \
        d0_ = fma(xq[2],  (double)v0_.z, d0_); d0_ = fma(xq[3],  (double)v0_.w, d0_); \
        d0_ = fma(xq[4],  (double)v1_.x, d0_); d0_ = fma(xq[5],  (double)v1_.y, d0_); \
        d0_ = fma(xq[6],  (double)v1_.z, d0_); d0_ = fma(xq[7],  (double)v1_.w, d0_); \
        d1_ = fma(xq[8],  (double)v2_.x, d1_); d1_ = fma(xq[9],  (double)v2_.y, d1_); \
        d1_ = fma(xq[10], (double)v2_.z, d1_); d1_ = fma(xq[11], (double)v2_.w, d1_); \
        d1_ = fma(xq[12], (double)v3_.x, d1_); d1_ = fma(xq[13], (double)v3_.y, d1_); \
        d1_ = fma(xq[14], (double)v3_.z, d1_); d1_ = fma(xq[15], (double)v3_.w, d1_); \
        double dot_ = d0_ + d1_; \
        dot_ += __shfl_xor(dot_, 1); \
        dot_ += __shfl_xor(dot_, 2); \
        if (lq == 0) { \
            dvs[w][16 * (R) + g] = x2 + e2d[cid[R]] - 2.0 * dot_; \
            dis[w][16 * (R) + g] = cid[R]; \
        } }

    ROUND(0,  gA0,gA1,gA2,gA3, 3)
    ROUND(1,  gB0,gB1,gB2,gB3, 4)
    ROUND(2,  gC0,gC1,gC2,gC3, 5)
    ROUND(3,  gA0,gA1,gA2,gA3, 6)
    ROUND(4,  gB0,gB1,gB2,gB3, 7)
    ROUND(5,  gC0,gC1,gC2,gC3, 8)
    ROUND(6,  gA0,gA1,gA2,gA3, 9)
    ROUND(7,  gB0,gB1,gB2,gB3, 10)
    ROUND(8,  gC0,gC1,gC2,gC3, 11)
    ROUND(9,  gA0,gA1,gA2,gA3, 12)
    ROUND(10, gB0,gB1,gB2,gB3, 12)
    ROUND(11, gC0,gC1,gC2,gC3, 12)
#undef ROUND
#undef GLOAD
    __syncthreads();

    // 3 candidates per lane; 10 wave-wide min-extractions by (d, idx).
    double cd[3]; int ci[3];
#pragma unroll
    for (int m = 0; m < 3; ++m) { cd[m] = dvs[w][lane + 64 * m]; ci[m] = dis[w][lane + 64 * m]; }

    double seld[TOP_K]; int seli[TOP_K];
#pragma unroll
    for (int k = 0; k < TOP_K; ++k) {
        double bd = cd[0]; int bi = ci[0];
        if (cd[1] < bd || (cd[1] == bd && ci[1] < bi)) { bd = cd[1]; bi = ci[1]; }
        if (cd[2] < bd || (cd[2] == bd && ci[2] < bi)) { bd = cd[2]; bi = ci[2]; }
#pragma unroll
        for (int off = 1; off < 64; off <<= 1) {
            const double od = __shfl_xor(bd, off);
            const int    oi = __shfl_xor(bi, off);
            if (od < bd || (od == bd && oi < bi)) { bd = od; bi = oi; }
        }
        seld[k] = bd; seli[k] = bi;   // uniform across wave
        if (ci[0] == bi) cd[0] = 1.0e300;
        if (ci[1] == bi) cd[1] = 1.0e300;
        if (ci[2] == bi) cd[2] = 1.0e300;
    }

    // Gumbel-max over top-10 (argmax keeps first max, like jnp.argmax)
    float gv = 0.0f;
    if (lane < TOP_K) gv = gumbel[(size_t)row * TOP_K + lane];
    float bestsc = -3.0e38f; double bestd = 0.0; int besti = 0;
#pragma unroll
    for (int k = 0; k < TOP_K; ++k) {
        const float gk = __shfl(gv, k);
        const float sc = (float)(-seld[k]) + gk;
        if (sc > bestsc) { bestsc = sc; bestd = seld[k]; besti = seli[k]; }
    }
    const int   cidx = besti;           // uniform
    const float mind = (float)bestd;

    const float vm = valid ? 1.0f : 0.0f;
    const float qv = cb[(size_t)cidx * EMB_DIM + lane];
    out[QST_OFF + (size_t)row * EMB_DIM + lane] = xf + (qv * vm - xf);

    // loss term uses UNMASKED q_valid, masked by vm
    const double dq = (double)qv - xd;
    double l = dq * dq * (double)vm;
#pragma unroll
    for (int off = 32; off >= 1; off >>= 1) l += __shfl_xor(l, off);

    if (lane == 0) {
        atomicAdd(lossacc, l);
        if (valid) {
            atomicAdd(&counts[cidx], 1);
            atomicAdd(nvalid, 1);
        }
        out[IDX_OFF + row]  = valid ? (float)cidx : 0.0f;
        out[MIND_OFF + row] = valid ? mind : 0.0f;
    }
}

// ---------------------------------------------------------------------------
// Kernel 3: perplexity + total loss scalars.
// ---------------------------------------------------------------------------
__global__ __launch_bounds__(256) void vq_scalars(const int* __restrict__ counts,
                                                  const int* __restrict__ nvalid,
                                                  const double* __restrict__ lossacc,
                                                  float* __restrict__ out) {
    __shared__ double red[256];
    const int tid = threadIdx.x;
    const int nv_i = *nvalid;
    const double nv = (double)(nv_i > 0 ? nv_i : 1);

    double h = 0.0;
    for (int k = tid; k < NUM_EMB; k += 256) {
        const double p = (double)counts[k] / nv;
        h += p * log(p + 1e-10);
    }
    red[tid] = h;
    __syncthreads();
    for (int s = 128; s >= 1; s >>= 1) {
        if (tid < s) red[tid] += red[tid + s];
        __syncthreads();
    }
    if (tid == 0) {
        const double H = red[0];                 // sum p*log(p+1e-10)
        const double perp = exp(-H);
        const double ploss = -log(perp + 1e-10);
        const double lvq = (*lossacc) / (nv * (double)EMB_DIM);
        out[LOSS_OFF] = (float)(lvq + PERP_W * ploss);
        out[PERP_OFF] = (float)perp;
    }
}

// ---------------------------------------------------------------------------
extern "C" void kernel_launch(void* const* d_in, const int* in_sizes, int n_in,
                              void* d_out, int out_size, void* d_ws, size_t ws_size,
                              hipStream_t stream) {
    const float* inp    = (const float*)d_in[0];  // [16384, 64]
    const float* cb     = (const float*)d_in[1];  // [8192, 64]
    const float* gumbel = (const float*)d_in[2];  // [16384, 10]
    float* out = (float*)d_out;

    char* ws = (char*)d_ws;
    float*          e2h     = (float*)(ws + WS_E2H);
    double*         e2d     = (double*)(ws + WS_E2D);
    int*            counts  = (int*)(ws + WS_COUNTS);
    double*         lossacc = (double*)(ws + WS_LOSS);
    int*            nvalid  = (int*)(ws + WS_NVALID);
    unsigned short* cb16    = (unsigned short*)(ws + WS_CB16);
    unsigned short* candw   = (unsigned short*)(ws + WS_CAND);

    vq_prep<<<NUM_EMB / 256, 256, 0, stream>>>(cb, e2h, e2d, cb16, counts, nvalid, lossacc);
    vq_gemm_topk<<<N_ROWS / 16, 256, 0, stream>>>(inp, cb16, e2h, candw);
    vq_finalize<<<N_ROWS / 4, 256, 0, stream>>>(inp, cb, e2d, gumbel, candw, out,
                                                counts, nvalid, lossacc);
    vq_scalars<<<1, 256, 0, stream>>>(counts, nvalid, lossacc, out);
}

// Round 7
// 347.066 us; speedup vs baseline: 86.3813x; 1.8300x over previous
//
#include <hip/hip_runtime.h>
#include <hip/hip_bf16.h>

// Problem constants
#define N_ROWS   16384      // 8*2048
#define EMB_DIM  64
#define NUM_EMB  8192
#define TOP_K    10
#define PERP_W   0.01

// Pass-1: 4 chunks of 2048 codes (one per wave); within a chunk each lane-quad
// owns a disjoint quarter of every 16-code tile (512 codes/lane); per-lane
// top-12 kept in REGISTERS as packed u32 = (23-bit monotone score | 9-bit
// subset-local idx). Union over 16 subsets x 12 = 192 candidates/row provably
// contains the true top-10 (<=9 global betters -> subset rank <=10; bf16 +
// 2^-14 quantization noise << order-stat spacing, margin ~2 ranks).
#define M_CHUNK   12
#define CANDS     192

// Output layout (all float32, concatenated in return order)
#define QST_OFF   0
#define LOSS_OFF  (N_ROWS * EMB_DIM)                 // 1048576
#define IDX_OFF   (LOSS_OFF + 1)                     // 1048577
#define MIND_OFF  (IDX_OFF + N_ROWS)                 // 1064961
#define PERP_OFF  (MIND_OFF + N_ROWS)                // 1081345

// ws layout (bytes) — NO global atomics anywhere; per-row partials instead.
#define WS_E2H     0                                 // 8192 f32 = -0.5*||e||^2 (32 KB)
#define WS_E2D     32768                              // 8192 f64   (64 KB)
#define WS_CB16    98304                              // 8192*64 bf16 (1 MB)
#define WS_ROWLOSS 1146880                            // 16384 f64  (128 KB)
#define WS_ROWIDX  1277952                            // 16384 i32  (64 KB)
#define WS_ROWVAL  1343488                            // 16384 i32  (64 KB)
#define WS_CAND    1409024                            // 16384*192 u16 (6 MB)

typedef short bf16x8 __attribute__((ext_vector_type(8)));
typedef float f32x4  __attribute__((ext_vector_type(4)));

__device__ __forceinline__ unsigned short f2bf(float f) {
    // round-to-nearest-even fp32 -> bf16 (inputs are finite gaussians)
    unsigned int u = __float_as_uint(f);
    unsigned int r = u + 0x7fffu + ((u >> 16) & 1u);
    return (unsigned short)(r >> 16);
}

// ---------------------------------------------------------------------------
// Kernel 0: prep — -||e||^2/2 (fp32, MFMA C-init), ||e||^2 (fp64, pass-2),
// codebook -> bf16. One thread per code row.
// ---------------------------------------------------------------------------
__global__ __launch_bounds__(256) void vq_prep(const float* __restrict__ cb,
                                               float* __restrict__ e2h,
                                               double* __restrict__ e2d,
                                               unsigned short* __restrict__ cb16) {
    const int k = blockIdx.x * 256 + threadIdx.x;   // 0..8191
    const float4* rp = (const float4*)(cb + (size_t)k * EMB_DIM);
    float  s  = 0.0f;
    double sd = 0.0;
#pragma unroll
    for (int i = 0; i < 16; ++i) {
        const float4 v = rp[i];
        s += v.x * v.x + v.y * v.y + v.z * v.z + v.w * v.w;
        sd += (double)v.x * (double)v.x + (double)v.y * (double)v.y
            + (double)v.z * (double)v.z + (double)v.w * (double)v.w;
        unsigned long long p =
              (unsigned long long)f2bf(v.x)
            | ((unsigned long long)f2bf(v.y) << 16)
            | ((unsigned long long)f2bf(v.z) << 32)
            | ((unsigned long long)f2bf(v.w) << 48);
        *(unsigned long long*)(cb16 + (size_t)k * EMB_DIM + 4 * i) = p;
    }
    e2h[k] = -0.5f * s;
    e2d[k] = sd;
}

// ---------------------------------------------------------------------------
// Kernel 1: MFMA distance GEMM + per-lane register top-12.
// Block = 256 = 4 waves = 16 rows; wave w owns code chunk [w*2048,(w+1)*2048).
// 32 codes (2 MFMA tiles) per sub-iter; unrolled by 2 with prefetch distance
// 2. Accumulators C-initialized with -e2/2 so score s = dot - e2/2 is free.
// Selection: packed u32 (score-hi23 | idx9), sorted 12-reg list, branch-gated
// unrolled min/max bubble. Zero LDS, zero barriers. (unchanged from r6)
// ---------------------------------------------------------------------------
__global__ __launch_bounds__(256) void vq_gemm_topk(
        const float* __restrict__ inp, const unsigned short* __restrict__ cb16,
        const float* __restrict__ e2h, unsigned short* __restrict__ cand) {
    const int tid   = threadIdx.x;
    const int w     = tid >> 6;        // chunk
    const int lane  = tid & 63;
    const int q     = lane >> 4;       // quad: k-slice for A/B, code subgroup for D
    const int rsub  = lane & 15;
    const int row   = blockIdx.x * 16 + rsub;
    const int cbase = w * 2048;

    // B fragments (this lane's row, k = q*8+j and +32), fp32 -> bf16
    bf16x8 b0, b1;
    {
        const float* xp = inp + (size_t)row * EMB_DIM + q * 8;
#pragma unroll
        for (int j = 0; j < 8; ++j) b0[j] = (short)f2bf(xp[j]);
#pragma unroll
        for (int j = 0; j < 8; ++j) b1[j] = (short)f2bf(xp[32 + j]);
    }

    // sorted-desc register list of packed (score|idx); l0 best, l11 worst
    unsigned l0=0,l1=0,l2=0,l3=0,l4=0,l5=0,l6=0,l7=0,l8=0,l9=0,l10=0,l11=0;

    // A / e2 base pointers (per-lane)
    const unsigned short* abase = cb16 + ((size_t)(cbase + rsub) << 6) + (q << 3);
    const float*          ebase = e2h + cbase + (q << 2);

#define LOADP(P0,P1,P2,P3,E0,E1,TT) { \
        const unsigned short* ab_ = abase + (size_t)(TT) * 2048; \
        P0 = *(const bf16x8*)(ab_); \
        P1 = *(const bf16x8*)(ab_ + 32); \
        P2 = *(const bf16x8*)(ab_ + 1024); \
        P3 = *(const bf16x8*)(ab_ + 1024 + 32); \
        const float* eb_ = ebase + (TT) * 32; \
        E0 = *(const f32x4*)(eb_); \
        E1 = *(const f32x4*)(eb_ + 16); }

    bf16x8 A00, A01, A10, A11, B00, B01, B10, B11;
    f32x4  Ae0, Ae1, Be0, Be1;
    LOADP(A00, A01, A10, A11, Ae0, Ae1, 0)
    LOADP(B00, B01, B10, B11, Be0, Be1, 1)

#define BUB(LK) { unsigned mx_ = (v_ > LK) ? v_ : LK; \
                  v_ = (v_ > LK) ? LK : v_; LK = mx_; }
#define PINS(SV, HR, TB) { \
        unsigned u_ = __float_as_uint(SV); \
        unsigned key_ = (u_ & 0x80000000u) ? ~u_ : (u_ | 0x80000000u); \
        unsigned p_ = (key_ & 0xFFFFFE00u) | ((TB) + (HR)); \
        if (p_ > l11) { unsigned v_ = p_; \
            BUB(l0) BUB(l1) BUB(l2) BUB(l3) BUB(l4)  BUB(l5) \
            BUB(l6) BUB(l7) BUB(l8) BUB(l9) BUB(l10) BUB(l11) } }

#define SUBITER(P0,P1,P2,P3,E0,E1,TT,TP) { \
        const bf16x8 c00_ = P0, c01_ = P1, c10_ = P2, c11_ = P3; \
        const f32x4  ce0_ = E0, ce1_ = E1; \
        LOADP(P0, P1, P2, P3, E0, E1, (TP) & 63) \
        f32x4 acc0_ = __builtin_amdgcn_mfma_f32_16x16x32_bf16(c00_, b0, ce0_, 0, 0, 0); \
        acc0_       = __builtin_amdgcn_mfma_f32_16x16x32_bf16(c01_, b1, acc0_, 0, 0, 0); \
        f32x4 acc1_ = __builtin_amdgcn_mfma_f32_16x16x32_bf16(c10_, b0, ce1_, 0, 0, 0); \
        acc1_       = __builtin_amdgcn_mfma_f32_16x16x32_bf16(c11_, b1, acc1_, 0, 0, 0); \
        const unsigned tb_ = (unsigned)((TT) << 3); \
        PINS(acc0_[0], 0, tb_) PINS(acc0_[1], 1, tb_) \
        PINS(acc0_[2], 2, tb_) PINS(acc0_[3], 3, tb_) \
        PINS(acc1_[0], 4, tb_) PINS(acc1_[1], 5, tb_) \
        PINS(acc1_[2], 6, tb_) PINS(acc1_[3], 7, tb_) }

    for (int t = 0; t < 64; t += 2) {
        SUBITER(A00, A01, A10, A11, Ae0, Ae1, t,     t + 2)
        SUBITER(B00, B01, B10, B11, Be0, Be1, t + 1, t + 3)
    }
#undef SUBITER
#undef PINS
#undef BUB
#undef LOADP

    // dump: decode packed -> global code id
    // code = cbase + t*32 + h*16 + q*4 + reg, tidx = (t<<3)|(h<<2)|reg
    unsigned short* cr = cand + (size_t)row * CANDS + w * 48 + q * 12;
#define DUMP(K, LK) { const unsigned t9 = (LK) & 0x1FFu; \
        cr[K] = (unsigned short)(cbase + ((t9 >> 3) << 5) + (((t9 >> 2) & 1u) << 4) \
                                 + (q << 2) + (t9 & 3u)); }
    DUMP(0, l0)  DUMP(1, l1)  DUMP(2, l2)  DUMP(3, l3)
    DUMP(4, l4)  DUMP(5, l5)  DUMP(6, l6)  DUMP(7, l7)
    DUMP(8, l8)  DUMP(9, l9)  DUMP(10, l10) DUMP(11, l11)
#undef DUMP
}

// ---------------------------------------------------------------------------
// Kernel 2: fp64 re-rank of 192 candidates (lane-quad per candidate, 3-deep
// pipelined gathers), wave-wide top-10 by (d, idx) via shuffle butterflies,
// Gumbel-max sample. NO GLOBAL ATOMICS: per-row loss/idx/valid partials to ws.
// ---------------------------------------------------------------------------
__global__ __launch_bounds__(256) void vq_finalize(const float* __restrict__ inp,
                                                   const float* __restrict__ cb,
                                                   const double* __restrict__ e2d,
                                                   const float* __restrict__ gumbel,
                                                   const unsigned short* __restrict__ cand,
                                                   float* __restrict__ out,
                                                   double* __restrict__ rowloss,
                                                   int* __restrict__ rowidx,
                                                   int* __restrict__ rowval) {
    __shared__ double dvs[4][CANDS];
    __shared__ int    dis[4][CANDS];

    const int tid  = threadIdx.x;
    const int w    = tid >> 6;
    const int lane = tid & 63;
    const int row  = blockIdx.x * 4 + w;
    const int g    = lane >> 2;   // quad id 0..15
    const int lq   = lane & 3;    // quarter within quad

    const float xf = inp[(size_t)row * EMB_DIM + lane];
    const double xd = (double)xf;

    // wave-wide ||x||^2 in fp64
    double x2 = xd * xd;
#pragma unroll
    for (int off = 32; off >= 1; off >>= 1) x2 += __shfl_xor(x2, off);
    const bool valid = sqrt(x2) > 1e-6;

    // lane's fp64 x-slice: dims [lq*16, lq*16+16) in registers
    double xq[16];
    {
        const float4* xp = (const float4*)(inp + (size_t)row * EMB_DIM + (lq << 4));
#pragma unroll
        for (int i = 0; i < 4; ++i) {
            const float4 v = xp[i];
            xq[4 * i + 0] = (double)v.x; xq[4 * i + 1] = (double)v.y;
            xq[4 * i + 2] = (double)v.z; xq[4 * i + 3] = (double)v.w;
        }
    }

    // hoisted candidate ids for this lane's quad (12 independent loads)
    int cid[12];
    {
        const unsigned short* crow = cand + (size_t)row * CANDS;
#pragma unroll
        for (int r = 0; r < 12; ++r) cid[r] = (int)crow[16 * r + g];
    }

    // software-pipelined gathers, depth 3 (buffers A,B,C rotate)
    float4 gA0, gA1, gA2, gA3, gB0, gB1, gB2, gB3, gC0, gC1, gC2, gC3;
#define GLOAD(S0,S1,S2,S3, R) { \
        const float4* ep_ = (const float4*)(cb + ((size_t)cid[R] << 6) + (lq << 4)); \
        S0 = ep_[0]; S1 = ep_[1]; S2 = ep_[2]; S3 = ep_[3]; }
    GLOAD(gA0,gA1,gA2,gA3, 0)
    GLOAD(gB0,gB1,gB2,gB3, 1)
    GLOAD(gC0,gC1,gC2,gC3, 2)

#define ROUND(R, S0,S1,S2,S3, PR) { \
        const float4 v0_ = S0, v1_ = S1, v2_ = S2, v3_ = S3; \
        if ((PR) < 12) { GLOAD(S0,S1,S2,S3, PR) } \
        double d0_ = 0.0, d1_ = 0.0; \
        d0_ = fma(xq[0],  (double)v0_.x, d0_); d0_ = fma(xq[1],  (double)v0_.y, d0_); \
        d0_ = fma(xq[2],  (double)v0_.z, d0_); d0_ = fma(xq[3],  (double)v0_.w, d0_); \
        d0_ = fma(xq[4],  (double)v1_.x, d0_); d0_ = fma(xq[5],  (double)v1_.y, d0_); \
        d0_ = fma(xq[6],  (double)v1_.z, d0_); d0_ = fma(xq[7],  (double)v1_.w, d0_); \
        d1_ = fma(xq[8],  (double)v2_.x, d1_); d1_ = fma(xq[9],  (double)v2_.y, d1_); \
        d1_ = fma(xq[10], (double)v2_.z, d1_); d1_ = fma(xq[11], (double)v2_.w, d1_); \
        d1_ = fma(xq[12], (double)v3_.x, d1_); d1_ = fma(xq[13], (double)v3_.y, d1_); \
        d1_ = fma(xq[14], (double)v3_.z, d1_); d1_ = fma(xq[15], (double)v3_.w, d1_); \
        double dot_ = d0_ + d1_; \
        dot_ += __shfl_xor(dot_, 1); \
        dot_ += __shfl_xor(dot_, 2); \
        if (lq == 0) { \
            dvs[w][16 * (R) + g] = x2 + e2d[cid[R]] - 2.0 * dot_; \
            dis[w][16 * (R) + g] = cid[R]; \
        } }

    ROUND(0,  gA0,gA1,gA2,gA3, 3)
    ROUND(1,  gB0,gB1,gB2,gB3, 4)
    ROUND(2,  gC0,gC1,gC2,gC3, 5)
    ROUND(3,  gA0,gA1,gA2,gA3, 6)
    ROUND(4,  gB0,gB1,gB2,gB3, 7)
    ROUND(5,  gC0,gC1,gC2,gC3, 8)
    ROUND(6,  gA0,gA1,gA2,gA3, 9)
    ROUND(7,  gB0,gB1,gB2,gB3, 10)
    ROUND(8,  gC0,gC1,gC2,gC3, 11)
    ROUND(9,  gA0,gA1,gA2,gA3, 12)
    ROUND(10, gB0,gB1,gB2,gB3, 12)
    ROUND(11, gC0,gC1,gC2,gC3, 12)
#undef ROUND
#undef GLOAD
    __syncthreads();

    // 3 candidates per lane; 10 wave-wide min-extractions by (d, idx).
    double cd[3]; int ci[3];
#pragma unroll
    for (int m = 0; m < 3; ++m) { cd[m] = dvs[w][lane + 64 * m]; ci[m] = dis[w][lane + 64 * m]; }

    double seld[TOP_K]; int seli[TOP_K];
#pragma unroll
    for (int k = 0; k < TOP_K; ++k) {
        double bd = cd[0]; int bi = ci[0];
        if (cd[1] < bd || (cd[1] == bd && ci[1] < bi)) { bd = cd[1]; bi = ci[1]; }
        if (cd[2] < bd || (cd[2] == bd && ci[2] < bi)) { bd = cd[2]; bi = ci[2]; }
#pragma unroll
        for (int off = 1; off < 64; off <<= 1) {
            const double od = __shfl_xor(bd, off);
            const int    oi = __shfl_xor(bi, off);
            if (od < bd || (od == bd && oi < bi)) { bd = od; bi = oi; }
        }
        seld[k] = bd; seli[k] = bi;   // uniform across wave
        if (ci[0] == bi) cd[0] = 1.0e300;
        if (ci[1] == bi) cd[1] = 1.0e300;
        if (ci[2] == bi) cd[2] = 1.0e300;
    }

    // Gumbel-max over top-10 (argmax keeps first max, like jnp.argmax)
    float gv = 0.0f;
    if (lane < TOP_K) gv = gumbel[(size_t)row * TOP_K + lane];
    float bestsc = -3.0e38f; double bestd = 0.0; int besti = 0;
#pragma unroll
    for (int k = 0; k < TOP_K; ++k) {
        const float gk = __shfl(gv, k);
        const float sc = (float)(-seld[k]) + gk;
        if (sc > bestsc) { bestsc = sc; bestd = seld[k]; besti = seli[k]; }
    }
    const int   cidx = besti;           // uniform
    const float mind = (float)bestd;

    const float vm = valid ? 1.0f : 0.0f;
    const float qv = cb[(size_t)cidx * EMB_DIM + lane];
    out[QST_OFF + (size_t)row * EMB_DIM + lane] = xf + (qv * vm - xf);

    // loss term uses UNMASKED q_valid, masked by vm
    const double dq = (double)qv - xd;
    double l = dq * dq * (double)vm;
#pragma unroll
    for (int off = 32; off >= 1; off >>= 1) l += __shfl_xor(l, off);

    if (lane == 0) {
        rowloss[row] = l;
        rowidx[row]  = cidx;
        rowval[row]  = valid ? 1 : 0;
        out[IDX_OFF + row]  = valid ? (float)cidx : 0.0f;
        out[MIND_OFF + row] = valid ? mind : 0.0f;
    }
}

// ---------------------------------------------------------------------------
// Kernel 3: reduce per-row partials (loss, valid), LDS histogram of sampled
// indices (valid-gated, matching .at[idx].add(valid)), entropy -> scalars.
// Single block, 256 threads. No global atomics.
// ---------------------------------------------------------------------------
__global__ __launch_bounds__(256) void vq_scalars(const double* __restrict__ rowloss,
                                                  const int* __restrict__ rowidx,
                                                  const int* __restrict__ rowval,
                                                  float* __restrict__ out) {
    __shared__ int    hist[NUM_EMB];     // 32 KB
    __shared__ double red[256];
    __shared__ double s_nv;
    const int tid = threadIdx.x;

    for (int k = tid; k < NUM_EMB; k += 256) hist[k] = 0;
    __syncthreads();

    double lsum = 0.0;
    int    nvl  = 0;
    for (int r = tid; r < N_ROWS; r += 256) {
        lsum += rowloss[r];
        const int v = rowval[r];
        nvl += v;
        if (v) atomicAdd(&hist[rowidx[r]], 1);
    }

    // reduce loss
    red[tid] = lsum;
    __syncthreads();
    for (int s = 128; s >= 1; s >>= 1) {
        if (tid < s) red[tid] += red[tid + s];
        __syncthreads();
    }
    const double losstot = red[0];
    __syncthreads();

    // reduce nvalid
    red[tid] = (double)nvl;
    __syncthreads();
    for (int s = 128; s >= 1; s >>= 1) {
        if (tid < s) red[tid] += red[tid + s];
        __syncthreads();
    }
    if (tid == 0) s_nv = (red[0] > 0.5) ? red[0] : 1.0;
    __syncthreads();
    const double nv = s_nv;
    __syncthreads();

    // entropy over histogram
    double h = 0.0;
    for (int k = tid; k < NUM_EMB; k += 256) {
        const double p = (double)hist[k] / nv;
        h += p * log(p + 1e-10);
    }
    red[tid] = h;
    __syncthreads();
    for (int s = 128; s >= 1; s >>= 1) {
        if (tid < s) red[tid] += red[tid + s];
        __syncthreads();
    }
    if (tid == 0) {
        const double H = red[0];                 // sum p*log(p+1e-10)
        const double perp = exp(-H);
        const double ploss = -log(perp + 1e-10);
        const double lvq = losstot / (nv * (double)EMB_DIM);
        out[LOSS_OFF] = (float)(lvq + PERP_W * ploss);
        out[PERP_OFF] = (float)perp;
    }
}

// ---------------------------------------------------------------------------
extern "C" void kernel_launch(void* const* d_in, const int* in_sizes, int n_in,
                              void* d_out, int out_size, void* d_ws, size_t ws_size,
                              hipStream_t stream) {
    const float* inp    = (const float*)d_in[0];  // [16384, 64]
    const float* cb     = (const float*)d_in[1];  // [8192, 64]
    const float* gumbel = (const float*)d_in[2];  // [16384, 10]
    float* out = (float*)d_out;

    char* ws = (char*)d_ws;
    float*          e2h     = (float*)(ws + WS_E2H);
    double*         e2d     = (double*)(ws + WS_E2D);
    unsigned short* cb16    = (unsigned short*)(ws + WS_CB16);
    double*         rowloss = (double*)(ws + WS_ROWLOSS);
    int*            rowidx  = (int*)(ws + WS_ROWIDX);
    int*            rowval  = (int*)(ws + WS_ROWVAL);
    unsigned short* candw   = (unsigned short*)(ws + WS_CAND);

    vq_prep<<<NUM_EMB / 256, 256, 0, stream>>>(cb, e2h, e2d, cb16);
    vq_gemm_topk<<<N_ROWS / 16, 256, 0, stream>>>(inp, cb16, e2h, candw);
    vq_finalize<<<N_ROWS / 4, 256, 0, stream>>>(inp, cb, e2d, gumbel, candw, out,
                                                rowloss, rowidx, rowval);
    vq_scalars<<<1, 256, 0, stream>>>(rowloss, rowidx, rowval, out);
}

// Round 8
// 316.164 us; speedup vs baseline: 94.8242x; 1.0977x over previous
//
#include <hip/hip_runtime.h>
#include <hip/hip_bf16.h>

// Problem constants
#define N_ROWS   16384      // 8*2048
#define EMB_DIM  64
#define NUM_EMB  8192
#define TOP_K    10
#define PERP_W   0.01

// Pass-1: 4 chunks of 2048 codes (one per wave); within a chunk each lane-quad
// owns a disjoint quarter of every 16-code tile (512 codes/lane); per-lane
// top-12 kept in REGISTERS as packed u32 = (23-bit positive-float score bits |
// 9-bit subset-local idx). Union over 16 subsets x 12 = 192 candidates/row
// provably contains the true top-10 (<=9 global betters -> subset rank <=10;
// bf16 + 2^-14-trunc noise << order-stat spacing, margin 2 ranks).
#define M_CHUNK   12
#define CANDS     192

// Output layout (all float32, concatenated in return order)
#define QST_OFF   0
#define LOSS_OFF  (N_ROWS * EMB_DIM)                 // 1048576
#define IDX_OFF   (LOSS_OFF + 1)                     // 1048577
#define MIND_OFF  (IDX_OFF + N_ROWS)                 // 1064961
#define PERP_OFF  (MIND_OFF + N_ROWS)                // 1081345

// ws layout (bytes)
#define WS_E2C    0                                  // 8192 f32 = 512-||e||^2/2 (32 KB)
#define WS_E2D    32768                              // 8192 f64   (64 KB)
#define WS_CB16   98304                              // 8192*64 bf16 (1 MB)
#define WS_HIST   1146880                            // 8192 i32  (32 KB)
#define WS_LOSSP  1179648                            // 4096 f64  (32 KB)
#define WS_NVP    1212416                            // 4096 i32  (16 KB)
#define WS_CAND   1228800                            // 16384*192 u16 (6.3 MB)

typedef short bf16x8 __attribute__((ext_vector_type(8)));
typedef float f32x4  __attribute__((ext_vector_type(4)));

__device__ __forceinline__ unsigned short f2bf(float f) {
    // round-to-nearest-even fp32 -> bf16 (inputs are finite gaussians)
    unsigned int u = __float_as_uint(f);
    unsigned int r = u + 0x7fffu + ((u >> 16) & 1u);
    return (unsigned short)(r >> 16);
}

// ---------------------------------------------------------------------------
// Kernel 0: prep — 512-||e||^2/2 (fp32, MFMA C-init; keeps all scores
// positive so raw float bits are uint-monotone), ||e||^2 (fp64, pass-2),
// codebook -> bf16, zero histogram. One thread per code row.
// ---------------------------------------------------------------------------
__global__ __launch_bounds__(256) void vq_prep(const float* __restrict__ cb,
                                               float* __restrict__ e2c,
                                               double* __restrict__ e2d,
                                               unsigned short* __restrict__ cb16,
                                               int* __restrict__ hist) {
    const int k = blockIdx.x * 256 + threadIdx.x;   // 0..8191
    hist[k] = 0;
    const float4* rp = (const float4*)(cb + (size_t)k * EMB_DIM);
    float  s  = 0.0f;
    double sd = 0.0;
#pragma unroll
    for (int i = 0; i < 16; ++i) {
        const float4 v = rp[i];
        s += v.x * v.x + v.y * v.y + v.z * v.z + v.w * v.w;
        sd += (double)v.x * (double)v.x + (double)v.y * (double)v.y
            + (double)v.z * (double)v.z + (double)v.w * (double)v.w;
        unsigned long long p =
              (unsigned long long)f2bf(v.x)
            | ((unsigned long long)f2bf(v.y) << 16)
            | ((unsigned long long)f2bf(v.z) << 32)
            | ((unsigned long long)f2bf(v.w) << 48);
        *(unsigned long long*)(cb16 + (size_t)k * EMB_DIM + 4 * i) = p;
    }
    e2c[k] = 512.0f - 0.5f * s;   // score s' = dot + 512 - e2/2 > 0 always
    e2d[k] = sd;
}

// ---------------------------------------------------------------------------
// Kernel 1: MFMA distance GEMM + per-lane register top-12.
// Block = 256 = 4 waves = 16 rows; wave w owns code chunk [w*2048,(w+1)*2048).
// 32 codes (2 MFMA tiles) per sub-iter; prefetch distance 2. Scores positive
// (C-init 512-e2/2) -> key = (float bits & ~0x1FF) | idx9, one v_and_or each.
// Per batch of 8: Batcher sort-8 (19 CE) descending, then gated descending
// inserts into sorted 12-reg list (exact early-exit). Zero LDS, no barriers.
// ---------------------------------------------------------------------------
__global__ __launch_bounds__(256) void vq_gemm_topk(
        const float* __restrict__ inp, const unsigned short* __restrict__ cb16,
        const float* __restrict__ e2c, unsigned short* __restrict__ cand) {
    const int tid   = threadIdx.x;
    const int w     = tid >> 6;        // chunk
    const int lane  = tid & 63;
    const int q     = lane >> 4;       // quad: k-slice for A/B, code subgroup for D
    const int rsub  = lane & 15;
    const int row   = blockIdx.x * 16 + rsub;
    const int cbase = w * 2048;

    // B fragments (this lane's row, k = q*8+j and +32), fp32 -> bf16
    bf16x8 b0, b1;
    {
        const float* xp = inp + (size_t)row * EMB_DIM + q * 8;
#pragma unroll
        for (int j = 0; j < 8; ++j) b0[j] = (short)f2bf(xp[j]);
#pragma unroll
        for (int j = 0; j < 8; ++j) b1[j] = (short)f2bf(xp[32 + j]);
    }

    // sorted-desc register list of packed (score|idx); l0 best, l11 worst
    unsigned l0=0,l1=0,l2=0,l3=0,l4=0,l5=0,l6=0,l7=0,l8=0,l9=0,l10=0,l11=0;

    // A / e2 base pointers (per-lane)
    const unsigned short* abase = cb16 + ((size_t)(cbase + rsub) << 6) + (q << 3);
    const float*          ebase = e2c + cbase + (q << 2);

#define LOADP(P0,P1,P2,P3,E0,E1,TT) { \
        const unsigned short* ab_ = abase + (size_t)(TT) * 2048; \
        P0 = *(const bf16x8*)(ab_); \
        P1 = *(const bf16x8*)(ab_ + 32); \
        P2 = *(const bf16x8*)(ab_ + 1024); \
        P3 = *(const bf16x8*)(ab_ + 1024 + 32); \
        const float* eb_ = ebase + (TT) * 32; \
        E0 = *(const f32x4*)(eb_); \
        E1 = *(const f32x4*)(eb_ + 16); }

    bf16x8 A00, A01, A10, A11, B00, B01, B10, B11;
    f32x4  Ae0, Ae1, Be0, Be1;
    LOADP(A00, A01, A10, A11, Ae0, Ae1, 0)
    LOADP(B00, B01, B10, B11, Be0, Be1, 1)

    // descending compare-exchange: max to first
#define CE(A,B) { const unsigned a_ = A, b_ = B; \
                  A = a_ > b_ ? a_ : b_; B = a_ > b_ ? b_ : a_; }
    // bubble-insert v_ into sorted-desc 12-list
#define BUB(LK) { const unsigned mx_ = (v_ > LK) ? v_ : LK; \
                  v_ = (v_ > LK) ? LK : v_; LK = mx_; }
#define INS(X) { unsigned v_ = (X); \
        BUB(l0) BUB(l1) BUB(l2) BUB(l3) BUB(l4)  BUB(l5) \
        BUB(l6) BUB(l7) BUB(l8) BUB(l9) BUB(l10) BUB(l11) }

#define SUBITER(P0,P1,P2,P3,E0,E1,TT,TP) { \
        const bf16x8 c00_ = P0, c01_ = P1, c10_ = P2, c11_ = P3; \
        const f32x4  ce0_ = E0, ce1_ = E1; \
        LOADP(P0, P1, P2, P3, E0, E1, (TP) & 63) \
        f32x4 acc0_ = __builtin_amdgcn_mfma_f32_16x16x32_bf16(c00_, b0, ce0_, 0, 0, 0); \
        acc0_       = __builtin_amdgcn_mfma_f32_16x16x32_bf16(c01_, b1, acc0_, 0, 0, 0); \
        f32x4 acc1_ = __builtin_amdgcn_mfma_f32_16x16x32_bf16(c10_, b0, ce1_, 0, 0, 0); \
        acc1_       = __builtin_amdgcn_mfma_f32_16x16x32_bf16(c11_, b1, acc1_, 0, 0, 0); \
        const unsigned tb_ = (unsigned)((TT) << 3); \
        unsigned k0 = (__float_as_uint(acc0_[0]) & 0xFFFFFE00u) | (tb_ + 0u); \
        unsigned k1 = (__float_as_uint(acc0_[1]) & 0xFFFFFE00u) | (tb_ + 1u); \
        unsigned k2 = (__float_as_uint(acc0_[2]) & 0xFFFFFE00u) | (tb_ + 2u); \
        unsigned k3 = (__float_as_uint(acc0_[3]) & 0xFFFFFE00u) | (tb_ + 3u); \
        unsigned k4 = (__float_as_uint(acc1_[0]) & 0xFFFFFE00u) | (tb_ + 4u); \
        unsigned k5 = (__float_as_uint(acc1_[1]) & 0xFFFFFE00u) | (tb_ + 5u); \
        unsigned k6 = (__float_as_uint(acc1_[2]) & 0xFFFFFE00u) | (tb_ + 6u); \
        unsigned k7 = (__float_as_uint(acc1_[3]) & 0xFFFFFE00u) | (tb_ + 7u); \
        /* Batcher odd-even mergesort, 8 keys, descending (19 CE) */ \
        CE(k0,k1) CE(k2,k3) CE(k4,k5) CE(k6,k7) \
        CE(k0,k2) CE(k1,k3) CE(k4,k6) CE(k5,k7) \
        CE(k1,k2) CE(k5,k6) \
        CE(k0,k4) CE(k1,k5) CE(k2,k6) CE(k3,k7) \
        CE(k2,k4) CE(k3,k5) \
        CE(k1,k2) CE(k3,k4) CE(k5,k6) \
        /* gated descending inserts: exact early-exit */ \
        if (k0 > l11) { INS(k0) \
        if (k1 > l11) { INS(k1) \
        if (k2 > l11) { INS(k2) \
        if (k3 > l11) { INS(k3) \
        if (k4 > l11) { INS(k4) \
        if (k5 > l11) { INS(k5) \
        if (k6 > l11) { INS(k6) \
        if (k7 > l11) { INS(k7) } } } } } } } } }

    for (int t = 0; t < 64; t += 2) {
        SUBITER(A00, A01, A10, A11, Ae0, Ae1, t,     t + 2)
        SUBITER(B00, B01, B10, B11, Be0, Be1, t + 1, t + 3)
    }
#undef SUBITER
#undef INS
#undef BUB
#undef CE
#undef LOADP

    // dump: decode packed -> global code id
    // code = cbase + t*32 + h*16 + q*4 + reg, tidx = (t<<3)|(h<<2)|reg
    unsigned short* cr = cand + (size_t)row * CANDS + w * 48 + q * 12;
#define DUMP(K, LK) { const unsigned t9 = (LK) & 0x1FFu; \
        cr[K] = (unsigned short)(cbase + ((t9 >> 3) << 5) + (((t9 >> 2) & 1u) << 4) \
                                 + (q << 2) + (t9 & 3u)); }
    DUMP(0, l0)  DUMP(1, l1)  DUMP(2, l2)  DUMP(3, l3)
    DUMP(4, l4)  DUMP(5, l5)  DUMP(6, l6)  DUMP(7, l7)
    DUMP(8, l8)  DUMP(9, l9)  DUMP(10, l10) DUMP(11, l11)
#undef DUMP
}

// ---------------------------------------------------------------------------
// Kernel 2: fp64 re-rank of 192 candidates (lane-quad per candidate, 3-deep
// pipelined gathers), wave-wide top-10 by (d, idx) via shuffle butterflies,
// Gumbel-max sample. Scattered-bin global histogram atomics (low contention)
// + per-block loss/valid partials (no hot-line atomics).
// ---------------------------------------------------------------------------
__global__ __launch_bounds__(256) void vq_finalize(const float* __restrict__ inp,
                                                   const float* __restrict__ cb,
                                                   const double* __restrict__ e2d,
                                                   const float* __restrict__ gumbel,
                                                   const unsigned short* __restrict__ cand,
                                                   float* __restrict__ out,
                                                   int* __restrict__ hist,
                                                   double* __restrict__ lossp,
                                                   int* __restrict__ nvp) {
    __shared__ double dvs[4][CANDS];
    __shared__ int    dis[4][CANDS];
    __shared__ double wl[4];
    __shared__ int    wv[4];

    const int tid  = threadIdx.x;
    const int w    = tid >> 6;
    const int lane = tid & 63;
    const int row  = blockIdx.x * 4 + w;
    const int g    = lane >> 2;   // quad id 0..15
    const int lq   = lane & 3;    // quarter within quad

    const float xf = inp[(size_t)row * EMB_DIM + lane];
    const double xd = (double)xf;

    // wave-wide ||x||^2 in fp64
    double x2 = xd * xd;
#pragma unroll
    for (int off = 32; off >= 1; off >>= 1) x2 += __shfl_xor(x2, off);
    const bool valid = sqrt(x2) > 1e-6;

    // lane's fp64 x-slice: dims [lq*16, lq*16+16) in registers
    double xq[16];
    {
        const float4* xp = (const float4*)(inp + (size_t)row * EMB_DIM + (lq << 4));
#pragma unroll
        for (int i = 0; i < 4; ++i) {
            const float4 v = xp[i];
            xq[4 * i + 0] = (double)v.x; xq[4 * i + 1] = (double)v.y;
            xq[4 * i + 2] = (double)v.z; xq[4 * i + 3] = (double)v.w;
        }
    }

    // hoisted candidate ids for this lane's quad (12 independent loads)
    int cid[12];
    {
        const unsigned short* crow = cand + (size_t)row * CANDS;
#pragma unroll
        for (int r = 0; r < 12; ++r) cid[r] = (int)crow[16 * r + g];
    }

    // software-pipelined gathers, depth 3 (buffers A,B,C rotate)
    float4 gA0, gA1, gA2, gA3, gB0, gB1, gB2, gB3, gC0, gC1, gC2, gC3;
#define GLOAD(S0,S1,S2,S3, R) { \
        const float4* ep_ = (const float4*)(cb + ((size_t)cid[R] << 6) + (lq << 4)); \
        S0 = ep_[0]; S1 = ep_[1]; S2 = ep_[2]; S3 = ep_[3]; }
    GLOAD(gA0,gA1,gA2,gA3, 0)
    GLOAD(gB0,gB1,gB2,gB3, 1)
    GLOAD(gC0,gC1,gC2,gC3, 2)

#define ROUND(R, S0,S1,S2,S3, PR) { \
        const float4 v0_ = S0, v1_ = S1, v2_ = S2, v3_ = S3; \
        if ((PR) < 12) { GLOAD(S0,S1,S2,S3, PR) } \
        double d0_ = 0.0, d1_ = 0.0; \
        d0_ = fma(xq[0],  (double)v0_.x, d0_); d0_ = fma(xq[1],  (double)v0_.y, d0_); \
        d0_ = fma(xq[2],  (double)v0_.z, d0_); d0_ = fma(xq[3],  (double)v0_.w, d0_); \
        d0_ = fma(xq[4],  (double)v1_.x, d0_); d0_ = fma(xq[5],  (double)v1_.y, d0_); \
        d0_ = fma(xq[6],  (double)v1_.z, d0_); d0_ = fma(xq[7],  (double)v1_.w, d0_); \
        d1_ = fma(xq[8],  (double)v2_.x, d1_); d1_ = fma(xq[9],  (double)v2_.y, d1_); \
        d1_ = fma(xq[10], (double)v2_.z, d1_); d1_ = fma(xq[11], (double)v2_.w, d1_); \
        d1_ = fma(xq[12], (double)v3_.x, d1_); d1_ = fma(xq[13], (double)v3_.y, d1_); \
        d1_ = fma(xq[14], (double)v3_.z, d1_); d1_ = fma(xq[15], (double)v3_.w, d1_); \
        double dot_ = d0_ + d1_; \
        dot_ += __shfl_xor(dot_, 1); \
        dot_ += __shfl_xor(dot_, 2); \
        if (lq == 0) { \
            dvs[w][16 * (R) + g] = x2 + e2d[cid[R]] - 2.0 * dot_; \
            dis[w][16 * (R) + g] = cid[R]; \
        } }

    ROUND(0,  gA0,gA1,gA2,gA3, 3)
    ROUND(1,  gB0,gB1,gB2,gB3, 4)
    ROUND(2,  gC0,gC1,gC2,gC3, 5)
    ROUND(3,  gA0,gA1,gA2,gA3, 6)
    ROUND(4,  gB0,gB1,gB2,gB3, 7)
    ROUND(5,  gC0,gC1,gC2,gC3, 8)
    ROUND(6,  gA0,gA1,gA2,gA3, 9)
    ROUND(7,  gB0,gB1,gB2,gB3, 10)
    ROUND(8,  gC0,gC1,gC2,gC3, 11)
    ROUND(9,  gA0,gA1,gA2,gA3, 12)
    ROUND(10, gB0,gB1,gB2,gB3, 12)
    ROUND(11, gC0,gC1,gC2,gC3, 12)
#undef ROUND
#undef GLOAD
    __syncthreads();

    // 3 candidates per lane; 10 wave-wide min-extractions by (d, idx).
    double cd[3]; int ci[3];
#pragma unroll
    for (int m = 0; m < 3; ++m) { cd[m] = dvs[w][lane + 64 * m]; ci[m] = dis[w][lane + 64 * m]; }

    double seld[TOP_K]; int seli[TOP_K];
#pragma unroll
    for (int k = 0; k < TOP_K; ++k) {
        double bd = cd[0]; int bi = ci[0];
        if (cd[1] < bd || (cd[1] == bd && ci[1] < bi)) { bd = cd[1]; bi = ci[1]; }
        if (cd[2] < bd || (cd[2] == bd && ci[2] < bi)) { bd = cd[2]; bi = ci[2]; }
#pragma unroll
        for (int off = 1; off < 64; off <<= 1) {
            const double od = __shfl_xor(bd, off);
            const int    oi = __shfl_xor(bi, off);
            if (od < bd || (od == bd && oi < bi)) { bd = od; bi = oi; }
        }
        seld[k] = bd; seli[k] = bi;   // uniform across wave
        if (ci[0] == bi) cd[0] = 1.0e300;
        if (ci[1] == bi) cd[1] = 1.0e300;
        if (ci[2] == bi) cd[2] = 1.0e300;
    }

    // Gumbel-max over top-10 (argmax keeps first max, like jnp.argmax)
    float gv = 0.0f;
    if (lane < TOP_K) gv = gumbel[(size_t)row * TOP_K + lane];
    float bestsc = -3.0e38f; double bestd = 0.0; int besti = 0;
#pragma unroll
    for (int k = 0; k < TOP_K; ++k) {
        const float gk = __shfl(gv, k);
        const float sc = (float)(-seld[k]) + gk;
        if (sc > bestsc) { bestsc = sc; bestd = seld[k]; besti = seli[k]; }
    }
    const int   cidx = besti;           // uniform
    const float mind = (float)bestd;

    const float vm = valid ? 1.0f : 0.0f;
    const float qv = cb[(size_t)cidx * EMB_DIM + lane];
    out[QST_OFF + (size_t)row * EMB_DIM + lane] = xf + (qv * vm - xf);

    // loss term uses UNMASKED q_valid, masked by vm
    const double dq = (double)qv - xd;
    double l = dq * dq * (double)vm;
#pragma unroll
    for (int off = 32; off >= 1; off >>= 1) l += __shfl_xor(l, off);

    if (lane == 0) {
        wl[w] = l;
        wv[w] = valid ? 1 : 0;
        if (valid) atomicAdd(&hist[cidx], 1);   // scattered bins, low contention
        out[IDX_OFF + row]  = valid ? (float)cidx : 0.0f;
        out[MIND_OFF + row] = valid ? mind : 0.0f;
    }
    __syncthreads();
    if (tid == 0) {
        lossp[blockIdx.x] = wl[0] + wl[1] + wl[2] + wl[3];
        nvp[blockIdx.x]   = wv[0] + wv[1] + wv[2] + wv[3];
    }
}

// ---------------------------------------------------------------------------
// Kernel 3: reduce per-block partials + histogram entropy -> scalars.
// Single block, 256 threads, ~80 KB of reads.
// ---------------------------------------------------------------------------
__global__ __launch_bounds__(256) void vq_scalars(const double* __restrict__ lossp,
                                                  const int* __restrict__ nvp,
                                                  const int* __restrict__ hist,
                                                  float* __restrict__ out) {
    __shared__ double red[256];
    __shared__ double s_nv;
    const int tid = threadIdx.x;

    double lsum = 0.0;
    int    nvl  = 0;
#pragma unroll
    for (int i = 0; i < 16; ++i) {
        const int j = tid + 256 * i;   // 4096 partials
        lsum += lossp[j];
        nvl  += nvp[j];
    }

    red[tid] = lsum;
    __syncthreads();
    for (int s = 128; s >= 1; s >>= 1) {
        if (tid < s) red[tid] += red[tid + s];
        __syncthreads();
    }
    const double losstot = red[0];
    __syncthreads();

    red[tid] = (double)nvl;
    __syncthreads();
    for (int s = 128; s >= 1; s >>= 1) {
        if (tid < s) red[tid] += red[tid + s];
        __syncthreads();
    }
    if (tid == 0) s_nv = (red[0] > 0.5) ? red[0] : 1.0;
    __syncthreads();
    const double nv = s_nv;
    __syncthreads();

    double h = 0.0;
    for (int k = tid; k < NUM_EMB; k += 256) {
        const double p = (double)hist[k] / nv;
        h += p * log(p + 1e-10);
    }
    red[tid] = h;
    __syncthreads();
    for (int s = 128; s >= 1; s >>= 1) {
        if (tid < s) red[tid] += red[tid + s];
        __syncthreads();
    }
    if (tid == 0) {
        const double H = red[0];                 // sum p*log(p+1e-10)
        const double perp = exp(-H);
        const double ploss = -log(perp + 1e-10);
        const double lvq = losstot / (nv * (double)EMB_DIM);
        out[LOSS_OFF] = (float)(lvq + PERP_W * ploss);
        out[PERP_OFF] = (float)perp;
    }
}

// ---------------------------------------------------------------------------
extern "C" void kernel_launch(void* const* d_in, const int* in_sizes, int n_in,
                              void* d_out, int out_size, void* d_ws, size_t ws_size,
                              hipStream_t stream) {
    const float* inp    = (const float*)d_in[0];  // [16384, 64]
    const float* cb     = (const float*)d_in[1];  // [8192, 64]
    const float* gumbel = (const float*)d_in[2];  // [16384, 10]
    float* out = (float*)d_out;

    char* ws = (char*)d_ws;
    float*          e2c   = (float*)(ws + WS_E2C);
    double*         e2d   = (double*)(ws + WS_E2D);
    unsigned short* cb16  = (unsigned short*)(ws + WS_CB16);
    int*            hist  = (int*)(ws + WS_HIST);
    double*         lossp = (double*)(ws + WS_LOSSP);
    int*            nvp   = (int*)(ws + WS_NVP);
    unsigned short* candw = (unsigned short*)(ws + WS_CAND);

    vq_prep<<<NUM_EMB / 256, 256, 0, stream>>>(cb, e2c, e2d, cb16, hist);
    vq_gemm_topk<<<N_ROWS / 16, 256, 0, stream>>>(inp, cb16, e2c, candw);
    vq_finalize<<<N_ROWS / 4, 256, 0, stream>>>(inp, cb, e2d, gumbel, candw, out,
                                                hist, lossp, nvp);
    vq_scalars<<<1, 256, 0, stream>>>(lossp, nvp, hist, out);
}

// Round 9
// 315.748 us; speedup vs baseline: 94.9494x; 1.0013x over previous
//
#include <hip/hip_runtime.h>
#include <hip/hip_bf16.h>

// Problem constants
#define N_ROWS   16384      // 8*2048
#define EMB_DIM  64
#define NUM_EMB  8192
#define TOP_K    10
#define PERP_W   0.01

// Pass-1: 4 chunks of 2048 codes (one per wave); within a chunk each lane-quad
// owns a disjoint quarter of every 16-code tile (512 codes/lane); per-lane
// top-12 kept in REGISTERS as packed u32 = (23-bit positive-float score bits |
// 9-bit subset-local idx). Union over 16 subsets x 12 = 192 candidates/row
// provably contains the true top-10 (<=9 global betters -> subset rank <=10;
// bf16 + 2^-14-trunc noise << order-stat spacing, margin 2 ranks).
#define M_CHUNK   12
#define CANDS     192

// Output layout (all float32, concatenated in return order)
#define QST_OFF   0
#define LOSS_OFF  (N_ROWS * EMB_DIM)                 // 1048576
#define IDX_OFF   (LOSS_OFF + 1)                     // 1048577
#define MIND_OFF  (IDX_OFF + N_ROWS)                 // 1064961
#define PERP_OFF  (MIND_OFF + N_ROWS)                // 1081345

// ws layout (bytes)
#define WS_E2C    0                                  // 8192 f32 = 512-||e||^2/2 (32 KB)
#define WS_E2D    32768                              // 8192 f64   (64 KB)
#define WS_CB16   98304                              // 8192*64 bf16 (1 MB)
#define WS_HIST   1146880                            // 8192 i32  (32 KB)
#define WS_LOSSP  1179648                            // 4096 f64  (32 KB)
#define WS_NVP    1212416                            // 4096 i32  (16 KB)
#define WS_CAND   1228800                            // 16384*192 u16 (6.3 MB)

typedef short bf16x8 __attribute__((ext_vector_type(8)));
typedef float f32x4  __attribute__((ext_vector_type(4)));

__device__ __forceinline__ unsigned short f2bf(float f) {
    // round-to-nearest-even fp32 -> bf16 (inputs are finite gaussians)
    unsigned int u = __float_as_uint(f);
    unsigned int r = u + 0x7fffu + ((u >> 16) & 1u);
    return (unsigned short)(r >> 16);
}

// ---------------------------------------------------------------------------
// Kernel 0: prep — 512-||e||^2/2 (fp32, MFMA C-init; keeps all scores
// positive so raw float bits are uint-monotone), ||e||^2 (fp64, pass-2),
// codebook -> bf16, zero histogram. One thread per code row.
// ---------------------------------------------------------------------------
__global__ __launch_bounds__(256) void vq_prep(const float* __restrict__ cb,
                                               float* __restrict__ e2c,
                                               double* __restrict__ e2d,
                                               unsigned short* __restrict__ cb16,
                                               int* __restrict__ hist) {
    const int k = blockIdx.x * 256 + threadIdx.x;   // 0..8191
    hist[k] = 0;
    const float4* rp = (const float4*)(cb + (size_t)k * EMB_DIM);
    float  s  = 0.0f;
    double sd = 0.0;
#pragma unroll
    for (int i = 0; i < 16; ++i) {
        const float4 v = rp[i];
        s += v.x * v.x + v.y * v.y + v.z * v.z + v.w * v.w;
        sd += (double)v.x * (double)v.x + (double)v.y * (double)v.y
            + (double)v.z * (double)v.z + (double)v.w * (double)v.w;
        unsigned long long p =
              (unsigned long long)f2bf(v.x)
            | ((unsigned long long)f2bf(v.y) << 16)
            | ((unsigned long long)f2bf(v.z) << 32)
            | ((unsigned long long)f2bf(v.w) << 48);
        *(unsigned long long*)(cb16 + (size_t)k * EMB_DIM + 4 * i) = p;
    }
    e2c[k] = 512.0f - 0.5f * s;   // score s' = dot + 512 - e2/2 > 0 always
    e2d[k] = sd;
}

// ---------------------------------------------------------------------------
// Kernel 1: MFMA distance GEMM + per-lane register top-12.
// Block = 256 = 4 waves = 16 rows; wave w owns code chunk [w*2048,(w+1)*2048).
// 32 codes (2 MFMA tiles) per sub-iter; prefetch distance 2. Scores positive
// (C-init 512-e2/2) -> key = (float bits & ~0x1FF) | idx9, one v_and_or each.
// Per batch of 8: Batcher sort-8 (19 CE) descending, then FIXED merge network:
// half-cleaner pairing CE(l[11-j], k[j]) (8 CE -> top-12 multiset, l bitonic)
// + bitonic-12 resort (24 CE: stride6, stride3, 4x sort-3). Branchless (one
// wave-coherent skip gate; network is a no-op when batch max <= l11).
// Zero LDS, zero barriers.
// ---------------------------------------------------------------------------
__global__ __launch_bounds__(256) void vq_gemm_topk(
        const float* __restrict__ inp, const unsigned short* __restrict__ cb16,
        const float* __restrict__ e2c, unsigned short* __restrict__ cand) {
    const int tid   = threadIdx.x;
    const int w     = tid >> 6;        // chunk
    const int lane  = tid & 63;
    const int q     = lane >> 4;       // quad: k-slice for A/B, code subgroup for D
    const int rsub  = lane & 15;
    const int row   = blockIdx.x * 16 + rsub;
    const int cbase = w * 2048;

    // B fragments (this lane's row, k = q*8+j and +32), fp32 -> bf16
    bf16x8 b0, b1;
    {
        const float* xp = inp + (size_t)row * EMB_DIM + q * 8;
#pragma unroll
        for (int j = 0; j < 8; ++j) b0[j] = (short)f2bf(xp[j]);
#pragma unroll
        for (int j = 0; j < 8; ++j) b1[j] = (short)f2bf(xp[32 + j]);
    }

    // sorted-desc register list of packed (score|idx); l0 best, l11 worst
    unsigned l0=0,l1=0,l2=0,l3=0,l4=0,l5=0,l6=0,l7=0,l8=0,l9=0,l10=0,l11=0;

    // A / e2 base pointers (per-lane)
    const unsigned short* abase = cb16 + ((size_t)(cbase + rsub) << 6) + (q << 3);
    const float*          ebase = e2c + cbase + (q << 2);

#define LOADP(P0,P1,P2,P3,E0,E1,TT) { \
        const unsigned short* ab_ = abase + (size_t)(TT) * 2048; \
        P0 = *(const bf16x8*)(ab_); \
        P1 = *(const bf16x8*)(ab_ + 32); \
        P2 = *(const bf16x8*)(ab_ + 1024); \
        P3 = *(const bf16x8*)(ab_ + 1024 + 32); \
        const float* eb_ = ebase + (TT) * 32; \
        E0 = *(const f32x4*)(eb_); \
        E1 = *(const f32x4*)(eb_ + 16); }

    bf16x8 A00, A01, A10, A11, B00, B01, B10, B11;
    f32x4  Ae0, Ae1, Be0, Be1;
    LOADP(A00, A01, A10, A11, Ae0, Ae1, 0)
    LOADP(B00, B01, B10, B11, Be0, Be1, 1)

    // descending compare-exchange: max to first operand
#define CE(A,B) { const unsigned a_ = A, b_ = B; \
                  A = a_ > b_ ? a_ : b_; B = a_ > b_ ? b_ : a_; }

#define SUBITER(P0,P1,P2,P3,E0,E1,TT,TP) { \
        const bf16x8 c00_ = P0, c01_ = P1, c10_ = P2, c11_ = P3; \
        const f32x4  ce0_ = E0, ce1_ = E1; \
        LOADP(P0, P1, P2, P3, E0, E1, (TP) & 63) \
        f32x4 acc0_ = __builtin_amdgcn_mfma_f32_16x16x32_bf16(c00_, b0, ce0_, 0, 0, 0); \
        acc0_       = __builtin_amdgcn_mfma_f32_16x16x32_bf16(c01_, b1, acc0_, 0, 0, 0); \
        f32x4 acc1_ = __builtin_amdgcn_mfma_f32_16x16x32_bf16(c10_, b0, ce1_, 0, 0, 0); \
        acc1_       = __builtin_amdgcn_mfma_f32_16x16x32_bf16(c11_, b1, acc1_, 0, 0, 0); \
        const unsigned tb_ = (unsigned)((TT) << 3); \
        unsigned k0 = (__float_as_uint(acc0_[0]) & 0xFFFFFE00u) | (tb_ + 0u); \
        unsigned k1 = (__float_as_uint(acc0_[1]) & 0xFFFFFE00u) | (tb_ + 1u); \
        unsigned k2 = (__float_as_uint(acc0_[2]) & 0xFFFFFE00u) | (tb_ + 2u); \
        unsigned k3 = (__float_as_uint(acc0_[3]) & 0xFFFFFE00u) | (tb_ + 3u); \
        unsigned k4 = (__float_as_uint(acc1_[0]) & 0xFFFFFE00u) | (tb_ + 4u); \
        unsigned k5 = (__float_as_uint(acc1_[1]) & 0xFFFFFE00u) | (tb_ + 5u); \
        unsigned k6 = (__float_as_uint(acc1_[2]) & 0xFFFFFE00u) | (tb_ + 6u); \
        unsigned k7 = (__float_as_uint(acc1_[3]) & 0xFFFFFE00u) | (tb_ + 7u); \
        /* Batcher odd-even mergesort, 8 keys, descending (19 CE) */ \
        CE(k0,k1) CE(k2,k3) CE(k4,k5) CE(k6,k7) \
        CE(k0,k2) CE(k1,k3) CE(k4,k6) CE(k5,k7) \
        CE(k1,k2) CE(k5,k6) \
        CE(k0,k4) CE(k1,k5) CE(k2,k6) CE(k3,k7) \
        CE(k2,k4) CE(k3,k5) \
        CE(k1,k2) CE(k3,k4) CE(k5,k6) \
        if (k0 > l11) { \
            /* half-cleaner pairing: l := top-12 multiset, l bitonic */ \
            CE(l11,k0) CE(l10,k1) CE(l9,k2) CE(l8,k3) \
            CE(l7,k4)  CE(l6,k5)  CE(l5,k6) CE(l4,k7) \
            /* bitonic-12 resort, descending */ \
            CE(l0,l6) CE(l1,l7) CE(l2,l8) CE(l3,l9) CE(l4,l10) CE(l5,l11) \
            CE(l0,l3) CE(l1,l4) CE(l2,l5) CE(l6,l9) CE(l7,l10) CE(l8,l11) \
            CE(l0,l1) CE(l0,l2) CE(l1,l2)  CE(l3,l4) CE(l3,l5) CE(l4,l5) \
            CE(l6,l7) CE(l6,l8) CE(l7,l8)  CE(l9,l10) CE(l9,l11) CE(l10,l11) \
        } }

    for (int t = 0; t < 64; t += 2) {
        SUBITER(A00, A01, A10, A11, Ae0, Ae1, t,     t + 2)
        SUBITER(B00, B01, B10, B11, Be0, Be1, t + 1, t + 3)
    }
#undef SUBITER
#undef CE
#undef LOADP

    // dump: decode packed -> global code id
    // code = cbase + t*32 + h*16 + q*4 + reg, tidx = (t<<3)|(h<<2)|reg
    unsigned short* cr = cand + (size_t)row * CANDS + w * 48 + q * 12;
#define DUMP(K, LK) { const unsigned t9 = (LK) & 0x1FFu; \
        cr[K] = (unsigned short)(cbase + ((t9 >> 3) << 5) + (((t9 >> 2) & 1u) << 4) \
                                 + (q << 2) + (t9 & 3u)); }
    DUMP(0, l0)  DUMP(1, l1)  DUMP(2, l2)  DUMP(3, l3)
    DUMP(4, l4)  DUMP(5, l5)  DUMP(6, l6)  DUMP(7, l7)
    DUMP(8, l8)  DUMP(9, l9)  DUMP(10, l10) DUMP(11, l11)
#undef DUMP
}

// ---------------------------------------------------------------------------
// Kernel 2: fp64 re-rank of 192 candidates (lane-quad per candidate, 3-deep
// pipelined gathers), wave-wide top-10 by (d, idx) via shuffle butterflies,
// Gumbel-max sample. Scattered-bin global histogram atomics (low contention)
// + per-block loss/valid partials (no hot-line atomics). (unchanged from r8)
// ---------------------------------------------------------------------------
__global__ __launch_bounds__(256) void vq_finalize(const float* __restrict__ inp,
                                                   const float* __restrict__ cb,
                                                   const double* __restrict__ e2d,
                                                   const float* __restrict__ gumbel,
                                                   const unsigned short* __restrict__ cand,
                                                   float* __restrict__ out,
                                                   int* __restrict__ hist,
                                                   double* __restrict__ lossp,
                                                   int* __restrict__ nvp) {
    __shared__ double dvs[4][CANDS];
    __shared__ int    dis[4][CANDS];
    __shared__ double wl[4];
    __shared__ int    wv[4];

    const int tid  = threadIdx.x;
    const int w    = tid >> 6;
    const int lane = tid & 63;
    const int row  = blockIdx.x * 4 + w;
    const int g    = lane >> 2;   // quad id 0..15
    const int lq   = lane & 3;    // quarter within quad

    const float xf = inp[(size_t)row * EMB_DIM + lane];
    const double xd = (double)xf;

    // wave-wide ||x||^2 in fp64
    double x2 = xd * xd;
#pragma unroll
    for (int off = 32; off >= 1; off >>= 1) x2 += __shfl_xor(x2, off);
    const bool valid = sqrt(x2) > 1e-6;

    // lane's fp64 x-slice: dims [lq*16, lq*16+16) in registers
    double xq[16];
    {
        const float4* xp = (const float4*)(inp + (size_t)row * EMB_DIM + (lq << 4));
#pragma unroll
        for (int i = 0; i < 4; ++i) {
            const float4 v = xp[i];
            xq[4 * i + 0] = (double)v.x; xq[4 * i + 1] = (double)v.y;
            xq[4 * i + 2] = (double)v.z; xq[4 * i + 3] = (double)v.w;
        }
    }

    // hoisted candidate ids for this lane's quad (12 independent loads)
    int cid[12];
    {
        const unsigned short* crow = cand + (size_t)row * CANDS;
#pragma unroll
        for (int r = 0; r < 12; ++r) cid[r] = (int)crow[16 * r + g];
    }

    // software-pipelined gathers, depth 3 (buffers A,B,C rotate)
    float4 gA0, gA1, gA2, gA3, gB0, gB1, gB2, gB3, gC0, gC1, gC2, gC3;
#define GLOAD(S0,S1,S2,S3, R) { \
        const float4* ep_ = (const float4*)(cb + ((size_t)cid[R] << 6) + (lq << 4)); \
        S0 = ep_[0]; S1 = ep_[1]; S2 = ep_[2]; S3 = ep_[3]; }
    GLOAD(gA0,gA1,gA2,gA3, 0)
    GLOAD(gB0,gB1,gB2,gB3, 1)
    GLOAD(gC0,gC1,gC2,gC3, 2)

#define ROUND(R, S0,S1,S2,S3, PR) { \
        const float4 v0_ = S0, v1_ = S1, v2_ = S2, v3_ = S3; \
        if ((PR) < 12) { GLOAD(S0,S1,S2,S3, PR) } \
        double d0_ = 0.0, d1_ = 0.0; \
        d0_ = fma(xq[0],  (double)v0_.x, d0_); d0_ = fma(xq[1],  (double)v0_.y, d0_); \
        d0_ = fma(xq[2],  (double)v0_.z, d0_); d0_ = fma(xq[3],  (double)v0_.w, d0_); \
        d0_ = fma(xq[4],  (double)v1_.x, d0_); d0_ = fma(xq[5],  (double)v1_.y, d0_); \
        d0_ = fma(xq[6],  (double)v1_.z, d0_); d0_ = fma(xq[7],  (double)v1_.w, d0_); \
        d1_ = fma(xq[8],  (double)v2_.x, d1_); d1_ = fma(xq[9],  (double)v2_.y, d1_); \
        d1_ = fma(xq[10], (double)v2_.z, d1_); d1_ = fma(xq[11], (double)v2_.w, d1_); \
        d1_ = fma(xq[12], (double)v3_.x, d1_); d1_ = fma(xq[13], (double)v3_.y, d1_); \
        d1_ = fma(xq[14], (double)v3_.z, d1_); d1_ = fma(xq[15], (double)v3_.w, d1_); \
        double dot_ = d0_ + d1_; \
        dot_ += __shfl_xor(dot_, 1); \
        dot_ += __shfl_xor(dot_, 2); \
        if (lq == 0) { \
            dvs[w][16 * (R) + g] = x2 + e2d[cid[R]] - 2.0 * dot_; \
            dis[w][16 * (R) + g] = cid[R]; \
        } }

    ROUND(0,  gA0,gA1,gA2,gA3, 3)
    ROUND(1,  gB0,gB1,gB2,gB3, 4)
    ROUND(2,  gC0,gC1,gC2,gC3, 5)
    ROUND(3,  gA0,gA1,gA2,gA3, 6)
    ROUND(4,  gB0,gB1,gB2,gB3, 7)
    ROUND(5,  gC0,gC1,gC2,gC3, 8)
    ROUND(6,  gA0,gA1,gA2,gA3, 9)
    ROUND(7,  gB0,gB1,gB2,gB3, 10)
    ROUND(8,  gC0,gC1,gC2,gC3, 11)
    ROUND(9,  gA0,gA1,gA2,gA3, 12)
    ROUND(10, gB0,gB1,gB2,gB3, 12)
    ROUND(11, gC0,gC1,gC2,gC3, 12)
#undef ROUND
#undef GLOAD
    __syncthreads();

    // 3 candidates per lane; 10 wave-wide min-extractions by (d, idx).
    double cd[3]; int ci[3];
#pragma unroll
    for (int m = 0; m < 3; ++m) { cd[m] = dvs[w][lane + 64 * m]; ci[m] = dis[w][lane + 64 * m]; }

    double seld[TOP_K]; int seli[TOP_K];
#pragma unroll
    for (int k = 0; k < TOP_K; ++k) {
        double bd = cd[0]; int bi = ci[0];
        if (cd[1] < bd || (cd[1] == bd && ci[1] < bi)) { bd = cd[1]; bi = ci[1]; }
        if (cd[2] < bd || (cd[2] == bd && ci[2] < bi)) { bd = cd[2]; bi = ci[2]; }
#pragma unroll
        for (int off = 1; off < 64; off <<= 1) {
            const double od = __shfl_xor(bd, off);
            const int    oi = __shfl_xor(bi, off);
            if (od < bd || (od == bd && oi < bi)) { bd = od; bi = oi; }
        }
        seld[k] = bd; seli[k] = bi;   // uniform across wave
        if (ci[0] == bi) cd[0] = 1.0e300;
        if (ci[1] == bi) cd[1] = 1.0e300;
        if (ci[2] == bi) cd[2] = 1.0e300;
    }

    // Gumbel-max over top-10 (argmax keeps first max, like jnp.argmax)
    float gv = 0.0f;
    if (lane < TOP_K) gv = gumbel[(size_t)row * TOP_K + lane];
    float bestsc = -3.0e38f; double bestd = 0.0; int besti = 0;
#pragma unroll
    for (int k = 0; k < TOP_K; ++k) {
        const float gk = __shfl(gv, k);
        const float sc = (float)(-seld[k]) + gk;
        if (sc > bestsc) { bestsc = sc; bestd = seld[k]; besti = seli[k]; }
    }
    const int   cidx = besti;           // uniform
    const float mind = (float)bestd;

    const float vm = valid ? 1.0f : 0.0f;
    const float qv = cb[(size_t)cidx * EMB_DIM + lane];
    out[QST_OFF + (size_t)row * EMB_DIM + lane] = xf + (qv * vm - xf);

    // loss term uses UNMASKED q_valid, masked by vm
    const double dq = (double)qv - xd;
    double l = dq * dq * (double)vm;
#pragma unroll
    for (int off = 32; off >= 1; off >>= 1) l += __shfl_xor(l, off);

    if (lane == 0) {
        wl[w] = l;
        wv[w] = valid ? 1 : 0;
        if (valid) atomicAdd(&hist[cidx], 1);   // scattered bins, low contention
        out[IDX_OFF + row]  = valid ? (float)cidx : 0.0f;
        out[MIND_OFF + row] = valid ? mind : 0.0f;
    }
    __syncthreads();
    if (tid == 0) {
        lossp[blockIdx.x] = wl[0] + wl[1] + wl[2] + wl[3];
        nvp[blockIdx.x]   = wv[0] + wv[1] + wv[2] + wv[3];
    }
}

// ---------------------------------------------------------------------------
// Kernel 3: reduce per-block partials + histogram entropy -> scalars.
// Single block, 256 threads, ~80 KB of reads.
// ---------------------------------------------------------------------------
__global__ __launch_bounds__(256) void vq_scalars(const double* __restrict__ lossp,
                                                  const int* __restrict__ nvp,
                                                  const int* __restrict__ hist,
                                                  float* __restrict__ out) {
    __shared__ double red[256];
    __shared__ double s_nv;
    const int tid = threadIdx.x;

    double lsum = 0.0;
    int    nvl  = 0;
#pragma unroll
    for (int i = 0; i < 16; ++i) {
        const int j = tid + 256 * i;   // 4096 partials
        lsum += lossp[j];
        nvl  += nvp[j];
    }

    red[tid] = lsum;
    __syncthreads();
    for (int s = 128; s >= 1; s >>= 1) {
        if (tid < s) red[tid] += red[tid + s];
        __syncthreads();
    }
    const double losstot = red[0];
    __syncthreads();

    red[tid] = (double)nvl;
    __syncthreads();
    for (int s = 128; s >= 1; s >>= 1) {
        if (tid < s) red[tid] += red[tid + s];
        __syncthreads();
    }
    if (tid == 0) s_nv = (red[0] > 0.5) ? red[0] : 1.0;
    __syncthreads();
    const double nv = s_nv;
    __syncthreads();

    double h = 0.0;
    for (int k = tid; k < NUM_EMB; k += 256) {
        const double p = (double)hist[k] / nv;
        h += p * log(p + 1e-10);
    }
    red[tid] = h;
    __syncthreads();
    for (int s = 128; s >= 1; s >>= 1) {
        if (tid < s) red[tid] += red[tid + s];
        __syncthreads();
    }
    if (tid == 0) {
        const double H = red[0];                 // sum p*log(p+1e-10)
        const double perp = exp(-H);
        const double ploss = -log(perp + 1e-10);
        const double lvq = losstot / (nv * (double)EMB_DIM);
        out[LOSS_OFF] = (float)(lvq + PERP_W * ploss);
        out[PERP_OFF] = (float)perp;
    }
}

// ---------------------------------------------------------------------------
extern "C" void kernel_launch(void* const* d_in, const int* in_sizes, int n_in,
                              void* d_out, int out_size, void* d_ws, size_t ws_size,
                              hipStream_t stream) {
    const float* inp    = (const float*)d_in[0];  // [16384, 64]
    const float* cb     = (const float*)d_in[1];  // [8192, 64]
    const float* gumbel = (const float*)d_in[2];  // [16384, 10]
    float* out = (float*)d_out;

    char* ws = (char*)d_ws;
    float*          e2c   = (float*)(ws + WS_E2C);
    double*         e2d   = (double*)(ws + WS_E2D);
    unsigned short* cb16  = (unsigned short*)(ws + WS_CB16);
    int*            hist  = (int*)(ws + WS_HIST);
    double*         lossp = (double*)(ws + WS_LOSSP);
    int*            nvp   = (int*)(ws + WS_NVP);
    unsigned short* candw = (unsigned short*)(ws + WS_CAND);

    vq_prep<<<NUM_EMB / 256, 256, 0, stream>>>(cb, e2c, e2d, cb16, hist);
    vq_gemm_topk<<<N_ROWS / 16, 256, 0, stream>>>(inp, cb16, e2c, candw);
    vq_finalize<<<N_ROWS / 4, 256, 0, stream>>>(inp, cb, e2d, gumbel, candw, out,
                                                hist, lossp, nvp);
    vq_scalars<<<1, 256, 0, stream>>>(lossp, nvp, hist, out);
}

// Round 10
// 289.295 us; speedup vs baseline: 103.6315x; 1.0914x over previous
//
#include <hip/hip_runtime.h>
#include <hip/hip_bf16.h>

// Problem constants
#define N_ROWS   16384      // 8*2048
#define EMB_DIM  64
#define NUM_EMB  8192
#define TOP_K    10
#define PERP_W   0.01

// Pass-1: 8 chunks of 1024 codes (one per wave, all 8 chunks of a row in ONE
// 512-thread block); within a chunk each lane-quad owns a disjoint quarter of
// every 16-code tile (256 codes/lane); per-lane top-12 in registers as packed
// u32 = (23-bit positive-float score bits | 9-bit subset-local idx). 32 subsets
// x 12 = 384 keys/row -> LDS -> per-row top-16 by key (u64 butterfly
// extraction) -> 16 candidate codes/row. Containment: a true top-10 item has
// <=9 global betters so subset rank <=10 (M=12, margin 2 — unchanged from the
// 6x absmax-0.0 rounds); key-top-16-of-384 then needs 6 rank leapfrogs against
// ~1.0 cumulative spacing vs <=0.1 key noise. fp64 re-rank restores exactness.
#define M_CHUNK   12

// Output layout (all float32, concatenated in return order)
#define QST_OFF   0
#define LOSS_OFF  (N_ROWS * EMB_DIM)                 // 1048576
#define IDX_OFF   (LOSS_OFF + 1)                     // 1048577
#define MIND_OFF  (IDX_OFF + N_ROWS)                 // 1064961
#define PERP_OFF  (MIND_OFF + N_ROWS)                // 1081345

// ws layout (bytes)
#define WS_E2C    0                                  // 8192 f32 = 512-||e||^2/2 (32 KB)
#define WS_E2D    32768                              // 8192 f64   (64 KB)
#define WS_CB16   98304                              // 8192*64 bf16 (1 MB)
#define WS_HIST   1146880                            // 8192 i32  (32 KB)
#define WS_LOSSP  1179648                            // 4096 f64  (32 KB)
#define WS_NVP    1212416                            // 4096 i32  (16 KB)
#define WS_C16    1228800                            // 16384*16 u16 (512 KB)

typedef short bf16x8 __attribute__((ext_vector_type(8)));
typedef float f32x4  __attribute__((ext_vector_type(4)));

__device__ __forceinline__ unsigned short f2bf(float f) {
    // round-to-nearest-even fp32 -> bf16 (inputs are finite gaussians)
    unsigned int u = __float_as_uint(f);
    unsigned int r = u + 0x7fffu + ((u >> 16) & 1u);
    return (unsigned short)(r >> 16);
}

// ---------------------------------------------------------------------------
// Kernel 0: prep — 512-||e||^2/2 (fp32, MFMA C-init; keeps all scores
// positive so raw float bits are uint-monotone), ||e||^2 (fp64, pass-2),
// codebook -> bf16, zero histogram. One thread per code row.
// ---------------------------------------------------------------------------
__global__ __launch_bounds__(256) void vq_prep(const float* __restrict__ cb,
                                               float* __restrict__ e2c,
                                               double* __restrict__ e2d,
                                               unsigned short* __restrict__ cb16,
                                               int* __restrict__ hist) {
    const int k = blockIdx.x * 256 + threadIdx.x;   // 0..8191
    hist[k] = 0;
    const float4* rp = (const float4*)(cb + (size_t)k * EMB_DIM);
    float  s  = 0.0f;
    double sd = 0.0;
#pragma unroll
    for (int i = 0; i < 16; ++i) {
        const float4 v = rp[i];
        s += v.x * v.x + v.y * v.y + v.z * v.z + v.w * v.w;
        sd += (double)v.x * (double)v.x + (double)v.y * (double)v.y
            + (double)v.z * (double)v.z + (double)v.w * (double)v.w;
        unsigned long long p =
              (unsigned long long)f2bf(v.x)
            | ((unsigned long long)f2bf(v.y) << 16)
            | ((unsigned long long)f2bf(v.z) << 32)
            | ((unsigned long long)f2bf(v.w) << 48);
        *(unsigned long long*)(cb16 + (size_t)k * EMB_DIM + 4 * i) = p;
    }
    e2c[k] = 512.0f - 0.5f * s;   // score s' = dot + 512 - e2/2 > 0 always
    e2d[k] = sd;
}

// ---------------------------------------------------------------------------
// Kernel 1: MFMA distance GEMM + per-lane register top-12 + in-block per-row
// key-top-16. Block = 512 threads = 8 waves = 16 rows; wave w owns code chunk
// [w*1024,(w+1)*1024) -> 32 waves/CU (VGPR 52, LDS 24.6 KB). Main loop, key
// packing and merge network identical to the verified r9 kernel.
// ---------------------------------------------------------------------------
__global__ __launch_bounds__(512) void vq_gemm_topk(
        const float* __restrict__ inp, const unsigned short* __restrict__ cb16,
        const float* __restrict__ e2c, unsigned short* __restrict__ cand16) {
    __shared__ unsigned keysh[16][385];   // [row][slot], padded stride 385

    const int tid   = threadIdx.x;
    const int w     = tid >> 6;        // chunk 0..7
    const int lane  = tid & 63;
    const int q     = lane >> 4;       // quad: k-slice for A/B, code subgroup for D
    const int rsub  = lane & 15;
    const int row0  = blockIdx.x * 16;
    const int row   = row0 + rsub;
    const int cbase = w * 1024;

    // B fragments (this lane's row, k = q*8+j and +32), fp32 -> bf16
    bf16x8 b0, b1;
    {
        const float* xp = inp + (size_t)row * EMB_DIM + q * 8;
#pragma unroll
        for (int j = 0; j < 8; ++j) b0[j] = (short)f2bf(xp[j]);
#pragma unroll
        for (int j = 0; j < 8; ++j) b1[j] = (short)f2bf(xp[32 + j]);
    }

    // sorted-desc register list of packed (score|idx); l0 best, l11 worst
    unsigned l0=0,l1=0,l2=0,l3=0,l4=0,l5=0,l6=0,l7=0,l8=0,l9=0,l10=0,l11=0;

    // A / e2 base pointers (per-lane)
    const unsigned short* abase = cb16 + ((size_t)(cbase + rsub) << 6) + (q << 3);
    const float*          ebase = e2c + cbase + (q << 2);

#define LOADP(P0,P1,P2,P3,E0,E1,TT) { \
        const unsigned short* ab_ = abase + (size_t)(TT) * 2048; \
        P0 = *(const bf16x8*)(ab_); \
        P1 = *(const bf16x8*)(ab_ + 32); \
        P2 = *(const bf16x8*)(ab_ + 1024); \
        P3 = *(const bf16x8*)(ab_ + 1024 + 32); \
        const float* eb_ = ebase + (TT) * 32; \
        E0 = *(const f32x4*)(eb_); \
        E1 = *(const f32x4*)(eb_ + 16); }

    bf16x8 A00, A01, A10, A11, B00, B01, B10, B11;
    f32x4  Ae0, Ae1, Be0, Be1;
    LOADP(A00, A01, A10, A11, Ae0, Ae1, 0)
    LOADP(B00, B01, B10, B11, Be0, Be1, 1)

    // descending compare-exchange: max to first operand
#define CE(A,B) { const unsigned a_ = A, b_ = B; \
                  A = a_ > b_ ? a_ : b_; B = a_ > b_ ? b_ : a_; }

#define SUBITER(P0,P1,P2,P3,E0,E1,TT,TP) { \
        const bf16x8 c00_ = P0, c01_ = P1, c10_ = P2, c11_ = P3; \
        const f32x4  ce0_ = E0, ce1_ = E1; \
        LOADP(P0, P1, P2, P3, E0, E1, (TP) & 31) \
        f32x4 acc0_ = __builtin_amdgcn_mfma_f32_16x16x32_bf16(c00_, b0, ce0_, 0, 0, 0); \
        acc0_       = __builtin_amdgcn_mfma_f32_16x16x32_bf16(c01_, b1, acc0_, 0, 0, 0); \
        f32x4 acc1_ = __builtin_amdgcn_mfma_f32_16x16x32_bf16(c10_, b0, ce1_, 0, 0, 0); \
        acc1_       = __builtin_amdgcn_mfma_f32_16x16x32_bf16(c11_, b1, acc1_, 0, 0, 0); \
        const unsigned tb_ = (unsigned)((TT) << 3); \
        unsigned k0 = (__float_as_uint(acc0_[0]) & 0xFFFFFE00u) | (tb_ + 0u); \
        unsigned k1 = (__float_as_uint(acc0_[1]) & 0xFFFFFE00u) | (tb_ + 1u); \
        unsigned k2 = (__float_as_uint(acc0_[2]) & 0xFFFFFE00u) | (tb_ + 2u); \
        unsigned k3 = (__float_as_uint(acc0_[3]) & 0xFFFFFE00u) | (tb_ + 3u); \
        unsigned k4 = (__float_as_uint(acc1_[0]) & 0xFFFFFE00u) | (tb_ + 4u); \
        unsigned k5 = (__float_as_uint(acc1_[1]) & 0xFFFFFE00u) | (tb_ + 5u); \
        unsigned k6 = (__float_as_uint(acc1_[2]) & 0xFFFFFE00u) | (tb_ + 6u); \
        unsigned k7 = (__float_as_uint(acc1_[3]) & 0xFFFFFE00u) | (tb_ + 7u); \
        /* Batcher odd-even mergesort, 8 keys, descending (19 CE) */ \
        CE(k0,k1) CE(k2,k3) CE(k4,k5) CE(k6,k7) \
        CE(k0,k2) CE(k1,k3) CE(k4,k6) CE(k5,k7) \
        CE(k1,k2) CE(k5,k6) \
        CE(k0,k4) CE(k1,k5) CE(k2,k6) CE(k3,k7) \
        CE(k2,k4) CE(k3,k5) \
        CE(k1,k2) CE(k3,k4) CE(k5,k6) \
        if (k0 > l11) { \
            /* half-cleaner pairing: l := top-12 multiset, l bitonic */ \
            CE(l11,k0) CE(l10,k1) CE(l9,k2) CE(l8,k3) \
            CE(l7,k4)  CE(l6,k5)  CE(l5,k6) CE(l4,k7) \
            /* bitonic-12 resort, descending */ \
            CE(l0,l6) CE(l1,l7) CE(l2,l8) CE(l3,l9) CE(l4,l10) CE(l5,l11) \
            CE(l0,l3) CE(l1,l4) CE(l2,l5) CE(l6,l9) CE(l7,l10) CE(l8,l11) \
            CE(l0,l1) CE(l0,l2) CE(l1,l2)  CE(l3,l4) CE(l3,l5) CE(l4,l5) \
            CE(l6,l7) CE(l6,l8) CE(l7,l8)  CE(l9,l10) CE(l9,l11) CE(l10,l11) \
        } }

    for (int t = 0; t < 32; t += 2) {
        SUBITER(A00, A01, A10, A11, Ae0, Ae1, t,     t + 2)
        SUBITER(B00, B01, B10, B11, Be0, Be1, t + 1, t + 3)
    }
#undef SUBITER
#undef CE
#undef LOADP

    // dump keys to LDS: slot = w*48 + q*12 + k
    {
        unsigned* kr = &keysh[rsub][w * 48 + q * 12];
        kr[0]=l0; kr[1]=l1; kr[2]=l2;  kr[3]=l3;
        kr[4]=l4; kr[5]=l5; kr[6]=l6;  kr[7]=l7;
        kr[8]=l8; kr[9]=l9; kr[10]=l10; kr[11]=l11;
    }
    __syncthreads();

    // per-row key-top-16: wave w handles local rows 2w, 2w+1.
    // v = (key << 9) | slot  (slot<384 -> unique -> total order).
#define U64MAX(A,B) ((A) > (B) ? (A) : (B))
    for (int rr = 0; rr < 2; ++rr) {
        const int lr = 2 * w + rr;
        unsigned long long v0 = ((unsigned long long)keysh[lr][lane      ] << 9) | (unsigned)(lane      );
        unsigned long long v1 = ((unsigned long long)keysh[lr][lane + 64 ] << 9) | (unsigned)(lane + 64 );
        unsigned long long v2 = ((unsigned long long)keysh[lr][lane + 128] << 9) | (unsigned)(lane + 128);
        unsigned long long v3 = ((unsigned long long)keysh[lr][lane + 192] << 9) | (unsigned)(lane + 192);
        unsigned long long v4 = ((unsigned long long)keysh[lr][lane + 256] << 9) | (unsigned)(lane + 256);
        unsigned long long v5 = ((unsigned long long)keysh[lr][lane + 320] << 9) | (unsigned)(lane + 320);
        unsigned long long kept = 0;
#pragma unroll
        for (int round = 0; round < 16; ++round) {
            unsigned long long gm =
                U64MAX(U64MAX(U64MAX(v0, v1), U64MAX(v2, v3)), U64MAX(v4, v5));
#pragma unroll
            for (int off = 1; off < 64; off <<= 1) {
                const unsigned long long om = __shfl_xor(gm, off);
                gm = U64MAX(gm, om);
            }
            if (round == lane) kept = gm;
            if (v0 == gm) v0 = 0; if (v1 == gm) v1 = 0; if (v2 == gm) v2 = 0;
            if (v3 == gm) v3 = 0; if (v4 == gm) v4 = 0; if (v5 == gm) v5 = 0;
        }
        if (lane < 16) {
            const unsigned j   = (unsigned)(kept & 511ull);
            const unsigned key = (unsigned)(kept >> 9);
            const unsigned t9  = key & 511u;
            const unsigned wq  = j / 48u;
            const unsigned qq  = (j % 48u) / 12u;
            const unsigned code = wq * 1024u + ((t9 >> 3) << 5)
                                + (((t9 >> 2) & 1u) << 4) + (qq << 2) + (t9 & 3u);
            cand16[(size_t)(row0 + lr) * 16 + lane] = (unsigned short)code;
        }
    }
#undef U64MAX
}

// ---------------------------------------------------------------------------
// Kernel 2: fp64 re-rank of the 16 key-selected candidates (one lane-quad per
// candidate), wave-wide top-10 by (d, idx) via shuffle butterflies, Gumbel-max
// sample, outputs, scattered-bin histogram atomics + per-block partials.
// One wave per row; 4 rows per 256-thread block.
// ---------------------------------------------------------------------------
__global__ __launch_bounds__(256) void vq_finalize(const float* __restrict__ inp,
                                                   const float* __restrict__ cb,
                                                   const double* __restrict__ e2d,
                                                   const float* __restrict__ gumbel,
                                                   const unsigned short* __restrict__ cand16,
                                                   float* __restrict__ out,
                                                   int* __restrict__ hist,
                                                   double* __restrict__ lossp,
                                                   int* __restrict__ nvp) {
    __shared__ double wl[4];
    __shared__ int    wv[4];

    const int tid  = threadIdx.x;
    const int w    = tid >> 6;
    const int lane = tid & 63;
    const int row  = blockIdx.x * 4 + w;
    const int g    = lane >> 2;   // quad id 0..15 -> candidate id
    const int lq   = lane & 3;    // quarter within quad

    const float xf = inp[(size_t)row * EMB_DIM + lane];
    const double xd = (double)xf;

    // wave-wide ||x||^2 in fp64
    double x2 = xd * xd;
#pragma unroll
    for (int off = 32; off >= 1; off >>= 1) x2 += __shfl_xor(x2, off);
    const bool valid = sqrt(x2) > 1e-6;

    // lane's fp64 x-slice: dims [lq*16, lq*16+16) in registers
    double xq[16];
    {
        const float4* xp = (const float4*)(inp + (size_t)row * EMB_DIM + (lq << 4));
#pragma unroll
        for (int i = 0; i < 4; ++i) {
            const float4 v = xp[i];
            xq[4 * i + 0] = (double)v.x; xq[4 * i + 1] = (double)v.y;
            xq[4 * i + 2] = (double)v.z; xq[4 * i + 3] = (double)v.w;
        }
    }

    // this quad's candidate (broadcast load within quad)
    const int code = (int)cand16[(size_t)row * 16 + g];

    // fp64 dot: quad covers 64 dims (16 per lane), coalesced 64B per quad
    double dg = 1.0e300;
    {
        const float4* ep = (const float4*)(cb + ((size_t)code << 6) + (lq << 4));
        const float4 e0 = ep[0], e1 = ep[1], e2v = ep[2], e3 = ep[3];
        double d0 = 0.0, d1 = 0.0;
        d0 = fma(xq[0],  (double)e0.x, d0);  d0 = fma(xq[1],  (double)e0.y, d0);
        d0 = fma(xq[2],  (double)e0.z, d0);  d0 = fma(xq[3],  (double)e0.w, d0);
        d0 = fma(xq[4],  (double)e1.x, d0);  d0 = fma(xq[5],  (double)e1.y, d0);
        d0 = fma(xq[6],  (double)e1.z, d0);  d0 = fma(xq[7],  (double)e1.w, d0);
        d1 = fma(xq[8],  (double)e2v.x, d1); d1 = fma(xq[9],  (double)e2v.y, d1);
        d1 = fma(xq[10], (double)e2v.z, d1); d1 = fma(xq[11], (double)e2v.w, d1);
        d1 = fma(xq[12], (double)e3.x, d1);  d1 = fma(xq[13], (double)e3.y, d1);
        d1 = fma(xq[14], (double)e3.z, d1);  d1 = fma(xq[15], (double)e3.w, d1);
        double dot = d0 + d1;
        dot += __shfl_xor(dot, 1);
        dot += __shfl_xor(dot, 2);
        if (lq == 0) dg = x2 + e2d[code] - 2.0 * dot;
    }

    // 10 wave-wide min-extractions by (d, idx) — JAX top_k order + tie-break.
    double cd = dg;
    int    ci = (lq == 0) ? code : 0x7fffffff;
    double seld[TOP_K]; int seli[TOP_K];
#pragma unroll
    for (int k = 0; k < TOP_K; ++k) {
        double bd = cd; int bi = ci;
#pragma unroll
        for (int off = 1; off < 64; off <<= 1) {
            const double od = __shfl_xor(bd, off);
            const int    oi = __shfl_xor(bi, off);
            if (od < bd || (od == bd && oi < bi)) { bd = od; bi = oi; }
        }
        seld[k] = bd; seli[k] = bi;   // uniform across wave
        if (ci == bi) cd = 1.0e300;
    }

    // Gumbel-max over top-10 (argmax keeps first max, like jnp.argmax)
    float gv = 0.0f;
    if (lane < TOP_K) gv = gumbel[(size_t)row * TOP_K + lane];
    float bestsc = -3.0e38f; double bestd = 0.0; int besti = 0;
#pragma unroll
    for (int k = 0; k < TOP_K; ++k) {
        const float gk = __shfl(gv, k);
        const float sc = (float)(-seld[k]) + gk;
        if (sc > bestsc) { bestsc = sc; bestd = seld[k]; besti = seli[k]; }
    }
    const int   cidx = besti;           // uniform
    const float mind = (float)bestd;

    const float vm = valid ? 1.0f : 0.0f;
    const float qv = cb[(size_t)cidx * EMB_DIM + lane];
    out[QST_OFF + (size_t)row * EMB_DIM + lane] = xf + (qv * vm - xf);

    // loss term uses UNMASKED q_valid, masked by vm
    const double dq = (double)qv - xd;
    double l = dq * dq * (double)vm;
#pragma unroll
    for (int off = 32; off >= 1; off >>= 1) l += __shfl_xor(l, off);

    if (lane == 0) {
        wl[w] = l;
        wv[w] = valid ? 1 : 0;
        if (valid) atomicAdd(&hist[cidx], 1);   // scattered bins, low contention
        out[IDX_OFF + row]  = valid ? (float)cidx : 0.0f;
        out[MIND_OFF + row] = valid ? mind : 0.0f;
    }
    __syncthreads();
    if (tid == 0) {
        lossp[blockIdx.x] = wl[0] + wl[1] + wl[2] + wl[3];
        nvp[blockIdx.x]   = wv[0] + wv[1] + wv[2] + wv[3];
    }
}

// ---------------------------------------------------------------------------
// Kernel 3: reduce per-block partials + histogram entropy -> scalars.
// Single block, 256 threads, ~80 KB of reads.
// ---------------------------------------------------------------------------
__global__ __launch_bounds__(256) void vq_scalars(const double* __restrict__ lossp,
                                                  const int* __restrict__ nvp,
                                                  const int* __restrict__ hist,
                                                  float* __restrict__ out) {
    __shared__ double red[256];
    __shared__ double s_nv;
    const int tid = threadIdx.x;

    double lsum = 0.0;
    int    nvl  = 0;
#pragma unroll
    for (int i = 0; i < 16; ++i) {
        const int j = tid + 256 * i;   // 4096 partials
        lsum += lossp[j];
        nvl  += nvp[j];
    }

    red[tid] = lsum;
    __syncthreads();
    for (int s = 128; s >= 1; s >>= 1) {
        if (tid < s) red[tid] += red[tid + s];
        __syncthreads();
    }
    const double losstot = red[0];
    __syncthreads();

    red[tid] = (double)nvl;
    __syncthreads();
    for (int s = 128; s >= 1; s >>= 1) {
        if (tid < s) red[tid] += red[tid + s];
        __syncthreads();
    }
    if (tid == 0) s_nv = (red[0] > 0.5) ? red[0] : 1.0;
    __syncthreads();
    const double nv = s_nv;
    __syncthreads();

    double h = 0.0;
    for (int k = tid; k < NUM_EMB; k += 256) {
        const double p = (double)hist[k] / nv;
        h += p * log(p + 1e-10);
    }
    red[tid] = h;
    __syncthreads();
    for (int s = 128; s >= 1; s >>= 1) {
        if (tid < s) red[tid] += red[tid + s];
        __syncthreads();
    }
    if (tid == 0) {
        const double H = red[0];                 // sum p*log(p+1e-10)
        const double perp = exp(-H);
        const double ploss = -log(perp + 1e-10);
        const double lvq = losstot / (nv * (double)EMB_DIM);
        out[LOSS_OFF] = (float)(lvq + PERP_W * ploss);
        out[PERP_OFF] = (float)perp;
    }
}

// ---------------------------------------------------------------------------
extern "C" void kernel_launch(void* const* d_in, const int* in_sizes, int n_in,
                              void* d_out, int out_size, void* d_ws, size_t ws_size,
                              hipStream_t stream) {
    const float* inp    = (const float*)d_in[0];  // [16384, 64]
    const float* cb     = (const float*)d_in[1];  // [8192, 64]
    const float* gumbel = (const float*)d_in[2];  // [16384, 10]
    float* out = (float*)d_out;

    char* ws = (char*)d_ws;
    float*          e2c    = (float*)(ws + WS_E2C);
    double*         e2d    = (double*)(ws + WS_E2D);
    unsigned short* cb16   = (unsigned short*)(ws + WS_CB16);
    int*            hist   = (int*)(ws + WS_HIST);
    double*         lossp  = (double*)(ws + WS_LOSSP);
    int*            nvp    = (int*)(ws + WS_NVP);
    unsigned short* cand16 = (unsigned short*)(ws + WS_C16);

    vq_prep<<<NUM_EMB / 256, 256, 0, stream>>>(cb, e2c, e2d, cb16, hist);
    vq_gemm_topk<<<N_ROWS / 16, 512, 0, stream>>>(inp, cb16, e2c, cand16);
    vq_finalize<<<N_ROWS / 4, 256, 0, stream>>>(inp, cb, e2d, gumbel, cand16, out,
                                                hist, lossp, nvp);
    vq_scalars<<<1, 256, 0, stream>>>(lossp, nvp, hist, out);
}

// Round 11
// 283.433 us; speedup vs baseline: 105.7747x; 1.0207x over previous
//
#include <hip/hip_runtime.h>
#include <hip/hip_bf16.h>

// Problem constants
#define N_ROWS   16384      // 8*2048
#define EMB_DIM  64
#define NUM_EMB  8192
#define TOP_K    10
#define PERP_W   0.01

// Pass-1: grid (1024, 2): each block = 256 thr = 4 waves = 16 rows x 4096
// codes (half the codebook). Wave w owns 1024 codes; each lane-quad owns a
// disjoint quarter of every 16-code tile (256 codes/lane); per-lane top-12 in
// registers as packed u32 = (hi-24 positive-float score bits | 8-bit local
// idx). Per block-half: 16 subsets x 12 = 192 keys/row -> LDS -> per-row
// key-top-16 (u32 butterfly extraction, slot-disambiguated) -> 16 codes.
// Union over 2 halves = 32 candidates/row. Containment: true top-10-of-half
// item has <=9 half-betters -> subset rank <=10 (M=12, margin 2) and
// half-key-rank <=10 (top-16, margin 6 vs key noise sigma~0.07 << order-stat
// gaps) — same argument as the 7x absmax-0.0 rounds. fp64 re-rank restores
// exact (d, idx) order.
#define M_CHUNK   12

// Output layout (all float32, concatenated in return order)
#define QST_OFF   0
#define LOSS_OFF  (N_ROWS * EMB_DIM)                 // 1048576
#define IDX_OFF   (LOSS_OFF + 1)                     // 1048577
#define MIND_OFF  (IDX_OFF + N_ROWS)                 // 1064961
#define PERP_OFF  (MIND_OFF + N_ROWS)                // 1081345

// ws layout (bytes)
#define WS_E2C    0                                  // 8192 f32 = 512-||e||^2/2 (32 KB)
#define WS_E2D    32768                              // 8192 f64   (64 KB)
#define WS_CB16   98304                              // 8192*64 bf16 (1 MB)
#define WS_HIST   1146880                            // 8192 i32  (32 KB)
#define WS_LOSSP  1179648                            // 4096 f64  (32 KB)
#define WS_NVP    1212416                            // 4096 i32  (16 KB)
#define WS_C32    1228800                            // 16384*32 u16 (1 MB)

typedef short bf16x8 __attribute__((ext_vector_type(8)));
typedef float f32x4  __attribute__((ext_vector_type(4)));

__device__ __forceinline__ unsigned short f2bf(float f) {
    // round-to-nearest-even fp32 -> bf16 (inputs are finite gaussians)
    unsigned int u = __float_as_uint(f);
    unsigned int r = u + 0x7fffu + ((u >> 16) & 1u);
    return (unsigned short)(r >> 16);
}

// ---------------------------------------------------------------------------
// Kernel 0: prep — 512-||e||^2/2 (fp32, MFMA C-init; keeps all scores
// positive so raw float bits are uint-monotone), ||e||^2 (fp64, pass-2),
// codebook -> bf16, zero histogram. One thread per code row.
// ---------------------------------------------------------------------------
__global__ __launch_bounds__(256) void vq_prep(const float* __restrict__ cb,
                                               float* __restrict__ e2c,
                                               double* __restrict__ e2d,
                                               unsigned short* __restrict__ cb16,
                                               int* __restrict__ hist) {
    const int k = blockIdx.x * 256 + threadIdx.x;   // 0..8191
    hist[k] = 0;
    const float4* rp = (const float4*)(cb + (size_t)k * EMB_DIM);
    float  s  = 0.0f;
    double sd = 0.0;
#pragma unroll
    for (int i = 0; i < 16; ++i) {
        const float4 v = rp[i];
        s += v.x * v.x + v.y * v.y + v.z * v.z + v.w * v.w;
        sd += (double)v.x * (double)v.x + (double)v.y * (double)v.y
            + (double)v.z * (double)v.z + (double)v.w * (double)v.w;
        unsigned long long p =
              (unsigned long long)f2bf(v.x)
            | ((unsigned long long)f2bf(v.y) << 16)
            | ((unsigned long long)f2bf(v.z) << 32)
            | ((unsigned long long)f2bf(v.w) << 48);
        *(unsigned long long*)(cb16 + (size_t)k * EMB_DIM + 4 * i) = p;
    }
    e2c[k] = 512.0f - 0.5f * s;   // score s' = dot + 512 - e2/2 > 0 always
    e2d[k] = sd;
}

// ---------------------------------------------------------------------------
// Kernel 1: MFMA distance GEMM + per-lane register top-12 + per-half per-row
// key-top-16. Block = 256 thr = 4 waves = 16 rows; blockIdx.y = half.
// 8 blocks/CU (LDS 12.4 KB, VGPR ~52) -> 32 waves/CU theoretical.
// ---------------------------------------------------------------------------
__global__ __launch_bounds__(256) void vq_gemm_topk(
        const float* __restrict__ inp, const unsigned short* __restrict__ cb16,
        const float* __restrict__ e2c, unsigned short* __restrict__ cand32) {
    __shared__ unsigned keysh[16][193];   // [row][slot 0..191], pad 193

    const int tid   = threadIdx.x;
    const int w     = tid >> 6;        // wave chunk 0..3
    const int lane  = tid & 63;
    const int q     = lane >> 4;       // quad: k-slice for A/B, code subgroup for D
    const int rsub  = lane & 15;
    const int row0  = blockIdx.x * 16;
    const int row   = row0 + rsub;
    const int half0 = blockIdx.y * 4096;
    const int cbase = half0 + w * 1024;

    // B fragments (this lane's row, k = q*8+j and +32), fp32 -> bf16
    bf16x8 b0, b1;
    {
        const float* xp = inp + (size_t)row * EMB_DIM + q * 8;
#pragma unroll
        for (int j = 0; j < 8; ++j) b0[j] = (short)f2bf(xp[j]);
#pragma unroll
        for (int j = 0; j < 8; ++j) b1[j] = (short)f2bf(xp[32 + j]);
    }

    // sorted-desc register list of packed (score|idx8); l0 best, l11 worst
    unsigned l0=0,l1=0,l2=0,l3=0,l4=0,l5=0,l6=0,l7=0,l8=0,l9=0,l10=0,l11=0;

    // A / e2 base pointers (per-lane)
    const unsigned short* abase = cb16 + ((size_t)(cbase + rsub) << 6) + (q << 3);
    const float*          ebase = e2c + cbase + (q << 2);

#define LOADP(P0,P1,P2,P3,E0,E1,TT) { \
        const unsigned short* ab_ = abase + (size_t)(TT) * 2048; \
        P0 = *(const bf16x8*)(ab_); \
        P1 = *(const bf16x8*)(ab_ + 32); \
        P2 = *(const bf16x8*)(ab_ + 1024); \
        P3 = *(const bf16x8*)(ab_ + 1024 + 32); \
        const float* eb_ = ebase + (TT) * 32; \
        E0 = *(const f32x4*)(eb_); \
        E1 = *(const f32x4*)(eb_ + 16); }

    bf16x8 A00, A01, A10, A11, B00, B01, B10, B11;
    f32x4  Ae0, Ae1, Be0, Be1;
    LOADP(A00, A01, A10, A11, Ae0, Ae1, 0)
    LOADP(B00, B01, B10, B11, Be0, Be1, 1)

    // descending compare-exchange: max to first operand
#define CE(A,B) { const unsigned a_ = A, b_ = B; \
                  A = a_ > b_ ? a_ : b_; B = a_ > b_ ? b_ : a_; }

#define SUBITER(P0,P1,P2,P3,E0,E1,TT,TP) { \
        const bf16x8 c00_ = P0, c01_ = P1, c10_ = P2, c11_ = P3; \
        const f32x4  ce0_ = E0, ce1_ = E1; \
        LOADP(P0, P1, P2, P3, E0, E1, (TP) & 31) \
        f32x4 acc0_ = __builtin_amdgcn_mfma_f32_16x16x32_bf16(c00_, b0, ce0_, 0, 0, 0); \
        acc0_       = __builtin_amdgcn_mfma_f32_16x16x32_bf16(c01_, b1, acc0_, 0, 0, 0); \
        f32x4 acc1_ = __builtin_amdgcn_mfma_f32_16x16x32_bf16(c10_, b0, ce1_, 0, 0, 0); \
        acc1_       = __builtin_amdgcn_mfma_f32_16x16x32_bf16(c11_, b1, acc1_, 0, 0, 0); \
        const unsigned tb_ = (unsigned)((TT) << 3); \
        unsigned k0 = (__float_as_uint(acc0_[0]) & 0xFFFFFF00u) | (tb_ + 0u); \
        unsigned k1 = (__float_as_uint(acc0_[1]) & 0xFFFFFF00u) | (tb_ + 1u); \
        unsigned k2 = (__float_as_uint(acc0_[2]) & 0xFFFFFF00u) | (tb_ + 2u); \
        unsigned k3 = (__float_as_uint(acc0_[3]) & 0xFFFFFF00u) | (tb_ + 3u); \
        unsigned k4 = (__float_as_uint(acc1_[0]) & 0xFFFFFF00u) | (tb_ + 4u); \
        unsigned k5 = (__float_as_uint(acc1_[1]) & 0xFFFFFF00u) | (tb_ + 5u); \
        unsigned k6 = (__float_as_uint(acc1_[2]) & 0xFFFFFF00u) | (tb_ + 6u); \
        unsigned k7 = (__float_as_uint(acc1_[3]) & 0xFFFFFF00u) | (tb_ + 7u); \
        /* Batcher odd-even mergesort, 8 keys, descending (19 CE) */ \
        CE(k0,k1) CE(k2,k3) CE(k4,k5) CE(k6,k7) \
        CE(k0,k2) CE(k1,k3) CE(k4,k6) CE(k5,k7) \
        CE(k1,k2) CE(k5,k6) \
        CE(k0,k4) CE(k1,k5) CE(k2,k6) CE(k3,k7) \
        CE(k2,k4) CE(k3,k5) \
        CE(k1,k2) CE(k3,k4) CE(k5,k6) \
        if (k0 > l11) { \
            /* half-cleaner pairing: l := top-12 multiset, l bitonic */ \
            CE(l11,k0) CE(l10,k1) CE(l9,k2) CE(l8,k3) \
            CE(l7,k4)  CE(l6,k5)  CE(l5,k6) CE(l4,k7) \
            /* bitonic-12 resort, descending */ \
            CE(l0,l6) CE(l1,l7) CE(l2,l8) CE(l3,l9) CE(l4,l10) CE(l5,l11) \
            CE(l0,l3) CE(l1,l4) CE(l2,l5) CE(l6,l9) CE(l7,l10) CE(l8,l11) \
            CE(l0,l1) CE(l0,l2) CE(l1,l2)  CE(l3,l4) CE(l3,l5) CE(l4,l5) \
            CE(l6,l7) CE(l6,l8) CE(l7,l8)  CE(l9,l10) CE(l9,l11) CE(l10,l11) \
        } }

    for (int t = 0; t < 32; t += 2) {
        SUBITER(A00, A01, A10, A11, Ae0, Ae1, t,     t + 2)
        SUBITER(B00, B01, B10, B11, Be0, Be1, t + 1, t + 3)
    }
#undef SUBITER
#undef CE
#undef LOADP

    // dump keys to LDS: slot = w*48 + q*12 + k  (0..191)
    {
        unsigned* kr = &keysh[rsub][w * 48 + q * 12];
        kr[0]=l0; kr[1]=l1; kr[2]=l2;  kr[3]=l3;
        kr[4]=l4; kr[5]=l5; kr[6]=l6;  kr[7]=l7;
        kr[8]=l8; kr[9]=l9; kr[10]=l10; kr[11]=l11;
    }
    __syncthreads();

    // per-row key-top-16 over 192 keys: wave w handles rows 4w..4w+3.
    // vu = (key & ~0xFF) | slot  (slot<192 unique -> total order, u32 only);
    // winner slot -> original key low byte recovers the local code idx.
#define UMAX(A,B) ((A) > (B) ? (A) : (B))
    for (int rr = 0; rr < 4; ++rr) {
        const int lr = 4 * w + rr;
        unsigned v0 = (keysh[lr][lane      ] & 0xFFFFFF00u) | (unsigned)(lane      );
        unsigned v1 = (keysh[lr][lane + 64 ] & 0xFFFFFF00u) | (unsigned)(lane + 64 );
        unsigned v2 = (keysh[lr][lane + 128] & 0xFFFFFF00u) | (unsigned)(lane + 128);
        unsigned kept = 0;
#pragma unroll
        for (int round = 0; round < 16; ++round) {
            unsigned gm = UMAX(v0, UMAX(v1, v2));
#pragma unroll
            for (int off = 1; off < 64; off <<= 1) {
                const unsigned om = __shfl_xor(gm, off);
                gm = UMAX(gm, om);
            }
            if (round == lane) kept = gm;
            if (v0 == gm) v0 = 0;
            if (v1 == gm) v1 = 0;
            if (v2 == gm) v2 = 0;
        }
        if (lane < 16) {
            const unsigned slot = kept & 0xFFu;
            const unsigned idx  = keysh[lr][slot] & 0xFFu;   // local code idx
            const unsigned wq   = slot / 48u;
            const unsigned qq   = (slot % 48u) / 12u;
            const unsigned code = (unsigned)half0 + wq * 1024u
                                + ((idx >> 3) << 5) + (((idx >> 2) & 1u) << 4)
                                + (qq << 2) + (idx & 3u);
            cand32[(size_t)(row0 + lr) * 32 + blockIdx.y * 16 + lane] =
                (unsigned short)code;
        }
    }
#undef UMAX
}

// ---------------------------------------------------------------------------
// Kernel 2: fp64 re-rank of the 32 key-selected candidates (one lane-quad per
// candidate, 2 rounds), wave-wide top-10 by (d, idx) via shuffle butterflies,
// Gumbel-max sample, outputs, scattered-bin histogram atomics + per-block
// partials. One wave per row; 4 rows per 256-thread block.
// ---------------------------------------------------------------------------
__global__ __launch_bounds__(256) void vq_finalize(const float* __restrict__ inp,
                                                   const float* __restrict__ cb,
                                                   const double* __restrict__ e2d,
                                                   const float* __restrict__ gumbel,
                                                   const unsigned short* __restrict__ cand32,
                                                   float* __restrict__ out,
                                                   int* __restrict__ hist,
                                                   double* __restrict__ lossp,
                                                   int* __restrict__ nvp) {
    __shared__ double dvs[4][32];
    __shared__ int    dis[4][32];
    __shared__ double wl[4];
    __shared__ int    wv[4];

    const int tid  = threadIdx.x;
    const int w    = tid >> 6;
    const int lane = tid & 63;
    const int row  = blockIdx.x * 4 + w;
    const int g    = lane >> 2;   // quad id 0..15
    const int lq   = lane & 3;    // quarter within quad

    const float xf = inp[(size_t)row * EMB_DIM + lane];
    const double xd = (double)xf;

    // wave-wide ||x||^2 in fp64
    double x2 = xd * xd;
#pragma unroll
    for (int off = 32; off >= 1; off >>= 1) x2 += __shfl_xor(x2, off);
    const bool valid = sqrt(x2) > 1e-6;

    // lane's fp64 x-slice: dims [lq*16, lq*16+16) in registers
    double xq[16];
    {
        const float4* xp = (const float4*)(inp + (size_t)row * EMB_DIM + (lq << 4));
#pragma unroll
        for (int i = 0; i < 4; ++i) {
            const float4 v = xp[i];
            xq[4 * i + 0] = (double)v.x; xq[4 * i + 1] = (double)v.y;
            xq[4 * i + 2] = (double)v.z; xq[4 * i + 3] = (double)v.w;
        }
    }

    // 2 rounds: quad g handles candidates g and 16+g (coalesced 64B per quad)
#pragma unroll
    for (int r = 0; r < 2; ++r) {
        const int j    = r * 16 + g;
        const int code = (int)cand32[(size_t)row * 32 + j];
        const float4* ep = (const float4*)(cb + ((size_t)code << 6) + (lq << 4));
        const float4 e0 = ep[0], e1 = ep[1], e2v = ep[2], e3 = ep[3];
        double d0 = 0.0, d1 = 0.0;
        d0 = fma(xq[0],  (double)e0.x, d0);  d0 = fma(xq[1],  (double)e0.y, d0);
        d0 = fma(xq[2],  (double)e0.z, d0);  d0 = fma(xq[3],  (double)e0.w, d0);
        d0 = fma(xq[4],  (double)e1.x, d0);  d0 = fma(xq[5],  (double)e1.y, d0);
        d0 = fma(xq[6],  (double)e1.z, d0);  d0 = fma(xq[7],  (double)e1.w, d0);
        d1 = fma(xq[8],  (double)e2v.x, d1); d1 = fma(xq[9],  (double)e2v.y, d1);
        d1 = fma(xq[10], (double)e2v.z, d1); d1 = fma(xq[11], (double)e2v.w, d1);
        d1 = fma(xq[12], (double)e3.x, d1);  d1 = fma(xq[13], (double)e3.y, d1);
        d1 = fma(xq[14], (double)e3.z, d1);  d1 = fma(xq[15], (double)e3.w, d1);
        double dot = d0 + d1;
        dot += __shfl_xor(dot, 1);
        dot += __shfl_xor(dot, 2);
        if (lq == 0) {
            dvs[w][j] = x2 + e2d[code] - 2.0 * dot;
            dis[w][j] = code;
        }
    }
    __syncthreads();

    // one candidate per lane (lane<32), 10 wave-wide min-extractions by (d,idx)
    double cd = (lane < 32) ? dvs[w][lane] : 1.0e300;
    int    ci = (lane < 32) ? dis[w][lane] : 0x7fffffff;

    double seld[TOP_K]; int seli[TOP_K];
#pragma unroll
    for (int k = 0; k < TOP_K; ++k) {
        double bd = cd; int bi = ci;
#pragma unroll
        for (int off = 1; off < 64; off <<= 1) {
            const double od = __shfl_xor(bd, off);
            const int    oi = __shfl_xor(bi, off);
            if (od < bd || (od == bd && oi < bi)) { bd = od; bi = oi; }
        }
        seld[k] = bd; seli[k] = bi;   // uniform across wave
        if (ci == bi) cd = 1.0e300;
    }

    // Gumbel-max over top-10 (argmax keeps first max, like jnp.argmax)
    float gv = 0.0f;
    if (lane < TOP_K) gv = gumbel[(size_t)row * TOP_K + lane];
    float bestsc = -3.0e38f; double bestd = 0.0; int besti = 0;
#pragma unroll
    for (int k = 0; k < TOP_K; ++k) {
        const float gk = __shfl(gv, k);
        const float sc = (float)(-seld[k]) + gk;
        if (sc > bestsc) { bestsc = sc; bestd = seld[k]; besti = seli[k]; }
    }
    const int   cidx = besti;           // uniform
    const float mind = (float)bestd;

    const float vm = valid ? 1.0f : 0.0f;
    const float qv = cb[(size_t)cidx * EMB_DIM + lane];
    out[QST_OFF + (size_t)row * EMB_DIM + lane] = xf + (qv * vm - xf);

    // loss term uses UNMASKED q_valid, masked by vm
    const double dq = (double)qv - xd;
    double l = dq * dq * (double)vm;
#pragma unroll
    for (int off = 32; off >= 1; off >>= 1) l += __shfl_xor(l, off);

    if (lane == 0) {
        wl[w] = l;
        wv[w] = valid ? 1 : 0;
        if (valid) atomicAdd(&hist[cidx], 1);   // scattered bins, low contention
        out[IDX_OFF + row]  = valid ? (float)cidx : 0.0f;
        out[MIND_OFF + row] = valid ? mind : 0.0f;
    }
    __syncthreads();
    if (tid == 0) {
        lossp[blockIdx.x] = wl[0] + wl[1] + wl[2] + wl[3];
        nvp[blockIdx.x]   = wv[0] + wv[1] + wv[2] + wv[3];
    }
}

// ---------------------------------------------------------------------------
// Kernel 3: reduce per-block partials + histogram entropy -> scalars.
// Single block, 256 threads, ~80 KB of reads.
// ---------------------------------------------------------------------------
__global__ __launch_bounds__(256) void vq_scalars(const double* __restrict__ lossp,
                                                  const int* __restrict__ nvp,
                                                  const int* __restrict__ hist,
                                                  float* __restrict__ out) {
    __shared__ double red[256];
    __shared__ double s_nv;
    const int tid = threadIdx.x;

    double lsum = 0.0;
    int    nvl  = 0;
#pragma unroll
    for (int i = 0; i < 16; ++i) {
        const int j = tid + 256 * i;   // 4096 partials
        lsum += lossp[j];
        nvl  += nvp[j];
    }

    red[tid] = lsum;
    __syncthreads();
    for (int s = 128; s >= 1; s >>= 1) {
        if (tid < s) red[tid] += red[tid + s];
        __syncthreads();
    }
    const double losstot = red[0];
    __syncthreads();

    red[tid] = (double)nvl;
    __syncthreads();
    for (int s = 128; s >= 1; s >>= 1) {
        if (tid < s) red[tid] += red[tid + s];
        __syncthreads();
    }
    if (tid == 0) s_nv = (red[0] > 0.5) ? red[0] : 1.0;
    __syncthreads();
    const double nv = s_nv;
    __syncthreads();

    double h = 0.0;
    for (int k = tid; k < NUM_EMB; k += 256) {
        const double p = (double)hist[k] / nv;
        h += p * log(p + 1e-10);
    }
    red[tid] = h;
    __syncthreads();
    for (int s = 128; s >= 1; s >>= 1) {
        if (tid < s) red[tid] += red[tid + s];
        __syncthreads();
    }
    if (tid == 0) {
        const double H = red[0];                 // sum p*log(p+1e-10)
        const double perp = exp(-H);
        const double ploss = -log(perp + 1e-10);
        const double lvq = losstot / (nv * (double)EMB_DIM);
        out[LOSS_OFF] = (float)(lvq + PERP_W * ploss);
        out[PERP_OFF] = (float)perp;
    }
}

// ---------------------------------------------------------------------------
extern "C" void kernel_launch(void* const* d_in, const int* in_sizes, int n_in,
                              void* d_out, int out_size, void* d_ws, size_t ws_size,
                              hipStream_t stream) {
    const float* inp    = (const float*)d_in[0];  // [16384, 64]
    const float* cb     = (const float*)d_in[1];  // [8192, 64]
    const float* gumbel = (const float*)d_in[2];  // [16384, 10]
    float* out = (float*)d_out;

    char* ws = (char*)d_ws;
    float*          e2c    = (float*)(ws + WS_E2C);
    double*         e2d    = (double*)(ws + WS_E2D);
    unsigned short* cb16   = (unsigned short*)(ws + WS_CB16);
    int*            hist   = (int*)(ws + WS_HIST);
    double*         lossp  = (double*)(ws + WS_LOSSP);
    int*            nvp    = (int*)(ws + WS_NVP);
    unsigned short* cand32 = (unsigned short*)(ws + WS_C32);

    vq_prep<<<NUM_EMB / 256, 256, 0, stream>>>(cb, e2c, e2d, cb16, hist);
    vq_gemm_topk<<<dim3(N_ROWS / 16, 2), 256, 0, stream>>>(inp, cb16, e2c, cand32);
    vq_finalize<<<N_ROWS / 4, 256, 0, stream>>>(inp, cb, e2d, gumbel, cand32, out,
                                                hist, lossp, nvp);
    vq_scalars<<<1, 256, 0, stream>>>(lossp, nvp, hist, out);
}